// Round 1
// baseline (1283.497 us; speedup 1.0000x reference)
//
#include <hip/hip_runtime.h>
#include <math.h>

#define FINF __builtin_inff()

__device__ __forceinline__ float leaky(float x){ return x > 0.f ? x : 0.01f*x; }

// float atomic max/min via integer ordering trick (init to -inf/+inf)
__device__ __forceinline__ void atomicMaxF(float* a, float v){
  if (v >= 0.f) atomicMax((int*)a, __float_as_int(v));
  else          atomicMin((unsigned int*)a, __float_as_uint(v));
}
__device__ __forceinline__ void atomicMinF(float* a, float v){
  if (v >= 0.f) atomicMin((int*)a, __float_as_int(v));
  else          atomicMax((unsigned int*)a, __float_as_uint(v));
}

__global__ void k_init(float* m1, float* den1, float* m2, float* den2,
                       int* counts, float* minmax, int N){
  int i = blockIdx.x*blockDim.x + threadIdx.x;
  if (i < N*8){ m1[i] = -FINF; den1[i] = 0.f; }
  if (i < N){ m2[i] = -FINF; den2[i] = 0.f; counts[i] = 0; }
  if (i == 0){ minmax[0] = FINF; minmax[1] = -FINF; }
}

// h1 = h @ W1 + b1   [N,16]
__global__ void k_h1(const float* __restrict__ h, const float* __restrict__ W1,
                     const float* __restrict__ b1, float* __restrict__ h1, int N){
  int i = blockIdx.x*blockDim.x + threadIdx.x;
  if (i >= N*16) return;
  int n = i >> 4, j = i & 15;
  float s = b1[j];
  const float* hr = h + (size_t)n*128;
  #pragma unroll 8
  for (int k = 0; k < 128; k++) s += hr[k]*W1[k*16 + j];
  h1[i] = s;
}

// z1[n, h*32+o] = sum_k h[n,k] * fc1[h,k,o]   (GEMM [N,128]x[128,256])
__global__ __launch_bounds__(256) void k_z1(const float* __restrict__ h,
        const float* __restrict__ fc1, float* __restrict__ z1, int N){
  __shared__ float hs[32][128];
  int t = threadIdx.x;
  int n0 = blockIdx.x * 32;
  const float4* h4 = (const float4*)(h + (size_t)n0*128);
  float4* hs4 = (float4*)&hs[0][0];
  #pragma unroll
  for (int i = 0; i < 4; i++){
    int idx = t + i*256;          // 0..1023 float4 slots (32 per row)
    int row = idx >> 5;
    if (n0 + row < N) hs4[idx] = h4[idx];
    else hs4[idx] = make_float4(0.f,0.f,0.f,0.f);
  }
  __syncthreads();
  float acc[32];
  #pragma unroll
  for (int m = 0; m < 32; m++) acc[m] = 0.f;
  int hh = t >> 5, o = t & 31;
  const float* wb = fc1 + (size_t)hh*4096 + o;   // fc1[h][k][o], stride 32 in k
  for (int k = 0; k < 128; k++){
    float wv = wb[(size_t)k*32];
    #pragma unroll
    for (int m = 0; m < 32; m++) acc[m] += hs[m][k]*wv;
  }
  for (int m = 0; m < 32; m++){
    int node = n0 + m;
    if (node < N) z1[(size_t)node*256 + t] = acc[m];
  }
}

// es1/ed1[n,h] = dot(z1[n,h,:], a1_src/dst[h,:])
__global__ void k_es_ed1(const float* __restrict__ z1, const float* __restrict__ a1s,
                         const float* __restrict__ a1d, float* __restrict__ es1,
                         float* __restrict__ ed1, int N){
  int i = blockIdx.x*blockDim.x + threadIdx.x;
  if (i >= N*8) return;
  int n = i >> 3, hh = i & 7;
  const float* zr = z1 + (size_t)n*256 + hh*32;
  const float* as = a1s + hh*32;
  const float* ad = a1d + hh*32;
  float s0 = 0.f, s1 = 0.f;
  #pragma unroll
  for (int o = 0; o < 32; o++){ float zv = zr[o]; s0 += zv*as[o]; s1 += zv*ad[o]; }
  es1[i] = s0; ed1[i] = s1;
}

// gate MLP edge scores s[e]; also dst histogram and global min/max of s
__global__ __launch_bounds__(256) void k_gate_edge(const float* __restrict__ h1,
        const int* __restrict__ src, const int* __restrict__ dst,
        const float* __restrict__ W2, const float* __restrict__ b2,
        const float* __restrict__ W3, const float* __restrict__ b3,
        float* __restrict__ sbuf, int* __restrict__ counts,
        float* __restrict__ minmax, int E){
  __shared__ float lw2[256], lb2[8], lw3[8];
  __shared__ float lb3;
  __shared__ float rmin[4], rmax[4];
  int t = threadIdx.x;
  lw2[t] = W2[t];
  if (t < 8){ lb2[t] = b2[t]; lw3[t] = W3[t]; }
  if (t == 0) lb3 = b3[0];
  __syncthreads();
  int e = blockIdx.x*blockDim.x + t;
  float s = 0.f;
  bool valid = (e < E);
  if (valid){
    int a = src[e], b = dst[e];
    float4 c0[4], c1[4];
    const float4* pa = (const float4*)(h1 + (size_t)a*16);
    const float4* pb = (const float4*)(h1 + (size_t)b*16);
    #pragma unroll
    for (int q = 0; q < 4; q++){ c0[q] = pa[q]; c1[q] = pb[q]; }
    const float* f0 = (const float*)c0;
    const float* f1 = (const float*)c1;
    s = lb3;
    #pragma unroll
    for (int j = 0; j < 8; j++){
      float tj = lb2[j];
      #pragma unroll
      for (int k = 0; k < 16; k++) tj += f0[k]*lw2[k*8 + j];
      #pragma unroll
      for (int k = 0; k < 16; k++) tj += f1[k]*lw2[(16 + k)*8 + j];
      s += fmaxf(tj, 0.f)*lw3[j];
    }
    sbuf[e] = s;
    atomicAdd(&counts[b], 1);
  }
  float vmin = valid ? s : FINF;
  float vmax = valid ? s : -FINF;
  #pragma unroll
  for (int o = 32; o > 0; o >>= 1){
    vmin = fminf(vmin, __shfl_xor(vmin, o));
    vmax = fmaxf(vmax, __shfl_xor(vmax, o));
  }
  if ((t & 63) == 0){ rmin[t >> 6] = vmin; rmax[t >> 6] = vmax; }
  __syncthreads();
  if (t == 0){
    float mn = fminf(fminf(rmin[0], rmin[1]), fminf(rmin[2], rmin[3]));
    float mx = fmaxf(fmaxf(rmax[0], rmax[1]), fmaxf(rmax[2], rmax[3]));
    atomicMinF(&minmax[0], mn);
    atomicMaxF(&minmax[1], mx);
  }
}

// exclusive scan of counts -> indptr; counts becomes the scatter cursor
__global__ __launch_bounds__(1024) void k_scan(int* __restrict__ counts,
                                               int* __restrict__ indptr, int N){
  __shared__ int tot[1024];
  int t = threadIdx.x;
  int per = (N + 1023) / 1024;
  int beg = t*per;
  int end = min(beg + per, N);
  int sum = 0;
  for (int i = beg; i < end; i++) sum += counts[i];
  tot[t] = sum;
  __syncthreads();
  for (int o = 1; o < 1024; o <<= 1){
    int v = (t >= o) ? tot[t - o] : 0;
    __syncthreads();
    tot[t] += v;
    __syncthreads();
  }
  int run = (t == 0) ? 0 : tot[t-1];
  for (int i = beg; i < end; i++){
    int c = counts[i];
    indptr[i] = run;
    counts[i] = run;   // cursor for scatter
    run += c;
  }
  if (t == 1023) indptr[N] = run;
}

__global__ void k_scatter(const int* __restrict__ dst, int* __restrict__ cursor,
                          int* __restrict__ eids, int E){
  int e = blockIdx.x*blockDim.x + threadIdx.x;
  if (e >= E) return;
  int pos = atomicAdd(&cursor[dst[e]], 1);
  eids[pos] = e;
}

__global__ void k_gate_norm(const float* __restrict__ sbuf, const float* __restrict__ minmax,
                            float* __restrict__ gate, int E){
  int e = blockIdx.x*blockDim.x + threadIdx.x;
  if (e >= E) return;
  float mn = minmax[0], mx = minmax[1];
  gate[e] = (sbuf[e] - mn) / (mx - mn);
}

// layer1 attention logits + segment max
__global__ void k_att1_max(const int* __restrict__ src, const int* __restrict__ dst,
                           const float* __restrict__ es1, const float* __restrict__ ed1,
                           const float* __restrict__ gate, float* __restrict__ p1,
                           float* __restrict__ m1, int E){
  int e = blockIdx.x*blockDim.x + threadIdx.x;
  if (e >= E) return;
  int a = src[e], b = dst[e];
  float g = gate[e];
  #pragma unroll
  for (int hh = 0; hh < 8; hh++){
    float v = leaky(es1[a*8 + hh] + ed1[b*8 + hh]) * g;
    p1[(size_t)e*8 + hh] = v;
    atomicMaxF(&m1[b*8 + hh], v);
  }
}

// p1 := exp(p1 - m1[dst]); den1 += p1
__global__ void k_att1_exp(const int* __restrict__ dst, float* __restrict__ p1,
                           const float* __restrict__ m1, float* __restrict__ den1, int E){
  int i = blockIdx.x*blockDim.x + threadIdx.x;
  if (i >= E*8) return;
  int e = i >> 3, hh = i & 7;
  int b = dst[e];
  float ex = __expf(p1[i] - m1[b*8 + hh]);
  p1[i] = ex;
  atomicAdd(&den1[b*8 + hh], ex);
}

// per-dst gather: hA[n,:] = leaky( (sum_e p1[e,h]*z1[src,:]) / den1[n,h] )
__global__ __launch_bounds__(256) void k_gather1(const int* __restrict__ indptr,
        const int* __restrict__ eids, const int* __restrict__ src,
        const float* __restrict__ p1, const float* __restrict__ den1,
        const float* __restrict__ z1, float* __restrict__ hA, int N){
  int n = blockIdx.x;
  int t = threadIdx.x;
  int hh = t >> 5;
  int beg = indptr[n], end = indptr[n+1];
  float acc = 0.f;
  for (int j = beg; j < end; j++){
    int e = eids[j];
    int sn = src[e];
    float wv = p1[(size_t)e*8 + hh];
    acc += wv * z1[(size_t)sn*256 + t];
  }
  float den = den1[n*8 + hh];
  float v = acc / fmaxf(den, 1e-12f);
  hA[(size_t)n*256 + t] = leaky(v);
}

// z2 = hA @ fc2   [N,256]x[256,64]
__global__ __launch_bounds__(256) void k_z2(const float* __restrict__ hA,
        const float* __restrict__ fc2, float* __restrict__ z2, int N){
  __shared__ float hs[32][256];
  int t = threadIdx.x;
  int n0 = blockIdx.x*32;
  const float4* a4 = (const float4*)(hA + (size_t)n0*256);
  float4* hs4 = (float4*)&hs[0][0];
  #pragma unroll
  for (int i = 0; i < 8; i++){
    int idx = t + i*256;          // 0..2047 float4 slots (64 per row)
    int row = idx >> 6;
    if (n0 + row < N) hs4[idx] = a4[idx];
    else hs4[idx] = make_float4(0.f,0.f,0.f,0.f);
  }
  __syncthreads();
  int col = t & 63, grp = t >> 6;
  float acc[8];
  #pragma unroll
  for (int i = 0; i < 8; i++) acc[i] = 0.f;
  const float* wb = fc2 + col;
  for (int k = 0; k < 256; k++){
    float wv = wb[(size_t)k*64];
    #pragma unroll
    for (int i = 0; i < 8; i++) acc[i] += hs[grp*8 + i][k]*wv;
  }
  #pragma unroll
  for (int i = 0; i < 8; i++){
    int node = n0 + grp*8 + i;
    if (node < N) z2[(size_t)node*64 + col] = acc[i];
  }
}

__global__ void k_es_ed2(const float* __restrict__ z2, const float* __restrict__ a2s,
                         const float* __restrict__ a2d, float* __restrict__ es2,
                         float* __restrict__ ed2, int N){
  int n = blockIdx.x*blockDim.x + threadIdx.x;
  if (n >= N) return;
  const float* zr = z2 + (size_t)n*64;
  float s0 = 0.f, s1 = 0.f;
  #pragma unroll 8
  for (int o = 0; o < 64; o++){ float zv = zr[o]; s0 += zv*a2s[o]; s1 += zv*a2d[o]; }
  es2[n] = s0; ed2[n] = s1;
}

__global__ void k_att2_max(const int* __restrict__ src, const int* __restrict__ dst,
                           const float* __restrict__ es2, const float* __restrict__ ed2,
                           const float* __restrict__ gate, float* __restrict__ p2,
                           float* __restrict__ m2, int E){
  int e = blockIdx.x*blockDim.x + threadIdx.x;
  if (e >= E) return;
  int a = src[e], b = dst[e];
  float v = leaky(es2[a] + ed2[b]) * gate[e];
  p2[e] = v;
  atomicMaxF(&m2[b], v);
}

__global__ void k_att2_exp(const int* __restrict__ dst, float* __restrict__ p2,
                           const float* __restrict__ m2, float* __restrict__ den2, int E){
  int e = blockIdx.x*blockDim.x + threadIdx.x;
  if (e >= E) return;
  int b = dst[e];
  float ex = __expf(p2[e] - m2[b]);
  p2[e] = ex;
  atomicAdd(&den2[b], ex);
}

__global__ __launch_bounds__(64) void k_gather2(const int* __restrict__ indptr,
        const int* __restrict__ eids, const int* __restrict__ src,
        const float* __restrict__ p2, const float* __restrict__ den2,
        const float* __restrict__ z2, float* __restrict__ hB, int N){
  int n = blockIdx.x;
  int t = threadIdx.x;
  int beg = indptr[n], end = indptr[n+1];
  float acc = 0.f;
  for (int j = beg; j < end; j++){
    int e = eids[j];
    int sn = src[e];
    acc += p2[e] * z2[(size_t)sn*64 + t];
  }
  hB[(size_t)n*64 + t] = acc / fmaxf(den2[n], 1e-12f);
}

__global__ __launch_bounds__(256) void k_edgepred(const int* __restrict__ src,
        const int* __restrict__ dst, const float* __restrict__ hB,
        const float* __restrict__ Wp, const float* __restrict__ bp,
        float* __restrict__ out, int E){
  __shared__ float lwp[256];
  int t = threadIdx.x;
  lwp[t] = Wp[t];
  __syncthreads();
  int e = blockIdx.x*256 + t;
  if (e >= E) return;
  int a = src[e], b = dst[e];
  float acc0 = bp[0], acc1 = bp[1];
  const float4* ra = (const float4*)(hB + (size_t)a*64);
  const float4* rb = (const float4*)(hB + (size_t)b*64);
  #pragma unroll
  for (int q = 0; q < 16; q++){
    float4 v = ra[q];
    acc0 += v.x*lwp[(q*4+0)*2+0] + v.y*lwp[(q*4+1)*2+0] + v.z*lwp[(q*4+2)*2+0] + v.w*lwp[(q*4+3)*2+0];
    acc1 += v.x*lwp[(q*4+0)*2+1] + v.y*lwp[(q*4+1)*2+1] + v.z*lwp[(q*4+2)*2+1] + v.w*lwp[(q*4+3)*2+1];
  }
  #pragma unroll
  for (int q = 0; q < 16; q++){
    float4 v = rb[q];
    acc0 += v.x*lwp[128+(q*4+0)*2+0] + v.y*lwp[128+(q*4+1)*2+0] + v.z*lwp[128+(q*4+2)*2+0] + v.w*lwp[128+(q*4+3)*2+0];
    acc1 += v.x*lwp[128+(q*4+0)*2+1] + v.y*lwp[128+(q*4+1)*2+1] + v.z*lwp[128+(q*4+2)*2+1] + v.w*lwp[128+(q*4+3)*2+1];
  }
  out[(size_t)e*2]     = acc0;
  out[(size_t)e*2 + 1] = acc1;
}

extern "C" void kernel_launch(void* const* d_in, const int* in_sizes, int n_in,
                              void* d_out, int out_size, void* d_ws, size_t ws_size,
                              hipStream_t stream) {
  const float* h   = (const float*)d_in[0];
  const int*   src = (const int*)d_in[1];
  const int*   dst = (const int*)d_in[2];
  const float* W1  = (const float*)d_in[3];
  const float* b1  = (const float*)d_in[4];
  const float* W2  = (const float*)d_in[5];
  const float* b2  = (const float*)d_in[6];
  const float* W3  = (const float*)d_in[7];
  const float* b3  = (const float*)d_in[8];
  const float* fc1 = (const float*)d_in[9];
  const float* a1s = (const float*)d_in[10];
  const float* a1d = (const float*)d_in[11];
  const float* fc2 = (const float*)d_in[12];
  const float* a2s = (const float*)d_in[13];
  const float* a2d = (const float*)d_in[14];
  const float* Wp  = (const float*)d_in[15];
  const float* bp  = (const float*)d_in[16];

  const int N = in_sizes[0] / 128;
  const int E = in_sizes[1];

  float* out_score = (float*)d_out;             // [E,2]
  float* gate      = out_score + (size_t)E*2;   // [E]

  char* w = (char*)d_ws;
  size_t off = 0;
  auto alloc = [&](size_t bytes) -> void* {
    off = (off + 255) & ~(size_t)255;
    void* p = w + off; off += bytes; return p;
  };
  float* h1   = (float*)alloc((size_t)N*16*4);
  float* z1   = (float*)alloc((size_t)N*256*4);
  float* es1  = (float*)alloc((size_t)N*8*4);
  float* ed1  = (float*)alloc((size_t)N*8*4);
  float* sbuf = (float*)alloc((size_t)E*4);
  float* m1   = (float*)alloc((size_t)N*8*4);
  float* den1 = (float*)alloc((size_t)N*8*4);
  float* p1   = (float*)alloc((size_t)E*8*4);
  float* hA   = (float*)alloc((size_t)N*256*4);
  float* es2  = (float*)alloc((size_t)N*4);
  float* ed2  = (float*)alloc((size_t)N*4);
  float* m2   = (float*)alloc((size_t)N*4);
  float* den2 = (float*)alloc((size_t)N*4);
  float* minmax = (float*)alloc(2*4);
  int* counts = (int*)alloc((size_t)N*4);
  int* indptr = (int*)alloc(((size_t)N+1)*4);
  int* eids   = (int*)alloc((size_t)E*4);
  (void)ws_size; (void)n_in; (void)out_size;

  // buffer reuse after z1/p1 are dead (post-gather1)
  float* z2 = z1;                   // [N,64]
  float* hB = z1 + (size_t)N*64;    // [N,64]
  float* p2 = p1;                   // [E]

  k_init<<<(N*8 + 255)/256, 256, 0, stream>>>(m1, den1, m2, den2, counts, minmax, N);
  k_h1<<<(N*16 + 255)/256, 256, 0, stream>>>(h, W1, b1, h1, N);
  k_z1<<<(N + 31)/32, 256, 0, stream>>>(h, fc1, z1, N);
  k_es_ed1<<<(N*8 + 255)/256, 256, 0, stream>>>(z1, a1s, a1d, es1, ed1, N);
  k_gate_edge<<<(E + 255)/256, 256, 0, stream>>>(h1, src, dst, W2, b2, W3, b3,
                                                 sbuf, counts, minmax, E);
  k_scan<<<1, 1024, 0, stream>>>(counts, indptr, N);
  k_scatter<<<(E + 255)/256, 256, 0, stream>>>(dst, counts, eids, E);
  k_gate_norm<<<(E + 255)/256, 256, 0, stream>>>(sbuf, minmax, gate, E);
  k_att1_max<<<(E + 255)/256, 256, 0, stream>>>(src, dst, es1, ed1, gate, p1, m1, E);
  k_att1_exp<<<(E*8 + 255)/256, 256, 0, stream>>>(dst, p1, m1, den1, E);
  k_gather1<<<N, 256, 0, stream>>>(indptr, eids, src, p1, den1, z1, hA, N);
  k_z2<<<(N + 31)/32, 256, 0, stream>>>(hA, fc2, z2, N);
  k_es_ed2<<<(N + 255)/256, 256, 0, stream>>>(z2, a2s, a2d, es2, ed2, N);
  k_att2_max<<<(E + 255)/256, 256, 0, stream>>>(src, dst, es2, ed2, gate, p2, m2, E);
  k_att2_exp<<<(E + 255)/256, 256, 0, stream>>>(dst, p2, m2, den2, E);
  k_gather2<<<N, 64, 0, stream>>>(indptr, eids, src, p2, den2, z2, hB, N);
  k_edgepred<<<(E + 255)/256, 256, 0, stream>>>(src, dst, hB, Wp, bp, out_score, E);
}

// Round 2
// 810.586 us; speedup vs baseline: 1.5834x; 1.5834x over previous
//
#include <hip/hip_runtime.h>
#include <math.h>

#define FINF __builtin_inff()

__device__ __forceinline__ float leaky(float x){ return x > 0.f ? x : 0.01f*x; }

__device__ __forceinline__ void atomicMaxF(float* a, float v){
  if (v >= 0.f) atomicMax((int*)a, __float_as_int(v));
  else          atomicMin((unsigned int*)a, __float_as_uint(v));
}
__device__ __forceinline__ void atomicMinF(float* a, float v){
  if (v >= 0.f) atomicMin((int*)a, __float_as_int(v));
  else          atomicMax((unsigned int*)a, __float_as_uint(v));
}

__global__ void k_init(int* counts, float* minmax, int N){
  int i = blockIdx.x*blockDim.x + threadIdx.x;
  if (i < N) counts[i] = 0;
  if (i == 0){ minmax[0] = FINF; minmax[1] = -FINF; }
}

// h1 = h @ W1 + b1   [N,16]
__global__ void k_h1(const float* __restrict__ h, const float* __restrict__ W1,
                     const float* __restrict__ b1, float* __restrict__ h1, int N){
  int i = blockIdx.x*blockDim.x + threadIdx.x;
  if (i >= N*16) return;
  int n = i >> 4, j = i & 15;
  float s = b1[j];
  const float* hr = h + (size_t)n*128;
  #pragma unroll 8
  for (int k = 0; k < 128; k++) s += hr[k]*W1[k*16 + j];
  h1[i] = s;
}

// z1[n, h*32+o] = sum_k h[n,k] * fc1[h,k,o]   (GEMM [N,128]x[128,256])
__global__ __launch_bounds__(256) void k_z1(const float* __restrict__ h,
        const float* __restrict__ fc1, float* __restrict__ z1, int N){
  __shared__ float hs[32][128];
  int t = threadIdx.x;
  int n0 = blockIdx.x * 32;
  const float4* h4 = (const float4*)(h + (size_t)n0*128);
  float4* hs4 = (float4*)&hs[0][0];
  #pragma unroll
  for (int i = 0; i < 4; i++){
    int idx = t + i*256;
    int row = idx >> 5;
    if (n0 + row < N) hs4[idx] = h4[idx];
    else hs4[idx] = make_float4(0.f,0.f,0.f,0.f);
  }
  __syncthreads();
  float acc[32];
  #pragma unroll
  for (int m = 0; m < 32; m++) acc[m] = 0.f;
  int hh = t >> 5, o = t & 31;
  const float* wb = fc1 + (size_t)hh*4096 + o;
  for (int k = 0; k < 128; k++){
    float wv = wb[(size_t)k*32];
    #pragma unroll
    for (int m = 0; m < 32; m++) acc[m] += hs[m][k]*wv;
  }
  for (int m = 0; m < 32; m++){
    int node = n0 + m;
    if (node < N) z1[(size_t)node*256 + t] = acc[m];
  }
}

// es1/ed1[n,h] = dot(z1[n,h,:], a1_src/dst[h,:])
__global__ void k_es_ed1(const float* __restrict__ z1, const float* __restrict__ a1s,
                         const float* __restrict__ a1d, float* __restrict__ es1,
                         float* __restrict__ ed1, int N){
  int i = blockIdx.x*blockDim.x + threadIdx.x;
  if (i >= N*8) return;
  int n = i >> 3, hh = i & 7;
  const float* zr = z1 + (size_t)n*256 + hh*32;
  const float* as = a1s + hh*32;
  const float* ad = a1d + hh*32;
  float s0 = 0.f, s1 = 0.f;
  #pragma unroll
  for (int o = 0; o < 32; o++){ float zv = zr[o]; s0 += zv*as[o]; s1 += zv*ad[o]; }
  es1[i] = s0; ed1[i] = s1;
}

// gate MLP edge scores s[e]; also dst histogram and global min/max of s
__global__ __launch_bounds__(256) void k_gate_edge(const float* __restrict__ h1,
        const int* __restrict__ src, const int* __restrict__ dst,
        const float* __restrict__ W2, const float* __restrict__ b2,
        const float* __restrict__ W3, const float* __restrict__ b3,
        float* __restrict__ sbuf, int* __restrict__ counts,
        float* __restrict__ minmax, int E){
  __shared__ float lw2[256], lb2[8], lw3[8];
  __shared__ float lb3;
  __shared__ float rmin[4], rmax[4];
  int t = threadIdx.x;
  lw2[t] = W2[t];
  if (t < 8){ lb2[t] = b2[t]; lw3[t] = W3[t]; }
  if (t == 0) lb3 = b3[0];
  __syncthreads();
  int e = blockIdx.x*blockDim.x + t;
  float s = 0.f;
  bool valid = (e < E);
  if (valid){
    int a = src[e], b = dst[e];
    float4 c0[4], c1[4];
    const float4* pa = (const float4*)(h1 + (size_t)a*16);
    const float4* pb = (const float4*)(h1 + (size_t)b*16);
    #pragma unroll
    for (int q = 0; q < 4; q++){ c0[q] = pa[q]; c1[q] = pb[q]; }
    const float* f0 = (const float*)c0;
    const float* f1 = (const float*)c1;
    s = lb3;
    #pragma unroll
    for (int j = 0; j < 8; j++){
      float tj = lb2[j];
      #pragma unroll
      for (int k = 0; k < 16; k++) tj += f0[k]*lw2[k*8 + j];
      #pragma unroll
      for (int k = 0; k < 16; k++) tj += f1[k]*lw2[(16 + k)*8 + j];
      s += fmaxf(tj, 0.f)*lw3[j];
    }
    sbuf[e] = s;
    atomicAdd(&counts[b], 1);
  }
  float vmin = valid ? s : FINF;
  float vmax = valid ? s : -FINF;
  #pragma unroll
  for (int o = 32; o > 0; o >>= 1){
    vmin = fminf(vmin, __shfl_xor(vmin, o));
    vmax = fmaxf(vmax, __shfl_xor(vmax, o));
  }
  if ((t & 63) == 0){ rmin[t >> 6] = vmin; rmax[t >> 6] = vmax; }
  __syncthreads();
  if (t == 0){
    float mn = fminf(fminf(rmin[0], rmin[1]), fminf(rmin[2], rmin[3]));
    float mx = fmaxf(fmaxf(rmax[0], rmax[1]), fmaxf(rmax[2], rmax[3]));
    atomicMinF(&minmax[0], mn);
    atomicMaxF(&minmax[1], mx);
  }
}

// exclusive scan of counts -> indptr; counts becomes the scatter cursor
__global__ __launch_bounds__(1024) void k_scan(int* __restrict__ counts,
                                               int* __restrict__ indptr, int N){
  __shared__ int tot[1024];
  int t = threadIdx.x;
  int per = (N + 1023) / 1024;
  int beg = t*per;
  int end = min(beg + per, N);
  int sum = 0;
  for (int i = beg; i < end; i++) sum += counts[i];
  tot[t] = sum;
  __syncthreads();
  for (int o = 1; o < 1024; o <<= 1){
    int v = (t >= o) ? tot[t - o] : 0;
    __syncthreads();
    tot[t] += v;
    __syncthreads();
  }
  int run = (t == 0) ? 0 : tot[t-1];
  for (int i = beg; i < end; i++){
    int c = counts[i];
    indptr[i] = run;
    counts[i] = run;   // cursor for scatter
    run += c;
  }
  if (t == 1023) indptr[N] = run;
}

__global__ void k_gate_norm(const float* __restrict__ sbuf, const float* __restrict__ minmax,
                            float* __restrict__ gate, int E){
  int e = blockIdx.x*blockDim.x + threadIdx.x;
  if (e >= E) return;
  float mn = minmax[0], mx = minmax[1];
  gate[e] = (sbuf[e] - mn) / (mx - mn);
}

// CSR scatter: emit dst-sorted src ids and gate values (no eids indirection later)
__global__ void k_scatter(const int* __restrict__ src, const int* __restrict__ dst,
                          const float* __restrict__ gate, int* __restrict__ cursor,
                          int* __restrict__ srcs, float* __restrict__ gs, int E){
  int e = blockIdx.x*blockDim.x + threadIdx.x;
  if (e >= E) return;
  int pos = atomicAdd(&cursor[dst[e]], 1);
  srcs[pos] = src[e];
  gs[pos] = gate[e];
}

// fused layer1: online segment-softmax + weighted gather
// block = 1 dst node, 256 threads = 8 heads x 32 dims. Logit is lane-uniform
// within a head group, so m/den are tracked per-thread with no reduction.
__global__ __launch_bounds__(256) void k_gather1f(const int* __restrict__ indptr,
        const int* __restrict__ srcs, const float* __restrict__ gs,
        const float* __restrict__ es1, const float* __restrict__ ed1,
        const float* __restrict__ z1, float* __restrict__ hA, int N){
  int n = blockIdx.x;
  int t = threadIdx.x;
  int hh = t >> 5;
  int beg = indptr[n], end = indptr[n+1];
  float ed = ed1[n*8 + hh];
  float m = -FINF, den = 0.f, acc = 0.f;
  for (int j = beg; j < end; j++){
    int a = srcs[j];
    float g = gs[j];
    float v = leaky(es1[a*8 + hh] + ed) * g;
    if (v > m){ float r = __expf(m - v); den *= r; acc *= r; m = v; }
    float w = __expf(v - m);
    den += w;
    acc += w * z1[(size_t)a*256 + t];
  }
  hA[(size_t)n*256 + t] = leaky(acc / fmaxf(den, 1e-12f));
}

// z2 = hA @ fc2   [N,256]x[256,64]
__global__ __launch_bounds__(256) void k_z2(const float* __restrict__ hA,
        const float* __restrict__ fc2, float* __restrict__ z2, int N){
  __shared__ float hs[32][256];
  int t = threadIdx.x;
  int n0 = blockIdx.x*32;
  const float4* a4 = (const float4*)(hA + (size_t)n0*256);
  float4* hs4 = (float4*)&hs[0][0];
  #pragma unroll
  for (int i = 0; i < 8; i++){
    int idx = t + i*256;
    int row = idx >> 6;
    if (n0 + row < N) hs4[idx] = a4[idx];
    else hs4[idx] = make_float4(0.f,0.f,0.f,0.f);
  }
  __syncthreads();
  int col = t & 63, grp = t >> 6;
  float acc[8];
  #pragma unroll
  for (int i = 0; i < 8; i++) acc[i] = 0.f;
  const float* wb = fc2 + col;
  for (int k = 0; k < 256; k++){
    float wv = wb[(size_t)k*64];
    #pragma unroll
    for (int i = 0; i < 8; i++) acc[i] += hs[grp*8 + i][k]*wv;
  }
  #pragma unroll
  for (int i = 0; i < 8; i++){
    int node = n0 + grp*8 + i;
    if (node < N) z2[(size_t)node*64 + col] = acc[i];
  }
}

__global__ void k_es_ed2(const float* __restrict__ z2, const float* __restrict__ a2s,
                         const float* __restrict__ a2d, float* __restrict__ es2,
                         float* __restrict__ ed2, int N){
  int n = blockIdx.x*blockDim.x + threadIdx.x;
  if (n >= N) return;
  const float* zr = z2 + (size_t)n*64;
  float s0 = 0.f, s1 = 0.f;
  #pragma unroll 8
  for (int o = 0; o < 64; o++){ float zv = zr[o]; s0 += zv*a2s[o]; s1 += zv*a2d[o]; }
  es2[n] = s0; ed2[n] = s1;
}

// fused layer2: 4 dst nodes per block, 64 lanes each, online softmax
__global__ __launch_bounds__(256) void k_gather2f(const int* __restrict__ indptr,
        const int* __restrict__ srcs, const float* __restrict__ gs,
        const float* __restrict__ es2, const float* __restrict__ ed2,
        const float* __restrict__ z2, float* __restrict__ hB, int N){
  int t = threadIdx.x;
  int n = blockIdx.x*4 + (t >> 6);
  if (n >= N) return;
  int lane = t & 63;
  int beg = indptr[n], end = indptr[n+1];
  float ed = ed2[n];
  float m = -FINF, den = 0.f, acc = 0.f;
  for (int j = beg; j < end; j++){
    int a = srcs[j];
    float v = leaky(es2[a] + ed) * gs[j];
    if (v > m){ float r = __expf(m - v); den *= r; acc *= r; m = v; }
    float w = __expf(v - m);
    den += w;
    acc += w * z2[(size_t)a*64 + lane];
  }
  hB[(size_t)n*64 + lane] = acc / fmaxf(den, 1e-12f);
}

__global__ __launch_bounds__(256) void k_edgepred(const int* __restrict__ src,
        const int* __restrict__ dst, const float* __restrict__ hB,
        const float* __restrict__ Wp, const float* __restrict__ bp,
        float* __restrict__ out, int E){
  __shared__ float lwp[256];
  int t = threadIdx.x;
  lwp[t] = Wp[t];
  __syncthreads();
  int e = blockIdx.x*256 + t;
  if (e >= E) return;
  int a = src[e], b = dst[e];
  float acc0 = bp[0], acc1 = bp[1];
  const float4* ra = (const float4*)(hB + (size_t)a*64);
  const float4* rb = (const float4*)(hB + (size_t)b*64);
  #pragma unroll
  for (int q = 0; q < 16; q++){
    float4 v = ra[q];
    acc0 += v.x*lwp[(q*4+0)*2+0] + v.y*lwp[(q*4+1)*2+0] + v.z*lwp[(q*4+2)*2+0] + v.w*lwp[(q*4+3)*2+0];
    acc1 += v.x*lwp[(q*4+0)*2+1] + v.y*lwp[(q*4+1)*2+1] + v.z*lwp[(q*4+2)*2+1] + v.w*lwp[(q*4+3)*2+1];
  }
  #pragma unroll
  for (int q = 0; q < 16; q++){
    float4 v = rb[q];
    acc0 += v.x*lwp[128+(q*4+0)*2+0] + v.y*lwp[128+(q*4+1)*2+0] + v.z*lwp[128+(q*4+2)*2+0] + v.w*lwp[128+(q*4+3)*2+0];
    acc1 += v.x*lwp[128+(q*4+0)*2+1] + v.y*lwp[128+(q*4+1)*2+1] + v.z*lwp[128+(q*4+2)*2+1] + v.w*lwp[128+(q*4+3)*2+1];
  }
  out[(size_t)e*2]     = acc0;
  out[(size_t)e*2 + 1] = acc1;
}

extern "C" void kernel_launch(void* const* d_in, const int* in_sizes, int n_in,
                              void* d_out, int out_size, void* d_ws, size_t ws_size,
                              hipStream_t stream) {
  const float* h   = (const float*)d_in[0];
  const int*   src = (const int*)d_in[1];
  const int*   dst = (const int*)d_in[2];
  const float* W1  = (const float*)d_in[3];
  const float* b1  = (const float*)d_in[4];
  const float* W2  = (const float*)d_in[5];
  const float* b2  = (const float*)d_in[6];
  const float* W3  = (const float*)d_in[7];
  const float* b3  = (const float*)d_in[8];
  const float* fc1 = (const float*)d_in[9];
  const float* a1s = (const float*)d_in[10];
  const float* a1d = (const float*)d_in[11];
  const float* fc2 = (const float*)d_in[12];
  const float* a2s = (const float*)d_in[13];
  const float* a2d = (const float*)d_in[14];
  const float* Wp  = (const float*)d_in[15];
  const float* bp  = (const float*)d_in[16];

  const int N = in_sizes[0] / 128;
  const int E = in_sizes[1];

  float* out_score = (float*)d_out;             // [E,2]
  float* gate      = out_score + (size_t)E*2;   // [E]

  char* w = (char*)d_ws;
  size_t off = 0;
  auto alloc = [&](size_t bytes) -> void* {
    off = (off + 255) & ~(size_t)255;
    void* p = w + off; off += bytes; return p;
  };
  float* h1   = (float*)alloc((size_t)N*16*4);
  float* z1   = (float*)alloc((size_t)N*256*4);
  float* es1  = (float*)alloc((size_t)N*8*4);
  float* ed1  = (float*)alloc((size_t)N*8*4);
  float* sbuf = (float*)alloc((size_t)E*4);
  float* hA   = (float*)alloc((size_t)N*256*4);
  float* es2  = (float*)alloc((size_t)N*4);
  float* ed2  = (float*)alloc((size_t)N*4);
  float* minmax = (float*)alloc(2*4);
  int* counts = (int*)alloc((size_t)N*4);
  int* indptr = (int*)alloc(((size_t)N+1)*4);
  int* srcs   = (int*)alloc((size_t)E*4);
  float* gs   = (float*)alloc((size_t)E*4);
  (void)ws_size; (void)n_in; (void)out_size;

  // buffer reuse after z1 is dead (post-gather1)
  float* z2 = z1;                   // [N,64]
  float* hB = z1 + (size_t)N*64;    // [N,64]

  k_init<<<(N + 255)/256, 256, 0, stream>>>(counts, minmax, N);
  k_h1<<<(N*16 + 255)/256, 256, 0, stream>>>(h, W1, b1, h1, N);
  k_z1<<<(N + 31)/32, 256, 0, stream>>>(h, fc1, z1, N);
  k_es_ed1<<<(N*8 + 255)/256, 256, 0, stream>>>(z1, a1s, a1d, es1, ed1, N);
  k_gate_edge<<<(E + 255)/256, 256, 0, stream>>>(h1, src, dst, W2, b2, W3, b3,
                                                 sbuf, counts, minmax, E);
  k_scan<<<1, 1024, 0, stream>>>(counts, indptr, N);
  k_gate_norm<<<(E + 255)/256, 256, 0, stream>>>(sbuf, minmax, gate, E);
  k_scatter<<<(E + 255)/256, 256, 0, stream>>>(src, dst, gate, counts, srcs, gs, E);
  k_gather1f<<<N, 256, 0, stream>>>(indptr, srcs, gs, es1, ed1, z1, hA, N);
  k_z2<<<(N + 31)/32, 256, 0, stream>>>(hA, fc2, z2, N);
  k_es_ed2<<<(N + 255)/256, 256, 0, stream>>>(z2, a2s, a2d, es2, ed2, N);
  k_gather2f<<<(N + 3)/4, 256, 0, stream>>>(indptr, srcs, gs, es2, ed2, z2, hB, N);
  k_edgepred<<<(E + 255)/256, 256, 0, stream>>>(src, dst, hB, Wp, bp, out_score, E);
}

// Round 3
// 726.973 us; speedup vs baseline: 1.7655x; 1.1150x over previous
//
#include <hip/hip_runtime.h>
#include <math.h>

#define FINF __builtin_inff()

__device__ __forceinline__ float leaky(float x){ return x > 0.f ? x : 0.01f*x; }

__device__ __forceinline__ void atomicMaxF(float* a, float v){
  if (v >= 0.f) atomicMax((int*)a, __float_as_int(v));
  else          atomicMin((unsigned int*)a, __float_as_uint(v));
}
__device__ __forceinline__ void atomicMinF(float* a, float v){
  if (v >= 0.f) atomicMin((int*)a, __float_as_int(v));
  else          atomicMax((unsigned int*)a, __float_as_uint(v));
}

__global__ void k_init(int* counts, float* minmax, int N){
  int i = blockIdx.x*blockDim.x + threadIdx.x;
  if (i < N) counts[i] = 0;
  if (i == 0){ minmax[0] = FINF; minmax[1] = -FINF; }
}

// h1 = h @ W1 + b1   [N,16]
__global__ void k_h1(const float* __restrict__ h, const float* __restrict__ W1,
                     const float* __restrict__ b1, float* __restrict__ h1, int N){
  int i = blockIdx.x*blockDim.x + threadIdx.x;
  if (i >= N*16) return;
  int n = i >> 4, j = i & 15;
  float s = b1[j];
  const float* hr = h + (size_t)n*128;
  #pragma unroll 8
  for (int k = 0; k < 128; k++) s += hr[k]*W1[k*16 + j];
  h1[i] = s;
}

// per-node split of gate-MLP layer 2 (pre-ReLU): u_s = h1@W2[0:16], u_d = h1@W2[16:32]
__global__ void k_u(const float* __restrict__ h1, const float* __restrict__ W2,
                    float* __restrict__ u_s, float* __restrict__ u_d, int N){
  int i = blockIdx.x*blockDim.x + threadIdx.x;
  if (i >= N*16) return;
  int n = i >> 4, j = i & 15;
  const float* hr = h1 + (size_t)n*16;
  if (j < 8){
    float s = 0.f;
    #pragma unroll
    for (int k = 0; k < 16; k++) s += hr[k]*W2[k*8 + j];
    u_s[n*8 + j] = s;
  } else {
    j -= 8;
    float s = 0.f;
    #pragma unroll
    for (int k = 0; k < 16; k++) s += hr[k]*W2[(16 + k)*8 + j];
    u_d[n*8 + j] = s;
  }
}

// z1[n, h*32+o] = sum_k h[n,k] * fc1[h,k,o]   (GEMM [N,128]x[128,256])
__global__ __launch_bounds__(256) void k_z1(const float* __restrict__ h,
        const float* __restrict__ fc1, float* __restrict__ z1, int N){
  __shared__ float hs[32][128];
  int t = threadIdx.x;
  int n0 = blockIdx.x * 32;
  const float4* h4 = (const float4*)(h + (size_t)n0*128);
  float4* hs4 = (float4*)&hs[0][0];
  #pragma unroll
  for (int i = 0; i < 4; i++){
    int idx = t + i*256;
    int row = idx >> 5;
    if (n0 + row < N) hs4[idx] = h4[idx];
    else hs4[idx] = make_float4(0.f,0.f,0.f,0.f);
  }
  __syncthreads();
  float acc[32];
  #pragma unroll
  for (int m = 0; m < 32; m++) acc[m] = 0.f;
  int hh = t >> 5, o = t & 31;
  const float* wb = fc1 + (size_t)hh*4096 + o;
  for (int k = 0; k < 128; k++){
    float wv = wb[(size_t)k*32];
    #pragma unroll
    for (int m = 0; m < 32; m++) acc[m] += hs[m][k]*wv;
  }
  for (int m = 0; m < 32; m++){
    int node = n0 + m;
    if (node < N) z1[(size_t)node*256 + t] = acc[m];
  }
}

// es1/ed1[n,h] = dot(z1[n,h,:], a1_src/dst[h,:])
__global__ void k_es_ed1(const float* __restrict__ z1, const float* __restrict__ a1s,
                         const float* __restrict__ a1d, float* __restrict__ es1,
                         float* __restrict__ ed1, int N){
  int i = blockIdx.x*blockDim.x + threadIdx.x;
  if (i >= N*8) return;
  int n = i >> 3, hh = i & 7;
  const float* zr = z1 + (size_t)n*256 + hh*32;
  const float* as = a1s + hh*32;
  const float* ad = a1d + hh*32;
  float s0 = 0.f, s1 = 0.f;
  #pragma unroll
  for (int o = 0; o < 32; o++){ float zv = zr[o]; s0 += zv*as[o]; s1 += zv*ad[o]; }
  es1[i] = s0; ed1[i] = s1;
}

// gate edge score via per-node decomposition; also dst histogram + global min/max
__global__ __launch_bounds__(256) void k_gate_edge(const float* __restrict__ u_s,
        const float* __restrict__ u_d,
        const int* __restrict__ src, const int* __restrict__ dst,
        const float* __restrict__ b2, const float* __restrict__ W3,
        const float* __restrict__ b3,
        float* __restrict__ sbuf, int* __restrict__ counts,
        float* __restrict__ minmax, int E){
  __shared__ float lb2[8], lw3[8];
  __shared__ float lb3;
  __shared__ float rmin[4], rmax[4];
  int t = threadIdx.x;
  if (t < 8){ lb2[t] = b2[t]; lw3[t] = W3[t]; }
  if (t == 8) lb3 = b3[0];
  __syncthreads();
  int e = blockIdx.x*blockDim.x + t;
  float s = 0.f;
  bool valid = (e < E);
  if (valid){
    int a = src[e], b = dst[e];
    float4 us0 = ((const float4*)(u_s + (size_t)a*8))[0];
    float4 us1 = ((const float4*)(u_s + (size_t)a*8))[1];
    float4 ud0 = ((const float4*)(u_d + (size_t)b*8))[0];
    float4 ud1 = ((const float4*)(u_d + (size_t)b*8))[1];
    float tv[8] = { us0.x+ud0.x, us0.y+ud0.y, us0.z+ud0.z, us0.w+ud0.w,
                    us1.x+ud1.x, us1.y+ud1.y, us1.z+ud1.z, us1.w+ud1.w };
    s = lb3;
    #pragma unroll
    for (int j = 0; j < 8; j++) s += fmaxf(tv[j] + lb2[j], 0.f)*lw3[j];
    sbuf[e] = s;
    atomicAdd(&counts[b], 1);
  }
  float vmin = valid ? s : FINF;
  float vmax = valid ? s : -FINF;
  #pragma unroll
  for (int o = 32; o > 0; o >>= 1){
    vmin = fminf(vmin, __shfl_xor(vmin, o));
    vmax = fmaxf(vmax, __shfl_xor(vmax, o));
  }
  if ((t & 63) == 0){ rmin[t >> 6] = vmin; rmax[t >> 6] = vmax; }
  __syncthreads();
  if (t == 0){
    float mn = fminf(fminf(rmin[0], rmin[1]), fminf(rmin[2], rmin[3]));
    float mx = fmaxf(fmaxf(rmax[0], rmax[1]), fmaxf(rmax[2], rmax[3]));
    atomicMinF(&minmax[0], mn);
    atomicMaxF(&minmax[1], mx);
  }
}

// exclusive scan of counts -> indptr; counts becomes the scatter cursor
__global__ __launch_bounds__(1024) void k_scan(int* __restrict__ counts,
                                               int* __restrict__ indptr, int N){
  __shared__ int tot[1024];
  int t = threadIdx.x;
  int per = (N + 1023) / 1024;
  int beg = t*per;
  int end = min(beg + per, N);
  int sum = 0;
  for (int i = beg; i < end; i++) sum += counts[i];
  tot[t] = sum;
  __syncthreads();
  for (int o = 1; o < 1024; o <<= 1){
    int v = (t >= o) ? tot[t - o] : 0;
    __syncthreads();
    tot[t] += v;
    __syncthreads();
  }
  int run = (t == 0) ? 0 : tot[t-1];
  for (int i = beg; i < end; i++){
    int c = counts[i];
    indptr[i] = run;
    counts[i] = run;   // cursor for scatter
    run += c;
  }
  if (t == 1023) indptr[N] = run;
}

// fused gate-normalize + CSR scatter: emits dst-sorted srcs[] and gate[] (gs),
// and writes the normalized gate output.
__global__ void k_scatter(const int* __restrict__ src, const int* __restrict__ dst,
                          const float* __restrict__ sbuf, const float* __restrict__ minmax,
                          float* __restrict__ gate_out, int* __restrict__ cursor,
                          int* __restrict__ srcs, float* __restrict__ gs, int E){
  int e = blockIdx.x*blockDim.x + threadIdx.x;
  if (e >= E) return;
  float mn = minmax[0], mx = minmax[1];
  float g = (sbuf[e] - mn) / (mx - mn);
  gate_out[e] = g;
  int pos = atomicAdd(&cursor[dst[e]], 1);
  srcs[pos] = src[e];
  gs[pos] = g;
}

// layer1 segment softmax: one thread per (dst,head). Writes ap[j*8+h]=exp(v-m)
// in CSR order and invden1[n*8+h].
__global__ void k_alpha1(const int* __restrict__ indptr, const int* __restrict__ srcs,
                         const float* __restrict__ gs, const float* __restrict__ es1,
                         const float* __restrict__ ed1, float* __restrict__ ap,
                         float* __restrict__ invden, int N){
  int i = blockIdx.x*blockDim.x + threadIdx.x;
  if (i >= N*8) return;
  int n = i >> 3, hh = i & 7;
  int beg = indptr[n], end = indptr[n+1];
  float ed = ed1[i];
  float m = -FINF;
  for (int j = beg; j < end; j++){
    int a = srcs[j];
    float v = leaky(es1[a*8 + hh] + ed) * gs[j];
    ap[(size_t)j*8 + hh] = v;
    m = fmaxf(m, v);
  }
  float den = 0.f;
  for (int j = beg; j < end; j++){
    float w = __expf(ap[(size_t)j*8 + hh] - m);
    ap[(size_t)j*8 + hh] = w;
    den += w;
  }
  invden[i] = 1.f / fmaxf(den, 1e-12f);
}

// layer1 aggregation: one wave per dst node, float4 per lane (64x16B = 1KB row)
__global__ __launch_bounds__(256) void k_gather1v(const int* __restrict__ indptr,
        const int* __restrict__ srcs, const float* __restrict__ ap,
        const float* __restrict__ invden, const float* __restrict__ z1,
        float* __restrict__ hA, int N){
  int t = threadIdx.x;
  int n = blockIdx.x*4 + (t >> 6);
  if (n >= N) return;
  int lane = t & 63;
  int hh = lane >> 3;
  int beg = indptr[n], end = indptr[n+1];
  float4 acc = make_float4(0.f,0.f,0.f,0.f);
  for (int j = beg; j < end; j++){
    int a = srcs[j];
    float w = ap[(size_t)j*8 + hh];
    float4 z = ((const float4*)(z1 + (size_t)a*256))[lane];
    acc.x += w*z.x; acc.y += w*z.y; acc.z += w*z.z; acc.w += w*z.w;
  }
  float iv = invden[n*8 + hh];
  float4 o;
  o.x = leaky(acc.x*iv); o.y = leaky(acc.y*iv);
  o.z = leaky(acc.z*iv); o.w = leaky(acc.w*iv);
  ((float4*)(hA + (size_t)n*256))[lane] = o;
}

// z2 = hA @ fc2   [N,256]x[256,64]
__global__ __launch_bounds__(256) void k_z2(const float* __restrict__ hA,
        const float* __restrict__ fc2, float* __restrict__ z2, int N){
  __shared__ float hs[32][256];
  int t = threadIdx.x;
  int n0 = blockIdx.x*32;
  const float4* a4 = (const float4*)(hA + (size_t)n0*256);
  float4* hs4 = (float4*)&hs[0][0];
  #pragma unroll
  for (int i = 0; i < 8; i++){
    int idx = t + i*256;
    int row = idx >> 6;
    if (n0 + row < N) hs4[idx] = a4[idx];
    else hs4[idx] = make_float4(0.f,0.f,0.f,0.f);
  }
  __syncthreads();
  int col = t & 63, grp = t >> 6;
  float acc[8];
  #pragma unroll
  for (int i = 0; i < 8; i++) acc[i] = 0.f;
  const float* wb = fc2 + col;
  for (int k = 0; k < 256; k++){
    float wv = wb[(size_t)k*64];
    #pragma unroll
    for (int i = 0; i < 8; i++) acc[i] += hs[grp*8 + i][k]*wv;
  }
  #pragma unroll
  for (int i = 0; i < 8; i++){
    int node = n0 + grp*8 + i;
    if (node < N) z2[(size_t)node*64 + col] = acc[i];
  }
}

__global__ void k_es_ed2(const float* __restrict__ z2, const float* __restrict__ a2s,
                         const float* __restrict__ a2d, float* __restrict__ es2,
                         float* __restrict__ ed2, int N){
  int n = blockIdx.x*blockDim.x + threadIdx.x;
  if (n >= N) return;
  const float* zr = z2 + (size_t)n*64;
  float s0 = 0.f, s1 = 0.f;
  #pragma unroll 8
  for (int o = 0; o < 64; o++){ float zv = zr[o]; s0 += zv*a2s[o]; s1 += zv*a2d[o]; }
  es2[n] = s0; ed2[n] = s1;
}

// layer2 segment softmax: one thread per dst node
__global__ void k_alpha2(const int* __restrict__ indptr, const int* __restrict__ srcs,
                         const float* __restrict__ gs, const float* __restrict__ es2,
                         const float* __restrict__ ed2, float* __restrict__ ap2,
                         float* __restrict__ invden2, int N){
  int n = blockIdx.x*blockDim.x + threadIdx.x;
  if (n >= N) return;
  int beg = indptr[n], end = indptr[n+1];
  float ed = ed2[n];
  float m = -FINF;
  for (int j = beg; j < end; j++){
    float v = leaky(es2[srcs[j]] + ed) * gs[j];
    ap2[j] = v;
    m = fmaxf(m, v);
  }
  float den = 0.f;
  for (int j = beg; j < end; j++){
    float w = __expf(ap2[j] - m);
    ap2[j] = w;
    den += w;
  }
  invden2[n] = 1.f / fmaxf(den, 1e-12f);
}

// layer2 aggregation: one wave per dst node, scalar lane per dim (64x4B = 256B row)
__global__ __launch_bounds__(256) void k_gather2v(const int* __restrict__ indptr,
        const int* __restrict__ srcs, const float* __restrict__ ap2,
        const float* __restrict__ invden2, const float* __restrict__ z2,
        float* __restrict__ hB, int N){
  int t = threadIdx.x;
  int n = blockIdx.x*4 + (t >> 6);
  if (n >= N) return;
  int lane = t & 63;
  int beg = indptr[n], end = indptr[n+1];
  float acc = 0.f;
  for (int j = beg; j < end; j++){
    int a = srcs[j];
    acc += ap2[j] * z2[(size_t)a*64 + lane];
  }
  hB[(size_t)n*64 + lane] = acc * invden2[n];
}

// per-node split of edge predictor: ps = hB@Wp[0:64], pd = hB@Wp[64:128]
__global__ __launch_bounds__(256) void k_ppred(const float* __restrict__ hB,
        const float* __restrict__ Wp, float* __restrict__ ps,
        float* __restrict__ pd, int N){
  __shared__ float lwp[256];
  int t = threadIdx.x;
  lwp[t] = Wp[t];
  __syncthreads();
  int n = blockIdx.x*256 + t;
  if (n >= N) return;
  const float4* r = (const float4*)(hB + (size_t)n*64);
  float s0 = 0.f, s1 = 0.f, d0 = 0.f, d1 = 0.f;
  #pragma unroll
  for (int q = 0; q < 16; q++){
    float4 v = r[q];
    int k = q*4;
    s0 += v.x*lwp[(k+0)*2]   + v.y*lwp[(k+1)*2]   + v.z*lwp[(k+2)*2]   + v.w*lwp[(k+3)*2];
    s1 += v.x*lwp[(k+0)*2+1] + v.y*lwp[(k+1)*2+1] + v.z*lwp[(k+2)*2+1] + v.w*lwp[(k+3)*2+1];
    d0 += v.x*lwp[128+(k+0)*2]   + v.y*lwp[128+(k+1)*2]   + v.z*lwp[128+(k+2)*2]   + v.w*lwp[128+(k+3)*2];
    d1 += v.x*lwp[128+(k+0)*2+1] + v.y*lwp[128+(k+1)*2+1] + v.z*lwp[128+(k+2)*2+1] + v.w*lwp[128+(k+3)*2+1];
  }
  ps[(size_t)n*2]   = s0; ps[(size_t)n*2+1] = s1;
  pd[(size_t)n*2]   = d0; pd[(size_t)n*2+1] = d1;
}

__global__ void k_edgepred(const int* __restrict__ src, const int* __restrict__ dst,
                           const float* __restrict__ ps, const float* __restrict__ pd,
                           const float* __restrict__ bp, float* __restrict__ out, int E){
  int e = blockIdx.x*blockDim.x + threadIdx.x;
  if (e >= E) return;
  int a = src[e], b = dst[e];
  float2 vs = ((const float2*)ps)[a];
  float2 vd = ((const float2*)pd)[b];
  float2 o;
  o.x = vs.x + vd.x + bp[0];
  o.y = vs.y + vd.y + bp[1];
  ((float2*)out)[e] = o;
}

extern "C" void kernel_launch(void* const* d_in, const int* in_sizes, int n_in,
                              void* d_out, int out_size, void* d_ws, size_t ws_size,
                              hipStream_t stream) {
  const float* h   = (const float*)d_in[0];
  const int*   src = (const int*)d_in[1];
  const int*   dst = (const int*)d_in[2];
  const float* W1  = (const float*)d_in[3];
  const float* b1  = (const float*)d_in[4];
  const float* W2  = (const float*)d_in[5];
  const float* b2  = (const float*)d_in[6];
  const float* W3  = (const float*)d_in[7];
  const float* b3  = (const float*)d_in[8];
  const float* fc1 = (const float*)d_in[9];
  const float* a1s = (const float*)d_in[10];
  const float* a1d = (const float*)d_in[11];
  const float* fc2 = (const float*)d_in[12];
  const float* a2s = (const float*)d_in[13];
  const float* a2d = (const float*)d_in[14];
  const float* Wp  = (const float*)d_in[15];
  const float* bp  = (const float*)d_in[16];

  const int N = in_sizes[0] / 128;
  const int E = in_sizes[1];

  float* out_score = (float*)d_out;             // [E,2]
  float* gate      = out_score + (size_t)E*2;   // [E]

  char* w = (char*)d_ws;
  size_t off = 0;
  auto alloc = [&](size_t bytes) -> void* {
    off = (off + 255) & ~(size_t)255;
    void* p = w + off; off += bytes; return p;
  };
  float* h1   = (float*)alloc((size_t)N*16*4);
  float* u_s  = (float*)alloc((size_t)N*8*4);
  float* u_d  = (float*)alloc((size_t)N*8*4);
  float* z1   = (float*)alloc((size_t)N*256*4);
  float* es1  = (float*)alloc((size_t)N*8*4);
  float* ed1  = (float*)alloc((size_t)N*8*4);
  float* sbuf = (float*)alloc((size_t)E*4);
  float* hA   = (float*)alloc((size_t)N*256*4);
  float* ap   = (float*)alloc((size_t)E*8*4);   // layer1 softmax numerators (CSR order)
  float* invden1 = (float*)alloc((size_t)N*8*4);
  float* es2  = (float*)alloc((size_t)N*4);
  float* ed2  = (float*)alloc((size_t)N*4);
  float* invden2 = (float*)alloc((size_t)N*4);
  float* minmax = (float*)alloc(2*4);
  int* counts = (int*)alloc((size_t)N*4);
  int* indptr = (int*)alloc(((size_t)N+1)*4);
  int* srcs   = (int*)alloc((size_t)E*4);
  float* gs   = (float*)alloc((size_t)E*4);
  (void)ws_size; (void)n_in; (void)out_size;

  // reuse: z1 dead after gather1v -> z2/hB live there; ap dead after gather1v -> ap2;
  // u_s/u_d dead after gate_edge -> ps/pd live there.
  float* z2  = z1;                   // [N,64]
  float* hB  = z1 + (size_t)N*64;    // [N,64]
  float* ap2 = ap;                   // [E]
  float* ps  = u_s;                  // [N,2]
  float* pd  = u_d;                  // [N,2]

  k_init<<<(N + 255)/256, 256, 0, stream>>>(counts, minmax, N);
  k_h1<<<(N*16 + 255)/256, 256, 0, stream>>>(h, W1, b1, h1, N);
  k_u<<<(N*16 + 255)/256, 256, 0, stream>>>(h1, W2, u_s, u_d, N);
  k_z1<<<(N + 31)/32, 256, 0, stream>>>(h, fc1, z1, N);
  k_es_ed1<<<(N*8 + 255)/256, 256, 0, stream>>>(z1, a1s, a1d, es1, ed1, N);
  k_gate_edge<<<(E + 255)/256, 256, 0, stream>>>(u_s, u_d, src, dst, b2, W3, b3,
                                                 sbuf, counts, minmax, E);
  k_scan<<<1, 1024, 0, stream>>>(counts, indptr, N);
  k_scatter<<<(E + 255)/256, 256, 0, stream>>>(src, dst, sbuf, minmax, gate,
                                               counts, srcs, gs, E);
  k_alpha1<<<(N*8 + 255)/256, 256, 0, stream>>>(indptr, srcs, gs, es1, ed1,
                                                ap, invden1, N);
  k_gather1v<<<(N + 3)/4, 256, 0, stream>>>(indptr, srcs, ap, invden1, z1, hA, N);
  k_z2<<<(N + 31)/32, 256, 0, stream>>>(hA, fc2, z2, N);
  k_es_ed2<<<(N + 255)/256, 256, 0, stream>>>(z2, a2s, a2d, es2, ed2, N);
  k_alpha2<<<(N + 255)/256, 256, 0, stream>>>(indptr, srcs, gs, es2, ed2,
                                              ap2, invden2, N);
  k_gather2v<<<(N + 3)/4, 256, 0, stream>>>(indptr, srcs, ap2, invden2, z2, hB, N);
  k_ppred<<<(N + 255)/256, 256, 0, stream>>>(hB, Wp, ps, pd, N);
  k_edgepred<<<(E + 255)/256, 256, 0, stream>>>(src, dst, ps, pd, bp, out_score, E);
}

// Round 4
// 681.742 us; speedup vs baseline: 1.8827x; 1.0663x over previous
//
#include <hip/hip_runtime.h>
#include <math.h>

#define FINF __builtin_inff()

__device__ __forceinline__ float leaky(float x){ return x > 0.f ? x : 0.01f*x; }

__device__ __forceinline__ void atomicMaxF(float* a, float v){
  if (v >= 0.f) atomicMax((int*)a, __float_as_int(v));
  else          atomicMin((unsigned int*)a, __float_as_uint(v));
}
__device__ __forceinline__ void atomicMinF(float* a, float v){
  if (v >= 0.f) atomicMin((int*)a, __float_as_int(v));
  else          atomicMax((unsigned int*)a, __float_as_uint(v));
}

__global__ void k_init(int* counts, float* minmax, int N){
  int i = blockIdx.x*blockDim.x + threadIdx.x;
  if (i < N) counts[i] = 0;
  if (i == 0){ minmax[0] = FINF; minmax[1] = -FINF; }
}

// h1 = h @ W1 + b1   [N,16]
__global__ void k_h1(const float* __restrict__ h, const float* __restrict__ W1,
                     const float* __restrict__ b1, float* __restrict__ h1, int N){
  int i = blockIdx.x*blockDim.x + threadIdx.x;
  if (i >= N*16) return;
  int n = i >> 4, j = i & 15;
  float s = b1[j];
  const float* hr = h + (size_t)n*128;
  #pragma unroll 8
  for (int k = 0; k < 128; k++) s += hr[k]*W1[k*16 + j];
  h1[i] = s;
}

// per-node split of gate-MLP layer 2 (pre-ReLU): u_s = h1@W2[0:16], u_d = h1@W2[16:32]
__global__ void k_u(const float* __restrict__ h1, const float* __restrict__ W2,
                    float* __restrict__ u_s, float* __restrict__ u_d, int N){
  int i = blockIdx.x*blockDim.x + threadIdx.x;
  if (i >= N*16) return;
  int n = i >> 4, j = i & 15;
  const float* hr = h1 + (size_t)n*16;
  if (j < 8){
    float s = 0.f;
    #pragma unroll
    for (int k = 0; k < 16; k++) s += hr[k]*W2[k*8 + j];
    u_s[n*8 + j] = s;
  } else {
    j -= 8;
    float s = 0.f;
    #pragma unroll
    for (int k = 0; k < 16; k++) s += hr[k]*W2[(16 + k)*8 + j];
    u_d[n*8 + j] = s;
  }
}

// z1 = h @ fc1  [N,128]x[128,256], register-blocked: thread = 16 rows x 4 cols.
// Wave-uniform row-group => every hs read is a same-address broadcast (no bank
// conflicts); each LDS float4 feeds 16 FMAs.
__global__ __launch_bounds__(256) void k_z1(const float* __restrict__ h,
        const float* __restrict__ fc1, float* __restrict__ z1, int N){
  __shared__ float hs[64][128];
  int t = threadIdx.x;
  int n0 = blockIdx.x * 64;
  const float4* h4 = (const float4*)(h + (size_t)n0*128);
  float4* hs4 = (float4*)&hs[0][0];
  #pragma unroll
  for (int i = 0; i < 8; i++){
    int idx = t + i*256;          // 0..2047 float4 slots (32 per row)
    int row = idx >> 5;
    hs4[idx] = (n0 + row < N) ? h4[idx] : make_float4(0.f,0.f,0.f,0.f);
  }
  __syncthreads();
  int cg = t & 63, rg = t >> 6;   // rg uniform within a wave
  int o0 = cg*4, m0 = rg*16;
  int hh = o0 >> 5, ob = o0 & 31;
  const float* wb = fc1 + (size_t)hh*4096 + ob;   // fc1[h][k][o]
  float acc[16][4];
  #pragma unroll
  for (int m = 0; m < 16; m++)
    acc[m][0] = acc[m][1] = acc[m][2] = acc[m][3] = 0.f;
  for (int k = 0; k < 128; k += 4){
    float4 w0 = *(const float4*)(wb + (size_t)(k+0)*32);
    float4 w1 = *(const float4*)(wb + (size_t)(k+1)*32);
    float4 w2 = *(const float4*)(wb + (size_t)(k+2)*32);
    float4 w3 = *(const float4*)(wb + (size_t)(k+3)*32);
    #pragma unroll
    for (int m = 0; m < 16; m++){
      float4 hv = *(const float4*)(&hs[m0 + m][k]);
      acc[m][0] += hv.x*w0.x + hv.y*w1.x + hv.z*w2.x + hv.w*w3.x;
      acc[m][1] += hv.x*w0.y + hv.y*w1.y + hv.z*w2.y + hv.w*w3.y;
      acc[m][2] += hv.x*w0.z + hv.y*w1.z + hv.z*w2.z + hv.w*w3.z;
      acc[m][3] += hv.x*w0.w + hv.y*w1.w + hv.z*w2.w + hv.w*w3.w;
    }
  }
  #pragma unroll
  for (int m = 0; m < 16; m++){
    int node = n0 + m0 + m;
    if (node < N)
      *(float4*)(z1 + (size_t)node*256 + o0) =
          make_float4(acc[m][0], acc[m][1], acc[m][2], acc[m][3]);
  }
}

// es1/ed1[n,h] = dot(z1[n,h,:], a1_src/dst[h,:])
__global__ void k_es_ed1(const float* __restrict__ z1, const float* __restrict__ a1s,
                         const float* __restrict__ a1d, float* __restrict__ es1,
                         float* __restrict__ ed1, int N){
  int i = blockIdx.x*blockDim.x + threadIdx.x;
  if (i >= N*8) return;
  int n = i >> 3, hh = i & 7;
  const float* zr = z1 + (size_t)n*256 + hh*32;
  const float* as = a1s + hh*32;
  const float* ad = a1d + hh*32;
  float s0 = 0.f, s1 = 0.f;
  #pragma unroll
  for (int o = 0; o < 32; o++){ float zv = zr[o]; s0 += zv*as[o]; s1 += zv*ad[o]; }
  es1[i] = s0; ed1[i] = s1;
}

// gate edge score via per-node decomposition; also dst histogram + global min/max
__global__ __launch_bounds__(256) void k_gate_edge(const float* __restrict__ u_s,
        const float* __restrict__ u_d,
        const int* __restrict__ src, const int* __restrict__ dst,
        const float* __restrict__ b2, const float* __restrict__ W3,
        const float* __restrict__ b3,
        float* __restrict__ sbuf, int* __restrict__ counts,
        float* __restrict__ minmax, int E){
  __shared__ float lb2[8], lw3[8];
  __shared__ float lb3;
  __shared__ float rmin[4], rmax[4];
  int t = threadIdx.x;
  if (t < 8){ lb2[t] = b2[t]; lw3[t] = W3[t]; }
  if (t == 8) lb3 = b3[0];
  __syncthreads();
  int e = blockIdx.x*blockDim.x + t;
  float s = 0.f;
  bool valid = (e < E);
  if (valid){
    int a = src[e], b = dst[e];
    float4 us0 = ((const float4*)(u_s + (size_t)a*8))[0];
    float4 us1 = ((const float4*)(u_s + (size_t)a*8))[1];
    float4 ud0 = ((const float4*)(u_d + (size_t)b*8))[0];
    float4 ud1 = ((const float4*)(u_d + (size_t)b*8))[1];
    float tv[8] = { us0.x+ud0.x, us0.y+ud0.y, us0.z+ud0.z, us0.w+ud0.w,
                    us1.x+ud1.x, us1.y+ud1.y, us1.z+ud1.z, us1.w+ud1.w };
    s = lb3;
    #pragma unroll
    for (int j = 0; j < 8; j++) s += fmaxf(tv[j] + lb2[j], 0.f)*lw3[j];
    sbuf[e] = s;
    atomicAdd(&counts[b], 1);
  }
  float vmin = valid ? s : FINF;
  float vmax = valid ? s : -FINF;
  #pragma unroll
  for (int o = 32; o > 0; o >>= 1){
    vmin = fminf(vmin, __shfl_xor(vmin, o));
    vmax = fmaxf(vmax, __shfl_xor(vmax, o));
  }
  if ((t & 63) == 0){ rmin[t >> 6] = vmin; rmax[t >> 6] = vmax; }
  __syncthreads();
  if (t == 0){
    float mn = fminf(fminf(rmin[0], rmin[1]), fminf(rmin[2], rmin[3]));
    float mx = fmaxf(fmaxf(rmax[0], rmax[1]), fmaxf(rmax[2], rmax[3]));
    atomicMinF(&minmax[0], mn);
    atomicMaxF(&minmax[1], mx);
  }
}

// exclusive scan of counts -> indptr; counts becomes the scatter cursor
__global__ __launch_bounds__(1024) void k_scan(int* __restrict__ counts,
                                               int* __restrict__ indptr, int N){
  __shared__ int tot[1024];
  int t = threadIdx.x;
  int per = (N + 1023) / 1024;
  int beg = t*per;
  int end = min(beg + per, N);
  int sum = 0;
  for (int i = beg; i < end; i++) sum += counts[i];
  tot[t] = sum;
  __syncthreads();
  for (int o = 1; o < 1024; o <<= 1){
    int v = (t >= o) ? tot[t - o] : 0;
    __syncthreads();
    tot[t] += v;
    __syncthreads();
  }
  int run = (t == 0) ? 0 : tot[t-1];
  for (int i = beg; i < end; i++){
    int c = counts[i];
    indptr[i] = run;
    counts[i] = run;   // cursor for scatter
    run += c;
  }
  if (t == 1023) indptr[N] = run;
}

// fused gate-normalize + CSR scatter
__global__ void k_scatter(const int* __restrict__ src, const int* __restrict__ dst,
                          const float* __restrict__ sbuf, const float* __restrict__ minmax,
                          float* __restrict__ gate_out, int* __restrict__ cursor,
                          int* __restrict__ srcs, float* __restrict__ gs, int E){
  int e = blockIdx.x*blockDim.x + threadIdx.x;
  if (e >= E) return;
  float mn = minmax[0], mx = minmax[1];
  float g = (sbuf[e] - mn) / (mx - mn);
  gate_out[e] = g;
  int pos = atomicAdd(&cursor[dst[e]], 1);
  srcs[pos] = src[e];
  gs[pos] = g;
}

// layer1 segment softmax: one thread per (dst,head)
__global__ void k_alpha1(const int* __restrict__ indptr, const int* __restrict__ srcs,
                         const float* __restrict__ gs, const float* __restrict__ es1,
                         const float* __restrict__ ed1, float* __restrict__ ap,
                         float* __restrict__ invden, int N){
  int i = blockIdx.x*blockDim.x + threadIdx.x;
  if (i >= N*8) return;
  int n = i >> 3, hh = i & 7;
  int beg = indptr[n], end = indptr[n+1];
  float ed = ed1[i];
  float m = -FINF;
  for (int j = beg; j < end; j++){
    int a = srcs[j];
    float v = leaky(es1[a*8 + hh] + ed) * gs[j];
    ap[(size_t)j*8 + hh] = v;
    m = fmaxf(m, v);
  }
  float den = 0.f;
  for (int j = beg; j < end; j++){
    float w = __expf(ap[(size_t)j*8 + hh] - m);
    ap[(size_t)j*8 + hh] = w;
    den += w;
  }
  invden[i] = 1.f / fmaxf(den, 1e-12f);
}

// layer1 aggregation: one wave per dst node, float4 per lane (64x16B = 1KB row)
__global__ __launch_bounds__(256) void k_gather1v(const int* __restrict__ indptr,
        const int* __restrict__ srcs, const float* __restrict__ ap,
        const float* __restrict__ invden, const float* __restrict__ z1,
        float* __restrict__ hA, int N){
  int t = threadIdx.x;
  int n = blockIdx.x*4 + (t >> 6);
  if (n >= N) return;
  int lane = t & 63;
  int hh = lane >> 3;
  int beg = indptr[n], end = indptr[n+1];
  float4 acc = make_float4(0.f,0.f,0.f,0.f);
  for (int j = beg; j < end; j++){
    int a = srcs[j];
    float w = ap[(size_t)j*8 + hh];
    float4 z = ((const float4*)(z1 + (size_t)a*256))[lane];
    acc.x += w*z.x; acc.y += w*z.y; acc.z += w*z.z; acc.w += w*z.w;
  }
  float iv = invden[n*8 + hh];
  float4 o;
  o.x = leaky(acc.x*iv); o.y = leaky(acc.y*iv);
  o.z = leaky(acc.z*iv); o.w = leaky(acc.w*iv);
  ((float4*)(hA + (size_t)n*256))[lane] = o;
}

// z2 = hA @ fc2  [N,256]x[256,64], register-blocked: thread = 8 rows x 2 cols,
// K staged in two 128-chunks. 2-way LDS address aliasing across half-waves is free.
__global__ __launch_bounds__(256) void k_z2(const float* __restrict__ hA,
        const float* __restrict__ fc2, float* __restrict__ z2, int N){
  __shared__ float hs[64][128];
  int t = threadIdx.x;
  int n0 = blockIdx.x * 64;
  int cg = t & 31, rg = t >> 5;
  int o0 = cg*2, m0 = rg*8;
  float acc[8][2];
  #pragma unroll
  for (int m = 0; m < 8; m++) acc[m][0] = acc[m][1] = 0.f;
  for (int kc = 0; kc < 2; kc++){
    const float* base = hA + (size_t)n0*256 + kc*128;
    #pragma unroll
    for (int i = 0; i < 8; i++){
      int idx = t + i*256;           // 0..2047 float4 slots (32 per row)
      int row = idx >> 5, c4 = idx & 31;
      float4 v = (n0 + row < N) ? *(const float4*)(base + (size_t)row*256 + c4*4)
                                : make_float4(0.f,0.f,0.f,0.f);
      *(float4*)(&hs[row][c4*4]) = v;
    }
    __syncthreads();
    const float* wp = fc2 + (size_t)(kc*128)*64 + o0;
    for (int k = 0; k < 128; k += 4){
      float2 w0 = *(const float2*)(wp + (size_t)(k+0)*64);
      float2 w1 = *(const float2*)(wp + (size_t)(k+1)*64);
      float2 w2 = *(const float2*)(wp + (size_t)(k+2)*64);
      float2 w3 = *(const float2*)(wp + (size_t)(k+3)*64);
      #pragma unroll
      for (int m = 0; m < 8; m++){
        float4 hv = *(const float4*)(&hs[m0 + m][k]);
        acc[m][0] += hv.x*w0.x + hv.y*w1.x + hv.z*w2.x + hv.w*w3.x;
        acc[m][1] += hv.x*w0.y + hv.y*w1.y + hv.z*w2.y + hv.w*w3.y;
      }
    }
    __syncthreads();
  }
  #pragma unroll
  for (int m = 0; m < 8; m++){
    int node = n0 + m0 + m;
    if (node < N)
      *(float2*)(z2 + (size_t)node*64 + o0) = make_float2(acc[m][0], acc[m][1]);
  }
}

__global__ void k_es_ed2(const float* __restrict__ z2, const float* __restrict__ a2s,
                         const float* __restrict__ a2d, float* __restrict__ es2,
                         float* __restrict__ ed2, int N){
  int n = blockIdx.x*blockDim.x + threadIdx.x;
  if (n >= N) return;
  const float* zr = z2 + (size_t)n*64;
  float s0 = 0.f, s1 = 0.f;
  #pragma unroll 8
  for (int o = 0; o < 64; o++){ float zv = zr[o]; s0 += zv*a2s[o]; s1 += zv*a2d[o]; }
  es2[n] = s0; ed2[n] = s1;
}

// layer2 segment softmax: one thread per dst node
__global__ void k_alpha2(const int* __restrict__ indptr, const int* __restrict__ srcs,
                         const float* __restrict__ gs, const float* __restrict__ es2,
                         const float* __restrict__ ed2, float* __restrict__ ap2,
                         float* __restrict__ invden2, int N){
  int n = blockIdx.x*blockDim.x + threadIdx.x;
  if (n >= N) return;
  int beg = indptr[n], end = indptr[n+1];
  float ed = ed2[n];
  float m = -FINF;
  for (int j = beg; j < end; j++){
    float v = leaky(es2[srcs[j]] + ed) * gs[j];
    ap2[j] = v;
    m = fmaxf(m, v);
  }
  float den = 0.f;
  for (int j = beg; j < end; j++){
    float w = __expf(ap2[j] - m);
    ap2[j] = w;
    den += w;
  }
  invden2[n] = 1.f / fmaxf(den, 1e-12f);
}

// layer2 aggregation: one wave per dst node, scalar lane per dim (64x4B = 256B row)
__global__ __launch_bounds__(256) void k_gather2v(const int* __restrict__ indptr,
        const int* __restrict__ srcs, const float* __restrict__ ap2,
        const float* __restrict__ invden2, const float* __restrict__ z2,
        float* __restrict__ hB, int N){
  int t = threadIdx.x;
  int n = blockIdx.x*4 + (t >> 6);
  if (n >= N) return;
  int lane = t & 63;
  int beg = indptr[n], end = indptr[n+1];
  float acc = 0.f;
  for (int j = beg; j < end; j++){
    int a = srcs[j];
    acc += ap2[j] * z2[(size_t)a*64 + lane];
  }
  hB[(size_t)n*64 + lane] = acc * invden2[n];
}

// per-node split of edge predictor: ps = hB@Wp[0:64], pd = hB@Wp[64:128]
__global__ __launch_bounds__(256) void k_ppred(const float* __restrict__ hB,
        const float* __restrict__ Wp, float* __restrict__ ps,
        float* __restrict__ pd, int N){
  __shared__ float lwp[256];
  int t = threadIdx.x;
  lwp[t] = Wp[t];
  __syncthreads();
  int n = blockIdx.x*256 + t;
  if (n >= N) return;
  const float4* r = (const float4*)(hB + (size_t)n*64);
  float s0 = 0.f, s1 = 0.f, d0 = 0.f, d1 = 0.f;
  #pragma unroll
  for (int q = 0; q < 16; q++){
    float4 v = r[q];
    int k = q*4;
    s0 += v.x*lwp[(k+0)*2]   + v.y*lwp[(k+1)*2]   + v.z*lwp[(k+2)*2]   + v.w*lwp[(k+3)*2];
    s1 += v.x*lwp[(k+0)*2+1] + v.y*lwp[(k+1)*2+1] + v.z*lwp[(k+2)*2+1] + v.w*lwp[(k+3)*2+1];
    d0 += v.x*lwp[128+(k+0)*2]   + v.y*lwp[128+(k+1)*2]   + v.z*lwp[128+(k+2)*2]   + v.w*lwp[128+(k+3)*2];
    d1 += v.x*lwp[128+(k+0)*2+1] + v.y*lwp[128+(k+1)*2+1] + v.z*lwp[128+(k+2)*2+1] + v.w*lwp[128+(k+3)*2+1];
  }
  ps[(size_t)n*2]   = s0; ps[(size_t)n*2+1] = s1;
  pd[(size_t)n*2]   = d0; pd[(size_t)n*2+1] = d1;
}

__global__ void k_edgepred(const int* __restrict__ src, const int* __restrict__ dst,
                           const float* __restrict__ ps, const float* __restrict__ pd,
                           const float* __restrict__ bp, float* __restrict__ out, int E){
  int e = blockIdx.x*blockDim.x + threadIdx.x;
  if (e >= E) return;
  int a = src[e], b = dst[e];
  float2 vs = ((const float2*)ps)[a];
  float2 vd = ((const float2*)pd)[b];
  float2 o;
  o.x = vs.x + vd.x + bp[0];
  o.y = vs.y + vd.y + bp[1];
  ((float2*)out)[e] = o;
}

extern "C" void kernel_launch(void* const* d_in, const int* in_sizes, int n_in,
                              void* d_out, int out_size, void* d_ws, size_t ws_size,
                              hipStream_t stream) {
  const float* h   = (const float*)d_in[0];
  const int*   src = (const int*)d_in[1];
  const int*   dst = (const int*)d_in[2];
  const float* W1  = (const float*)d_in[3];
  const float* b1  = (const float*)d_in[4];
  const float* W2  = (const float*)d_in[5];
  const float* b2  = (const float*)d_in[6];
  const float* W3  = (const float*)d_in[7];
  const float* b3  = (const float*)d_in[8];
  const float* fc1 = (const float*)d_in[9];
  const float* a1s = (const float*)d_in[10];
  const float* a1d = (const float*)d_in[11];
  const float* fc2 = (const float*)d_in[12];
  const float* a2s = (const float*)d_in[13];
  const float* a2d = (const float*)d_in[14];
  const float* Wp  = (const float*)d_in[15];
  const float* bp  = (const float*)d_in[16];

  const int N = in_sizes[0] / 128;
  const int E = in_sizes[1];

  float* out_score = (float*)d_out;             // [E,2]
  float* gate      = out_score + (size_t)E*2;   // [E]

  char* w = (char*)d_ws;
  size_t off = 0;
  auto alloc = [&](size_t bytes) -> void* {
    off = (off + 255) & ~(size_t)255;
    void* p = w + off; off += bytes; return p;
  };
  float* h1   = (float*)alloc((size_t)N*16*4);
  float* u_s  = (float*)alloc((size_t)N*8*4);
  float* u_d  = (float*)alloc((size_t)N*8*4);
  float* z1   = (float*)alloc((size_t)N*256*4);
  float* es1  = (float*)alloc((size_t)N*8*4);
  float* ed1  = (float*)alloc((size_t)N*8*4);
  float* sbuf = (float*)alloc((size_t)E*4);
  float* hA   = (float*)alloc((size_t)N*256*4);
  float* ap   = (float*)alloc((size_t)E*8*4);   // layer1 softmax numerators (CSR order)
  float* invden1 = (float*)alloc((size_t)N*8*4);
  float* es2  = (float*)alloc((size_t)N*4);
  float* ed2  = (float*)alloc((size_t)N*4);
  float* invden2 = (float*)alloc((size_t)N*4);
  float* minmax = (float*)alloc(2*4);
  int* counts = (int*)alloc((size_t)N*4);
  int* indptr = (int*)alloc(((size_t)N+1)*4);
  int* srcs   = (int*)alloc((size_t)E*4);
  float* gs   = (float*)alloc((size_t)E*4);
  (void)ws_size; (void)n_in; (void)out_size;

  // reuse: z1 dead after gather1v -> z2/hB live there; ap dead after gather1v -> ap2;
  // u_s/u_d dead after gate_edge -> ps/pd live there.
  float* z2  = z1;                   // [N,64]
  float* hB  = z1 + (size_t)N*64;    // [N,64]
  float* ap2 = ap;                   // [E]
  float* ps  = u_s;                  // [N,2]
  float* pd  = u_d;                  // [N,2]

  k_init<<<(N + 255)/256, 256, 0, stream>>>(counts, minmax, N);
  k_h1<<<(N*16 + 255)/256, 256, 0, stream>>>(h, W1, b1, h1, N);
  k_u<<<(N*16 + 255)/256, 256, 0, stream>>>(h1, W2, u_s, u_d, N);
  k_z1<<<(N + 63)/64, 256, 0, stream>>>(h, fc1, z1, N);
  k_es_ed1<<<(N*8 + 255)/256, 256, 0, stream>>>(z1, a1s, a1d, es1, ed1, N);
  k_gate_edge<<<(E + 255)/256, 256, 0, stream>>>(u_s, u_d, src, dst, b2, W3, b3,
                                                 sbuf, counts, minmax, E);
  k_scan<<<1, 1024, 0, stream>>>(counts, indptr, N);
  k_scatter<<<(E + 255)/256, 256, 0, stream>>>(src, dst, sbuf, minmax, gate,
                                               counts, srcs, gs, E);
  k_alpha1<<<(N*8 + 255)/256, 256, 0, stream>>>(indptr, srcs, gs, es1, ed1,
                                                ap, invden1, N);
  k_gather1v<<<(N + 3)/4, 256, 0, stream>>>(indptr, srcs, ap, invden1, z1, hA, N);
  k_z2<<<(N + 63)/64, 256, 0, stream>>>(hA, fc2, z2, N);
  k_es_ed2<<<(N + 255)/256, 256, 0, stream>>>(z2, a2s, a2d, es2, ed2, N);
  k_alpha2<<<(N + 255)/256, 256, 0, stream>>>(indptr, srcs, gs, es2, ed2,
                                              ap2, invden2, N);
  k_gather2v<<<(N + 3)/4, 256, 0, stream>>>(indptr, srcs, ap2, invden2, z2, hB, N);
  k_ppred<<<(N + 255)/256, 256, 0, stream>>>(hB, Wp, ps, pd, N);
  k_edgepred<<<(E + 255)/256, 256, 0, stream>>>(src, dst, ps, pd, bp, out_score, E);
}

// Round 5
// 569.947 us; speedup vs baseline: 2.2520x; 1.1962x over previous
//
#include <hip/hip_runtime.h>
#include <math.h>

#define FINF __builtin_inff()

__device__ __forceinline__ float leaky(float x){ return x > 0.f ? x : 0.01f*x; }

__device__ __forceinline__ void atomicMaxF(float* a, float v){
  if (v >= 0.f) atomicMax((int*)a, __float_as_int(v));
  else          atomicMin((unsigned int*)a, __float_as_uint(v));
}
__device__ __forceinline__ void atomicMinF(float* a, float v){
  if (v >= 0.f) atomicMin((int*)a, __float_as_int(v));
  else          atomicMax((unsigned int*)a, __float_as_uint(v));
}

// fp32 -> bf16 (RNE) and pack two into a u32
__device__ __forceinline__ unsigned int f2bf(float f){
  unsigned int x = __float_as_uint(f);
  x += 0x7FFFu + ((x >> 16) & 1u);
  return x >> 16;
}
__device__ __forceinline__ unsigned int pack2(float lo, float hi){
  return f2bf(lo) | (f2bf(hi) << 16);
}
__device__ __forceinline__ float bflo(unsigned int u){ return __uint_as_float(u << 16); }
__device__ __forceinline__ float bfhi(unsigned int u){ return __uint_as_float(u & 0xFFFF0000u); }

__global__ void k_init(int* counts, float* minmax, int N){
  int i = blockIdx.x*blockDim.x + threadIdx.x;
  if (i < N) counts[i] = 0;
  if (i == 0){ minmax[0] = FINF; minmax[1] = -FINF; }
}

// fused: h1 = h@W1+b1 (LDS only), then u_s = h1@W2[0:16], u_d = h1@W2[16:32]
__global__ __launch_bounds__(256) void k_h1u(const float* __restrict__ h,
        const float* __restrict__ W1, const float* __restrict__ b1,
        const float* __restrict__ W2,
        float* __restrict__ u_s, float* __restrict__ u_d, int N){
  __shared__ float lh[16][132];   // padded: bank-conflict-free broadcast
  __shared__ float lw[128][16];
  __shared__ float lh1[16][17];
  int t = threadIdx.x;
  int n0 = blockIdx.x*16;
  const float4* w4 = (const float4*)W1;
  ((float4*)&lw[0][0])[t]       = w4[t];
  ((float4*)&lw[0][0])[t + 256] = w4[t + 256];
  const float4* h4 = (const float4*)(h + (size_t)n0*128);
  {
    int idx = t, row = idx >> 5, c4 = idx & 31;
    *(float4*)&lh[row][c4*4] = (n0+row < N) ? h4[idx] : make_float4(0,0,0,0);
    idx = t + 256; row = idx >> 5; c4 = idx & 31;
    *(float4*)&lh[row][c4*4] = (n0+row < N) ? h4[idx] : make_float4(0,0,0,0);
  }
  __syncthreads();
  int nl = t >> 4, j = t & 15;
  float s = b1[j];
  #pragma unroll 8
  for (int k = 0; k < 128; k++) s += lh[nl][k]*lw[k][j];
  lh1[nl][j] = s;
  __syncthreads();
  int n = n0 + nl;
  if (n < N){
    float acc = 0.f;
    if (j < 8){
      #pragma unroll
      for (int k = 0; k < 16; k++) acc += lh1[nl][k]*W2[k*8 + j];
      u_s[(size_t)n*8 + j] = acc;
    } else {
      int jj = j - 8;
      #pragma unroll
      for (int k = 0; k < 16; k++) acc += lh1[nl][k]*W2[(16 + k)*8 + jj];
      u_d[(size_t)n*8 + jj] = acc;
    }
  }
}

// z1 = h @ fc1 (reg-blocked 16x4), stored as bf16; es1/ed1 fused in epilogue
// from fp32 accumulators via 8-lane shfl reduce.
__global__ __launch_bounds__(256) void k_z1(const float* __restrict__ h,
        const float* __restrict__ fc1, const float* __restrict__ a1s,
        const float* __restrict__ a1d, unsigned int* __restrict__ z1b,
        float* __restrict__ es1, float* __restrict__ ed1, int N){
  __shared__ float hs[64][128];
  int t = threadIdx.x;
  int n0 = blockIdx.x * 64;
  const float4* h4 = (const float4*)(h + (size_t)n0*128);
  float4* hs4 = (float4*)&hs[0][0];
  #pragma unroll
  for (int i = 0; i < 8; i++){
    int idx = t + i*256;
    int row = idx >> 5;
    hs4[idx] = (n0 + row < N) ? h4[idx] : make_float4(0.f,0.f,0.f,0.f);
  }
  __syncthreads();
  int cg = t & 63, rg = t >> 6;
  int o0 = cg*4, m0 = rg*16;
  int hh = cg >> 3;
  const float* wb = fc1 + (size_t)hh*4096 + (o0 & 31);
  float acc[16][4];
  #pragma unroll
  for (int m = 0; m < 16; m++)
    acc[m][0] = acc[m][1] = acc[m][2] = acc[m][3] = 0.f;
  for (int k = 0; k < 128; k += 4){
    float4 w0 = *(const float4*)(wb + (size_t)(k+0)*32);
    float4 w1 = *(const float4*)(wb + (size_t)(k+1)*32);
    float4 w2 = *(const float4*)(wb + (size_t)(k+2)*32);
    float4 w3 = *(const float4*)(wb + (size_t)(k+3)*32);
    #pragma unroll
    for (int m = 0; m < 16; m++){
      float4 hv = *(const float4*)(&hs[m0 + m][k]);
      acc[m][0] += hv.x*w0.x + hv.y*w1.x + hv.z*w2.x + hv.w*w3.x;
      acc[m][1] += hv.x*w0.y + hv.y*w1.y + hv.z*w2.y + hv.w*w3.y;
      acc[m][2] += hv.x*w0.z + hv.y*w1.z + hv.z*w2.z + hv.w*w3.z;
      acc[m][3] += hv.x*w0.w + hv.y*w1.w + hv.z*w2.w + hv.w*w3.w;
    }
  }
  float4 as4 = *(const float4*)(a1s + hh*32 + (o0 & 31));
  float4 ad4 = *(const float4*)(a1d + hh*32 + (o0 & 31));
  #pragma unroll
  for (int m = 0; m < 16; m++){
    int node = n0 + m0 + m;
    if (node < N){
      uint2 pk;
      pk.x = pack2(acc[m][0], acc[m][1]);
      pk.y = pack2(acc[m][2], acc[m][3]);
      *(uint2*)(z1b + (size_t)node*128 + cg*2) = pk;
    }
    float s0 = acc[m][0]*as4.x + acc[m][1]*as4.y + acc[m][2]*as4.z + acc[m][3]*as4.w;
    float s1 = acc[m][0]*ad4.x + acc[m][1]*ad4.y + acc[m][2]*ad4.z + acc[m][3]*ad4.w;
    s0 += __shfl_xor(s0, 1); s1 += __shfl_xor(s1, 1);
    s0 += __shfl_xor(s0, 2); s1 += __shfl_xor(s1, 2);
    s0 += __shfl_xor(s0, 4); s1 += __shfl_xor(s1, 4);
    if ((cg & 7) == 0 && node < N){ es1[node*8 + hh] = s0; ed1[node*8 + hh] = s1; }
  }
}

// gate edge score via per-node decomposition; dst histogram + global min/max
__global__ __launch_bounds__(256) void k_gate_edge(const float* __restrict__ u_s,
        const float* __restrict__ u_d,
        const int* __restrict__ src, const int* __restrict__ dst,
        const float* __restrict__ b2, const float* __restrict__ W3,
        const float* __restrict__ b3,
        float* __restrict__ sbuf, int* __restrict__ counts,
        float* __restrict__ minmax, int E){
  __shared__ float lb2[8], lw3[8];
  __shared__ float lb3;
  __shared__ float rmin[4], rmax[4];
  int t = threadIdx.x;
  if (t < 8){ lb2[t] = b2[t]; lw3[t] = W3[t]; }
  if (t == 8) lb3 = b3[0];
  __syncthreads();
  int e = blockIdx.x*blockDim.x + t;
  float s = 0.f;
  bool valid = (e < E);
  if (valid){
    int a = src[e], b = dst[e];
    float4 us0 = ((const float4*)(u_s + (size_t)a*8))[0];
    float4 us1 = ((const float4*)(u_s + (size_t)a*8))[1];
    float4 ud0 = ((const float4*)(u_d + (size_t)b*8))[0];
    float4 ud1 = ((const float4*)(u_d + (size_t)b*8))[1];
    float tv[8] = { us0.x+ud0.x, us0.y+ud0.y, us0.z+ud0.z, us0.w+ud0.w,
                    us1.x+ud1.x, us1.y+ud1.y, us1.z+ud1.z, us1.w+ud1.w };
    s = lb3;
    #pragma unroll
    for (int j = 0; j < 8; j++) s += fmaxf(tv[j] + lb2[j], 0.f)*lw3[j];
    sbuf[e] = s;
    atomicAdd(&counts[b], 1);
  }
  float vmin = valid ? s : FINF;
  float vmax = valid ? s : -FINF;
  #pragma unroll
  for (int o = 32; o > 0; o >>= 1){
    vmin = fminf(vmin, __shfl_xor(vmin, o));
    vmax = fmaxf(vmax, __shfl_xor(vmax, o));
  }
  if ((t & 63) == 0){ rmin[t >> 6] = vmin; rmax[t >> 6] = vmax; }
  __syncthreads();
  if (t == 0){
    float mn = fminf(fminf(rmin[0], rmin[1]), fminf(rmin[2], rmin[3]));
    float mx = fmaxf(fmaxf(rmax[0], rmax[1]), fmaxf(rmax[2], rmax[3]));
    atomicMinF(&minmax[0], mn);
    atomicMaxF(&minmax[1], mx);
  }
}

// exclusive scan of counts -> indptr; counts becomes the scatter cursor
__global__ __launch_bounds__(1024) void k_scan(int* __restrict__ counts,
                                               int* __restrict__ indptr, int N){
  __shared__ int tot[1024];
  int t = threadIdx.x;
  int per = (N + 1023) / 1024;
  int beg = t*per;
  int end = min(beg + per, N);
  int sum = 0;
  for (int i = beg; i < end; i++) sum += counts[i];
  tot[t] = sum;
  __syncthreads();
  for (int o = 1; o < 1024; o <<= 1){
    int v = (t >= o) ? tot[t - o] : 0;
    __syncthreads();
    tot[t] += v;
    __syncthreads();
  }
  int run = (t == 0) ? 0 : tot[t-1];
  for (int i = beg; i < end; i++){
    int c = counts[i];
    indptr[i] = run;
    counts[i] = run;   // cursor for scatter
    run += c;
  }
  if (t == 1023) indptr[N] = run;
}

// fused gate-normalize + CSR scatter; (src,gate) packed into one uint2
__global__ void k_scatter(const int* __restrict__ src, const int* __restrict__ dst,
                          const float* __restrict__ sbuf, const float* __restrict__ minmax,
                          float* __restrict__ gate_out, int* __restrict__ cursor,
                          uint2* __restrict__ eg, int E){
  int e = blockIdx.x*blockDim.x + threadIdx.x;
  if (e >= E) return;
  float mn = minmax[0], mx = minmax[1];
  float g = (sbuf[e] - mn) / (mx - mn);
  gate_out[e] = g;
  int pos = atomicAdd(&cursor[dst[e]], 1);
  uint2 v; v.x = (unsigned int)src[e]; v.y = __float_as_uint(g);
  eg[pos] = v;
}

// layer1 segment softmax: one thread per (dst,head)
__global__ void k_alpha1(const int* __restrict__ indptr, const uint2* __restrict__ eg,
                         const float* __restrict__ es1, const float* __restrict__ ed1,
                         float* __restrict__ ap, float* __restrict__ invden, int N){
  int i = blockIdx.x*blockDim.x + threadIdx.x;
  if (i >= N*8) return;
  int n = i >> 3, hh = i & 7;
  int beg = indptr[n], end = indptr[n+1];
  float ed = ed1[i];
  float m = -FINF;
  for (int j = beg; j < end; j++){
    uint2 v = eg[j];
    float val = leaky(es1[(int)v.x*8 + hh] + ed) * __uint_as_float(v.y);
    ap[(size_t)j*8 + hh] = val;
    m = fmaxf(m, val);
  }
  float den = 0.f;
  for (int j = beg; j < end; j++){
    float w = __expf(ap[(size_t)j*8 + hh] - m);
    ap[(size_t)j*8 + hh] = w;
    den += w;
  }
  invden[i] = 1.f / fmaxf(den, 1e-12f);
}

// layer1 aggregation: one wave per dst node; bf16 z rows (512B, uint2/lane);
// srcs staged in registers (+shfl broadcast), weights staged in LDS per 64-edge chunk.
__global__ __launch_bounds__(256) void k_gather1v(const int* __restrict__ indptr,
        const uint2* __restrict__ eg, const float* __restrict__ ap,
        const float* __restrict__ invden, const unsigned int* __restrict__ z1b,
        float* __restrict__ hA, int N){
  __shared__ float lap[4][64][8];
  int t = threadIdx.x;
  int w = t >> 6, lane = t & 63;
  int n = blockIdx.x*4 + w;
  if (n >= N) return;
  int hh = lane >> 3;
  int beg = indptr[n], end = indptr[n+1];
  float4 acc = make_float4(0.f,0.f,0.f,0.f);
  for (int c = beg; c < end; c += 64){
    int len = min(64, end - c);
    int sv = 0;
    if (lane < len){
      sv = (int)eg[c + lane].x;
      float4 a0 = *(const float4*)(ap + (size_t)(c + lane)*8);
      float4 a1 = *(const float4*)(ap + (size_t)(c + lane)*8 + 4);
      *(float4*)&lap[w][lane][0] = a0;
      *(float4*)&lap[w][lane][4] = a1;
    }
    __builtin_amdgcn_wave_barrier();
    for (int jj = 0; jj < len; jj++){
      int a = __shfl(sv, jj);
      float wgt = lap[w][jj][hh];
      uint2 zv = *(const uint2*)(z1b + (size_t)a*128 + lane*2);
      acc.x += wgt*bflo(zv.x); acc.y += wgt*bfhi(zv.x);
      acc.z += wgt*bflo(zv.y); acc.w += wgt*bfhi(zv.y);
    }
    __builtin_amdgcn_wave_barrier();
  }
  float iv = invden[n*8 + hh];
  float4 o;
  o.x = leaky(acc.x*iv); o.y = leaky(acc.y*iv);
  o.z = leaky(acc.z*iv); o.w = leaky(acc.w*iv);
  ((float4*)(hA + (size_t)n*256))[lane] = o;
}

// z2 = hA @ fc2 (reg-blocked 8x2), stored as bf16; es2/ed2 fused via 32-lane reduce
__global__ __launch_bounds__(256) void k_z2(const float* __restrict__ hA,
        const float* __restrict__ fc2, const float* __restrict__ a2s,
        const float* __restrict__ a2d, unsigned int* __restrict__ z2b,
        float* __restrict__ es2, float* __restrict__ ed2, int N){
  __shared__ float hs[64][128];
  int t = threadIdx.x;
  int n0 = blockIdx.x * 64;
  int cg = t & 31, rg = t >> 5;
  int o0 = cg*2, m0 = rg*8;
  float acc[8][2];
  #pragma unroll
  for (int m = 0; m < 8; m++) acc[m][0] = acc[m][1] = 0.f;
  for (int kc = 0; kc < 2; kc++){
    const float* base = hA + (size_t)n0*256 + kc*128;
    #pragma unroll
    for (int i = 0; i < 8; i++){
      int idx = t + i*256;
      int row = idx >> 5, c4 = idx & 31;
      float4 v = (n0 + row < N) ? *(const float4*)(base + (size_t)row*256 + c4*4)
                                : make_float4(0.f,0.f,0.f,0.f);
      *(float4*)(&hs[row][c4*4]) = v;
    }
    __syncthreads();
    const float* wp = fc2 + (size_t)(kc*128)*64 + o0;
    for (int k = 0; k < 128; k += 4){
      float2 w0 = *(const float2*)(wp + (size_t)(k+0)*64);
      float2 w1 = *(const float2*)(wp + (size_t)(k+1)*64);
      float2 w2 = *(const float2*)(wp + (size_t)(k+2)*64);
      float2 w3 = *(const float2*)(wp + (size_t)(k+3)*64);
      #pragma unroll
      for (int m = 0; m < 8; m++){
        float4 hv = *(const float4*)(&hs[m0 + m][k]);
        acc[m][0] += hv.x*w0.x + hv.y*w1.x + hv.z*w2.x + hv.w*w3.x;
        acc[m][1] += hv.x*w0.y + hv.y*w1.y + hv.z*w2.y + hv.w*w3.y;
      }
    }
    __syncthreads();
  }
  float a2s0 = a2s[o0], a2s1 = a2s[o0+1];
  float a2d0 = a2d[o0], a2d1 = a2d[o0+1];
  #pragma unroll
  for (int m = 0; m < 8; m++){
    int node = n0 + m0 + m;
    if (node < N)
      z2b[(size_t)node*32 + cg] = pack2(acc[m][0], acc[m][1]);
    float s0 = acc[m][0]*a2s0 + acc[m][1]*a2s1;
    float s1 = acc[m][0]*a2d0 + acc[m][1]*a2d1;
    #pragma unroll
    for (int o = 1; o < 32; o <<= 1){
      s0 += __shfl_xor(s0, o);
      s1 += __shfl_xor(s1, o);
    }
    if (cg == 0 && node < N){ es2[node] = s0; ed2[node] = s1; }
  }
}

// layer2 segment softmax: one thread per dst node
__global__ void k_alpha2(const int* __restrict__ indptr, const uint2* __restrict__ eg,
                         const float* __restrict__ es2, const float* __restrict__ ed2,
                         float* __restrict__ ap2, float* __restrict__ invden2, int N){
  int n = blockIdx.x*blockDim.x + threadIdx.x;
  if (n >= N) return;
  int beg = indptr[n], end = indptr[n+1];
  float ed = ed2[n];
  float m = -FINF;
  for (int j = beg; j < end; j++){
    uint2 v = eg[j];
    float val = leaky(es2[(int)v.x] + ed) * __uint_as_float(v.y);
    ap2[j] = val;
    m = fmaxf(m, val);
  }
  float den = 0.f;
  for (int j = beg; j < end; j++){
    float w = __expf(ap2[j] - m);
    ap2[j] = w;
    den += w;
  }
  invden2[n] = 1.f / fmaxf(den, 1e-12f);
}

// layer2 aggregation: half-wave (32 lanes) per dst node, bf16 rows (128B, u32/lane)
__global__ __launch_bounds__(256) void k_gather2v(const int* __restrict__ indptr,
        const uint2* __restrict__ eg, const float* __restrict__ ap2,
        const float* __restrict__ invden2, const unsigned int* __restrict__ z2b,
        float* __restrict__ hB, int N){
  int t = threadIdx.x;
  int n = blockIdx.x*8 + (t >> 5);
  if (n >= N) return;
  int l = t & 31;
  int beg = indptr[n], end = indptr[n+1];
  float a0 = 0.f, a1 = 0.f;
  for (int j = beg; j < end; j++){
    int a = (int)eg[j].x;
    float wgt = ap2[j];
    unsigned int u = z2b[(size_t)a*32 + l];
    a0 += wgt*bflo(u);
    a1 += wgt*bfhi(u);
  }
  float iv = invden2[n];
  *(float2*)(hB + (size_t)n*64 + l*2) = make_float2(a0*iv, a1*iv);
}

// per-node split of edge predictor: ps = hB@Wp[0:64], pd = hB@Wp[64:128]
__global__ __launch_bounds__(256) void k_ppred(const float* __restrict__ hB,
        const float* __restrict__ Wp, float* __restrict__ ps,
        float* __restrict__ pd, int N){
  __shared__ float lwp[256];
  int t = threadIdx.x;
  lwp[t] = Wp[t];
  __syncthreads();
  int n = blockIdx.x*256 + t;
  if (n >= N) return;
  const float4* r = (const float4*)(hB + (size_t)n*64);
  float s0 = 0.f, s1 = 0.f, d0 = 0.f, d1 = 0.f;
  #pragma unroll
  for (int q = 0; q < 16; q++){
    float4 v = r[q];
    int k = q*4;
    s0 += v.x*lwp[(k+0)*2]   + v.y*lwp[(k+1)*2]   + v.z*lwp[(k+2)*2]   + v.w*lwp[(k+3)*2];
    s1 += v.x*lwp[(k+0)*2+1] + v.y*lwp[(k+1)*2+1] + v.z*lwp[(k+2)*2+1] + v.w*lwp[(k+3)*2+1];
    d0 += v.x*lwp[128+(k+0)*2]   + v.y*lwp[128+(k+1)*2]   + v.z*lwp[128+(k+2)*2]   + v.w*lwp[128+(k+3)*2];
    d1 += v.x*lwp[128+(k+0)*2+1] + v.y*lwp[128+(k+1)*2+1] + v.z*lwp[128+(k+2)*2+1] + v.w*lwp[128+(k+3)*2+1];
  }
  ps[(size_t)n*2]   = s0; ps[(size_t)n*2+1] = s1;
  pd[(size_t)n*2]   = d0; pd[(size_t)n*2+1] = d1;
}

__global__ void k_edgepred(const int* __restrict__ src, const int* __restrict__ dst,
                           const float* __restrict__ ps, const float* __restrict__ pd,
                           const float* __restrict__ bp, float* __restrict__ out, int E){
  int e = blockIdx.x*blockDim.x + threadIdx.x;
  if (e >= E) return;
  int a = src[e], b = dst[e];
  float2 vs = ((const float2*)ps)[a];
  float2 vd = ((const float2*)pd)[b];
  float2 o;
  o.x = vs.x + vd.x + bp[0];
  o.y = vs.y + vd.y + bp[1];
  ((float2*)out)[e] = o;
}

extern "C" void kernel_launch(void* const* d_in, const int* in_sizes, int n_in,
                              void* d_out, int out_size, void* d_ws, size_t ws_size,
                              hipStream_t stream) {
  const float* h   = (const float*)d_in[0];
  const int*   src = (const int*)d_in[1];
  const int*   dst = (const int*)d_in[2];
  const float* W1  = (const float*)d_in[3];
  const float* b1  = (const float*)d_in[4];
  const float* W2  = (const float*)d_in[5];
  const float* b2  = (const float*)d_in[6];
  const float* W3  = (const float*)d_in[7];
  const float* b3  = (const float*)d_in[8];
  const float* fc1 = (const float*)d_in[9];
  const float* a1s = (const float*)d_in[10];
  const float* a1d = (const float*)d_in[11];
  const float* fc2 = (const float*)d_in[12];
  const float* a2s = (const float*)d_in[13];
  const float* a2d = (const float*)d_in[14];
  const float* Wp  = (const float*)d_in[15];
  const float* bp  = (const float*)d_in[16];

  const int N = in_sizes[0] / 128;
  const int E = in_sizes[1];

  float* out_score = (float*)d_out;             // [E,2]
  float* gate      = out_score + (size_t)E*2;   // [E]

  char* w = (char*)d_ws;
  size_t off = 0;
  auto alloc = [&](size_t bytes) -> void* {
    off = (off + 255) & ~(size_t)255;
    void* p = w + off; off += bytes; return p;
  };
  float* u_s  = (float*)alloc((size_t)N*8*4);
  float* u_d  = (float*)alloc((size_t)N*8*4);
  unsigned int* z1b = (unsigned int*)alloc((size_t)N*256*2);  // bf16 [N,256]
  float* es1  = (float*)alloc((size_t)N*8*4);
  float* ed1  = (float*)alloc((size_t)N*8*4);
  float* sbuf = (float*)alloc((size_t)E*4);
  float* hA   = (float*)alloc((size_t)N*256*4);
  float* ap   = (float*)alloc((size_t)E*8*4);
  float* invden1 = (float*)alloc((size_t)N*8*4);
  float* es2  = (float*)alloc((size_t)N*4);
  float* ed2  = (float*)alloc((size_t)N*4);
  float* invden2 = (float*)alloc((size_t)N*4);
  float* minmax = (float*)alloc(2*4);
  int* counts = (int*)alloc((size_t)N*4);
  int* indptr = (int*)alloc(((size_t)N+1)*4);
  uint2* eg   = (uint2*)alloc((size_t)E*8);
  (void)ws_size; (void)n_in; (void)out_size;

  // reuse: z1b dead after gather1v -> z2b; hA dead after z2 -> hB;
  // ap dead after gather1v -> ap2; u_s/u_d dead after gate_edge -> ps/pd.
  unsigned int* z2b = z1b;          // bf16 [N,64]
  float* hB  = hA;                  // [N,64]
  float* ap2 = ap;                  // [E]
  float* ps  = u_s;                 // [N,2]
  float* pd  = u_d;                 // [N,2]

  k_init<<<(N + 255)/256, 256, 0, stream>>>(counts, minmax, N);
  k_h1u<<<(N + 15)/16, 256, 0, stream>>>(h, W1, b1, W2, u_s, u_d, N);
  k_z1<<<(N + 63)/64, 256, 0, stream>>>(h, fc1, a1s, a1d, z1b, es1, ed1, N);
  k_gate_edge<<<(E + 255)/256, 256, 0, stream>>>(u_s, u_d, src, dst, b2, W3, b3,
                                                 sbuf, counts, minmax, E);
  k_scan<<<1, 1024, 0, stream>>>(counts, indptr, N);
  k_scatter<<<(E + 255)/256, 256, 0, stream>>>(src, dst, sbuf, minmax, gate,
                                               counts, eg, E);
  k_alpha1<<<(N*8 + 255)/256, 256, 0, stream>>>(indptr, eg, es1, ed1, ap, invden1, N);
  k_gather1v<<<(N + 3)/4, 256, 0, stream>>>(indptr, eg, ap, invden1, z1b, hA, N);
  k_z2<<<(N + 63)/64, 256, 0, stream>>>(hA, fc2, a2s, a2d, z2b, es2, ed2, N);
  k_alpha2<<<(N + 255)/256, 256, 0, stream>>>(indptr, eg, es2, ed2, ap2, invden2, N);
  k_gather2v<<<(N + 7)/8, 256, 0, stream>>>(indptr, eg, ap2, invden2, z2b, hB, N);
  k_ppred<<<(N + 255)/256, 256, 0, stream>>>(hB, Wp, ps, pd, N);
  k_edgepred<<<(E + 255)/256, 256, 0, stream>>>(src, dst, ps, pd, bp, out_score, E);
}

// Round 6
// 469.285 us; speedup vs baseline: 2.7350x; 1.2145x over previous
//
#include <hip/hip_runtime.h>
#include <math.h>

#define FINF __builtin_inff()

__device__ __forceinline__ float leaky(float x){ return x > 0.f ? x : 0.01f*x; }

__device__ __forceinline__ void atomicMaxF(float* a, float v){
  if (v >= 0.f) atomicMax((int*)a, __float_as_int(v));
  else          atomicMin((unsigned int*)a, __float_as_uint(v));
}
__device__ __forceinline__ void atomicMinF(float* a, float v){
  if (v >= 0.f) atomicMin((int*)a, __float_as_int(v));
  else          atomicMax((unsigned int*)a, __float_as_uint(v));
}

// fp32 -> bf16 (RNE) and pack two into a u32
__device__ __forceinline__ unsigned int f2bf(float f){
  unsigned int x = __float_as_uint(f);
  x += 0x7FFFu + ((x >> 16) & 1u);
  return x >> 16;
}
__device__ __forceinline__ unsigned int pack2(float lo, float hi){
  return f2bf(lo) | (f2bf(hi) << 16);
}
__device__ __forceinline__ float bflo(unsigned int u){ return __uint_as_float(u << 16); }
__device__ __forceinline__ float bfhi(unsigned int u){ return __uint_as_float(u & 0xFFFF0000u); }

__global__ void k_init(int* counts, float* minmax, int N){
  int i = blockIdx.x*blockDim.x + threadIdx.x;
  if (i < N) counts[i] = 0;
  if (i == 0){ minmax[0] = FINF; minmax[1] = -FINF; }
}

// fused: h1 = h@W1+b1 (LDS only), then u_s = h1@W2[0:16], u_d = h1@W2[16:32]
__global__ __launch_bounds__(256) void k_h1u(const float* __restrict__ h,
        const float* __restrict__ W1, const float* __restrict__ b1,
        const float* __restrict__ W2,
        float* __restrict__ u_s, float* __restrict__ u_d, int N){
  __shared__ float lh[16][132];   // padded: bank-conflict-free broadcast
  __shared__ float lw[128][16];
  __shared__ float lh1[16][17];
  int t = threadIdx.x;
  int n0 = blockIdx.x*16;
  const float4* w4 = (const float4*)W1;
  ((float4*)&lw[0][0])[t]       = w4[t];
  ((float4*)&lw[0][0])[t + 256] = w4[t + 256];
  const float4* h4 = (const float4*)(h + (size_t)n0*128);
  {
    int idx = t, row = idx >> 5, c4 = idx & 31;
    *(float4*)&lh[row][c4*4] = (n0+row < N) ? h4[idx] : make_float4(0,0,0,0);
    idx = t + 256; row = idx >> 5; c4 = idx & 31;
    *(float4*)&lh[row][c4*4] = (n0+row < N) ? h4[idx] : make_float4(0,0,0,0);
  }
  __syncthreads();
  int nl = t >> 4, j = t & 15;
  float s = b1[j];
  #pragma unroll 8
  for (int k = 0; k < 128; k++) s += lh[nl][k]*lw[k][j];
  lh1[nl][j] = s;
  __syncthreads();
  int n = n0 + nl;
  if (n < N){
    float acc = 0.f;
    if (j < 8){
      #pragma unroll
      for (int k = 0; k < 16; k++) acc += lh1[nl][k]*W2[k*8 + j];
      u_s[(size_t)n*8 + j] = acc;
    } else {
      int jj = j - 8;
      #pragma unroll
      for (int k = 0; k < 16; k++) acc += lh1[nl][k]*W2[(16 + k)*8 + jj];
      u_d[(size_t)n*8 + jj] = acc;
    }
  }
}

// z1 = h @ fc1 (reg-blocked 16x4), stored as bf16; es1/ed1 fused in epilogue
__global__ __launch_bounds__(256) void k_z1(const float* __restrict__ h,
        const float* __restrict__ fc1, const float* __restrict__ a1s,
        const float* __restrict__ a1d, unsigned int* __restrict__ z1b,
        float* __restrict__ es1, float* __restrict__ ed1, int N){
  __shared__ float hs[64][128];
  int t = threadIdx.x;
  int n0 = blockIdx.x * 64;
  const float4* h4 = (const float4*)(h + (size_t)n0*128);
  float4* hs4 = (float4*)&hs[0][0];
  #pragma unroll
  for (int i = 0; i < 8; i++){
    int idx = t + i*256;
    int row = idx >> 5;
    hs4[idx] = (n0 + row < N) ? h4[idx] : make_float4(0.f,0.f,0.f,0.f);
  }
  __syncthreads();
  int cg = t & 63, rg = t >> 6;
  int o0 = cg*4, m0 = rg*16;
  int hh = cg >> 3;
  const float* wb = fc1 + (size_t)hh*4096 + (o0 & 31);
  float acc[16][4];
  #pragma unroll
  for (int m = 0; m < 16; m++)
    acc[m][0] = acc[m][1] = acc[m][2] = acc[m][3] = 0.f;
  for (int k = 0; k < 128; k += 4){
    float4 w0 = *(const float4*)(wb + (size_t)(k+0)*32);
    float4 w1 = *(const float4*)(wb + (size_t)(k+1)*32);
    float4 w2 = *(const float4*)(wb + (size_t)(k+2)*32);
    float4 w3 = *(const float4*)(wb + (size_t)(k+3)*32);
    #pragma unroll
    for (int m = 0; m < 16; m++){
      float4 hv = *(const float4*)(&hs[m0 + m][k]);
      acc[m][0] += hv.x*w0.x + hv.y*w1.x + hv.z*w2.x + hv.w*w3.x;
      acc[m][1] += hv.x*w0.y + hv.y*w1.y + hv.z*w2.y + hv.w*w3.y;
      acc[m][2] += hv.x*w0.z + hv.y*w1.z + hv.z*w2.z + hv.w*w3.z;
      acc[m][3] += hv.x*w0.w + hv.y*w1.w + hv.z*w2.w + hv.w*w3.w;
    }
  }
  float4 as4 = *(const float4*)(a1s + hh*32 + (o0 & 31));
  float4 ad4 = *(const float4*)(a1d + hh*32 + (o0 & 31));
  #pragma unroll
  for (int m = 0; m < 16; m++){
    int node = n0 + m0 + m;
    if (node < N){
      uint2 pk;
      pk.x = pack2(acc[m][0], acc[m][1]);
      pk.y = pack2(acc[m][2], acc[m][3]);
      *(uint2*)(z1b + (size_t)node*128 + cg*2) = pk;
    }
    float s0 = acc[m][0]*as4.x + acc[m][1]*as4.y + acc[m][2]*as4.z + acc[m][3]*as4.w;
    float s1 = acc[m][0]*ad4.x + acc[m][1]*ad4.y + acc[m][2]*ad4.z + acc[m][3]*ad4.w;
    s0 += __shfl_xor(s0, 1); s1 += __shfl_xor(s1, 1);
    s0 += __shfl_xor(s0, 2); s1 += __shfl_xor(s1, 2);
    s0 += __shfl_xor(s0, 4); s1 += __shfl_xor(s1, 4);
    if ((cg & 7) == 0 && node < N){ es1[node*8 + hh] = s0; ed1[node*8 + hh] = s1; }
  }
}

// gate edge score via per-node decomposition; dst histogram + global min/max
__global__ __launch_bounds__(256) void k_gate_edge(const float* __restrict__ u_s,
        const float* __restrict__ u_d,
        const int* __restrict__ src, const int* __restrict__ dst,
        const float* __restrict__ b2, const float* __restrict__ W3,
        const float* __restrict__ b3,
        float* __restrict__ sbuf, int* __restrict__ counts,
        float* __restrict__ minmax, int E){
  __shared__ float lb2[8], lw3[8];
  __shared__ float lb3;
  __shared__ float rmin[4], rmax[4];
  int t = threadIdx.x;
  if (t < 8){ lb2[t] = b2[t]; lw3[t] = W3[t]; }
  if (t == 8) lb3 = b3[0];
  __syncthreads();
  int e = blockIdx.x*blockDim.x + t;
  float s = 0.f;
  bool valid = (e < E);
  if (valid){
    int a = src[e], b = dst[e];
    float4 us0 = ((const float4*)(u_s + (size_t)a*8))[0];
    float4 us1 = ((const float4*)(u_s + (size_t)a*8))[1];
    float4 ud0 = ((const float4*)(u_d + (size_t)b*8))[0];
    float4 ud1 = ((const float4*)(u_d + (size_t)b*8))[1];
    float tv[8] = { us0.x+ud0.x, us0.y+ud0.y, us0.z+ud0.z, us0.w+ud0.w,
                    us1.x+ud1.x, us1.y+ud1.y, us1.z+ud1.z, us1.w+ud1.w };
    s = lb3;
    #pragma unroll
    for (int j = 0; j < 8; j++) s += fmaxf(tv[j] + lb2[j], 0.f)*lw3[j];
    sbuf[e] = s;
    atomicAdd(&counts[b], 1);
  }
  float vmin = valid ? s : FINF;
  float vmax = valid ? s : -FINF;
  #pragma unroll
  for (int o = 32; o > 0; o >>= 1){
    vmin = fminf(vmin, __shfl_xor(vmin, o));
    vmax = fmaxf(vmax, __shfl_xor(vmax, o));
  }
  if ((t & 63) == 0){ rmin[t >> 6] = vmin; rmax[t >> 6] = vmax; }
  __syncthreads();
  if (t == 0){
    float mn = fminf(fminf(rmin[0], rmin[1]), fminf(rmin[2], rmin[3]));
    float mx = fmaxf(fmaxf(rmax[0], rmax[1]), fmaxf(rmax[2], rmax[3]));
    atomicMinF(&minmax[0], mn);
    atomicMaxF(&minmax[1], mx);
  }
}

// ---- device-wide exclusive scan (3 kernels) ----
// pass1: each block scans 1024 counts; within-block exclusive prefixes -> indptr,
// block total -> blockSums
__global__ __launch_bounds__(256) void k_scan1(const int* __restrict__ counts,
        int* __restrict__ indptr, int* __restrict__ blockSums, int N){
  __shared__ int wsum[4];
  int t = threadIdx.x;
  int base = blockIdx.x*1024 + t*4;
  int c[4];
  #pragma unroll
  for (int i = 0; i < 4; i++) c[i] = (base + i < N) ? counts[base + i] : 0;
  int s = c[0] + c[1] + c[2] + c[3];
  int lane = t & 63, wid = t >> 6;
  int inc = s;
  #pragma unroll
  for (int o = 1; o < 64; o <<= 1){
    int v = __shfl_up(inc, o);
    if (lane >= o) inc += v;
  }
  if (lane == 63) wsum[wid] = inc;
  __syncthreads();
  int woff = 0;
  #pragma unroll
  for (int i = 0; i < 4; i++) if (i < wid) woff += wsum[i];
  int run = woff + inc - s;   // exclusive prefix of this thread's chunk
  #pragma unroll
  for (int i = 0; i < 4; i++){
    if (base + i < N) indptr[base + i] = run;
    run += c[i];
  }
  if (t == 255) blockSums[blockIdx.x] = woff + inc;
}

// pass2: single wave scans block sums (looped), writes total to indptr[N]
__global__ __launch_bounds__(64) void k_scan2(int* __restrict__ blockSums,
        int* __restrict__ indptr, int B, int N){
  int t = threadIdx.x;
  int carry = 0;
  for (int b0 = 0; b0 < B; b0 += 64){
    int idx = b0 + t;
    int v = (idx < B) ? blockSums[idx] : 0;
    int inc = v;
    #pragma unroll
    for (int o = 1; o < 64; o <<= 1){
      int u = __shfl_up(inc, o);
      if (t >= o) inc += u;
    }
    if (idx < B) blockSums[idx] = carry + inc - v;   // exclusive block offset
    carry += __shfl(inc, 63);
  }
  if (t == 0) indptr[N] = carry;
}

// pass3: add block offsets; also materialize the scatter cursor
__global__ __launch_bounds__(256) void k_scan3(int* __restrict__ indptr,
        const int* __restrict__ blockSums, int* __restrict__ cursor, int N){
  int i = blockIdx.x*blockDim.x + threadIdx.x;
  if (i >= N) return;
  int v = indptr[i] + blockSums[i >> 10];
  indptr[i] = v;
  cursor[i] = v;
}

// fused gate-normalize + CSR scatter; (src,gate) packed into one uint2
__global__ void k_scatter(const int* __restrict__ src, const int* __restrict__ dst,
                          const float* __restrict__ sbuf, const float* __restrict__ minmax,
                          float* __restrict__ gate_out, int* __restrict__ cursor,
                          uint2* __restrict__ eg, int E){
  int e = blockIdx.x*blockDim.x + threadIdx.x;
  if (e >= E) return;
  float mn = minmax[0], mx = minmax[1];
  float g = (sbuf[e] - mn) / (mx - mn);
  gate_out[e] = g;
  int pos = atomicAdd(&cursor[dst[e]], 1);
  uint2 v; v.x = (unsigned int)src[e]; v.y = __float_as_uint(g);
  eg[pos] = v;
}

// layer1 segment softmax: one thread per (dst,head)
__global__ void k_alpha1(const int* __restrict__ indptr, const uint2* __restrict__ eg,
                         const float* __restrict__ es1, const float* __restrict__ ed1,
                         float* __restrict__ ap, float* __restrict__ invden, int N){
  int i = blockIdx.x*blockDim.x + threadIdx.x;
  if (i >= N*8) return;
  int n = i >> 3, hh = i & 7;
  int beg = indptr[n], end = indptr[n+1];
  float ed = ed1[i];
  float m = -FINF;
  for (int j = beg; j < end; j++){
    uint2 v = eg[j];
    float val = leaky(es1[(int)v.x*8 + hh] + ed) * __uint_as_float(v.y);
    ap[(size_t)j*8 + hh] = val;
    m = fmaxf(m, val);
  }
  float den = 0.f;
  for (int j = beg; j < end; j++){
    float w = __expf(ap[(size_t)j*8 + hh] - m);
    ap[(size_t)j*8 + hh] = w;
    den += w;
  }
  invden[i] = 1.f / fmaxf(den, 1e-12f);
}

// layer1 aggregation: one wave per dst node; bf16 z rows (512B, uint2/lane)
__global__ __launch_bounds__(256) void k_gather1v(const int* __restrict__ indptr,
        const uint2* __restrict__ eg, const float* __restrict__ ap,
        const float* __restrict__ invden, const unsigned int* __restrict__ z1b,
        float* __restrict__ hA, int N){
  __shared__ float lap[4][64][8];
  int t = threadIdx.x;
  int w = t >> 6, lane = t & 63;
  int n = blockIdx.x*4 + w;
  if (n >= N) return;
  int hh = lane >> 3;
  int beg = indptr[n], end = indptr[n+1];
  float4 acc = make_float4(0.f,0.f,0.f,0.f);
  for (int c = beg; c < end; c += 64){
    int len = min(64, end - c);
    int sv = 0;
    if (lane < len){
      sv = (int)eg[c + lane].x;
      float4 a0 = *(const float4*)(ap + (size_t)(c + lane)*8);
      float4 a1 = *(const float4*)(ap + (size_t)(c + lane)*8 + 4);
      *(float4*)&lap[w][lane][0] = a0;
      *(float4*)&lap[w][lane][4] = a1;
    }
    __builtin_amdgcn_wave_barrier();
    for (int jj = 0; jj < len; jj++){
      int a = __shfl(sv, jj);
      float wgt = lap[w][jj][hh];
      uint2 zv = *(const uint2*)(z1b + (size_t)a*128 + lane*2);
      acc.x += wgt*bflo(zv.x); acc.y += wgt*bfhi(zv.x);
      acc.z += wgt*bflo(zv.y); acc.w += wgt*bfhi(zv.y);
    }
    __builtin_amdgcn_wave_barrier();
  }
  float iv = invden[n*8 + hh];
  float4 o;
  o.x = leaky(acc.x*iv); o.y = leaky(acc.y*iv);
  o.z = leaky(acc.z*iv); o.w = leaky(acc.w*iv);
  ((float4*)(hA + (size_t)n*256))[lane] = o;
}

// z2 = hA @ fc2 (reg-blocked 8x2), stored as bf16; es2/ed2 fused via 32-lane reduce
__global__ __launch_bounds__(256) void k_z2(const float* __restrict__ hA,
        const float* __restrict__ fc2, const float* __restrict__ a2s,
        const float* __restrict__ a2d, unsigned int* __restrict__ z2b,
        float* __restrict__ es2, float* __restrict__ ed2, int N){
  __shared__ float hs[64][128];
  int t = threadIdx.x;
  int n0 = blockIdx.x * 64;
  int cg = t & 31, rg = t >> 5;
  int o0 = cg*2, m0 = rg*8;
  float acc[8][2];
  #pragma unroll
  for (int m = 0; m < 8; m++) acc[m][0] = acc[m][1] = 0.f;
  for (int kc = 0; kc < 2; kc++){
    const float* base = hA + (size_t)n0*256 + kc*128;
    #pragma unroll
    for (int i = 0; i < 8; i++){
      int idx = t + i*256;
      int row = idx >> 5, c4 = idx & 31;
      float4 v = (n0 + row < N) ? *(const float4*)(base + (size_t)row*256 + c4*4)
                                : make_float4(0.f,0.f,0.f,0.f);
      *(float4*)(&hs[row][c4*4]) = v;
    }
    __syncthreads();
    const float* wp = fc2 + (size_t)(kc*128)*64 + o0;
    for (int k = 0; k < 128; k += 4){
      float2 w0 = *(const float2*)(wp + (size_t)(k+0)*64);
      float2 w1 = *(const float2*)(wp + (size_t)(k+1)*64);
      float2 w2 = *(const float2*)(wp + (size_t)(k+2)*64);
      float2 w3 = *(const float2*)(wp + (size_t)(k+3)*64);
      #pragma unroll
      for (int m = 0; m < 8; m++){
        float4 hv = *(const float4*)(&hs[m0 + m][k]);
        acc[m][0] += hv.x*w0.x + hv.y*w1.x + hv.z*w2.x + hv.w*w3.x;
        acc[m][1] += hv.x*w0.y + hv.y*w1.y + hv.z*w2.y + hv.w*w3.y;
      }
    }
    __syncthreads();
  }
  float a2s0 = a2s[o0], a2s1 = a2s[o0+1];
  float a2d0 = a2d[o0], a2d1 = a2d[o0+1];
  #pragma unroll
  for (int m = 0; m < 8; m++){
    int node = n0 + m0 + m;
    if (node < N)
      z2b[(size_t)node*32 + cg] = pack2(acc[m][0], acc[m][1]);
    float s0 = acc[m][0]*a2s0 + acc[m][1]*a2s1;
    float s1 = acc[m][0]*a2d0 + acc[m][1]*a2d1;
    #pragma unroll
    for (int o = 1; o < 32; o <<= 1){
      s0 += __shfl_xor(s0, o);
      s1 += __shfl_xor(s1, o);
    }
    if (cg == 0 && node < N){ es2[node] = s0; ed2[node] = s1; }
  }
}

// layer2 segment softmax: one thread per dst node
__global__ void k_alpha2(const int* __restrict__ indptr, const uint2* __restrict__ eg,
                         const float* __restrict__ es2, const float* __restrict__ ed2,
                         float* __restrict__ ap2, float* __restrict__ invden2, int N){
  int n = blockIdx.x*blockDim.x + threadIdx.x;
  if (n >= N) return;
  int beg = indptr[n], end = indptr[n+1];
  float ed = ed2[n];
  float m = -FINF;
  for (int j = beg; j < end; j++){
    uint2 v = eg[j];
    float val = leaky(es2[(int)v.x] + ed) * __uint_as_float(v.y);
    ap2[j] = val;
    m = fmaxf(m, val);
  }
  float den = 0.f;
  for (int j = beg; j < end; j++){
    float w = __expf(ap2[j] - m);
    ap2[j] = w;
    den += w;
  }
  invden2[n] = 1.f / fmaxf(den, 1e-12f);
}

// layer2 aggregation: half-wave (32 lanes) per dst node, bf16 rows (128B, u32/lane)
__global__ __launch_bounds__(256) void k_gather2v(const int* __restrict__ indptr,
        const uint2* __restrict__ eg, const float* __restrict__ ap2,
        const float* __restrict__ invden2, const unsigned int* __restrict__ z2b,
        float* __restrict__ hB, int N){
  int t = threadIdx.x;
  int n = blockIdx.x*8 + (t >> 5);
  if (n >= N) return;
  int l = t & 31;
  int beg = indptr[n], end = indptr[n+1];
  float a0 = 0.f, a1 = 0.f;
  for (int j = beg; j < end; j++){
    int a = (int)eg[j].x;
    float wgt = ap2[j];
    unsigned int u = z2b[(size_t)a*32 + l];
    a0 += wgt*bflo(u);
    a1 += wgt*bfhi(u);
  }
  float iv = invden2[n];
  *(float2*)(hB + (size_t)n*64 + l*2) = make_float2(a0*iv, a1*iv);
}

// per-node split of edge predictor: ps = hB@Wp[0:64], pd = hB@Wp[64:128]
__global__ __launch_bounds__(256) void k_ppred(const float* __restrict__ hB,
        const float* __restrict__ Wp, float* __restrict__ ps,
        float* __restrict__ pd, int N){
  __shared__ float lwp[256];
  int t = threadIdx.x;
  lwp[t] = Wp[t];
  __syncthreads();
  int n = blockIdx.x*256 + t;
  if (n >= N) return;
  const float4* r = (const float4*)(hB + (size_t)n*64);
  float s0 = 0.f, s1 = 0.f, d0 = 0.f, d1 = 0.f;
  #pragma unroll
  for (int q = 0; q < 16; q++){
    float4 v = r[q];
    int k = q*4;
    s0 += v.x*lwp[(k+0)*2]   + v.y*lwp[(k+1)*2]   + v.z*lwp[(k+2)*2]   + v.w*lwp[(k+3)*2];
    s1 += v.x*lwp[(k+0)*2+1] + v.y*lwp[(k+1)*2+1] + v.z*lwp[(k+2)*2+1] + v.w*lwp[(k+3)*2+1];
    d0 += v.x*lwp[128+(k+0)*2]   + v.y*lwp[128+(k+1)*2]   + v.z*lwp[128+(k+2)*2]   + v.w*lwp[128+(k+3)*2];
    d1 += v.x*lwp[128+(k+0)*2+1] + v.y*lwp[128+(k+1)*2+1] + v.z*lwp[128+(k+2)*2+1] + v.w*lwp[128+(k+3)*2+1];
  }
  ps[(size_t)n*2]   = s0; ps[(size_t)n*2+1] = s1;
  pd[(size_t)n*2]   = d0; pd[(size_t)n*2+1] = d1;
}

__global__ void k_edgepred(const int* __restrict__ src, const int* __restrict__ dst,
                           const float* __restrict__ ps, const float* __restrict__ pd,
                           const float* __restrict__ bp, float* __restrict__ out, int E){
  int e = blockIdx.x*blockDim.x + threadIdx.x;
  if (e >= E) return;
  int a = src[e], b = dst[e];
  float2 vs = ((const float2*)ps)[a];
  float2 vd = ((const float2*)pd)[b];
  float2 o;
  o.x = vs.x + vd.x + bp[0];
  o.y = vs.y + vd.y + bp[1];
  ((float2*)out)[e] = o;
}

extern "C" void kernel_launch(void* const* d_in, const int* in_sizes, int n_in,
                              void* d_out, int out_size, void* d_ws, size_t ws_size,
                              hipStream_t stream) {
  const float* h   = (const float*)d_in[0];
  const int*   src = (const int*)d_in[1];
  const int*   dst = (const int*)d_in[2];
  const float* W1  = (const float*)d_in[3];
  const float* b1  = (const float*)d_in[4];
  const float* W2  = (const float*)d_in[5];
  const float* b2  = (const float*)d_in[6];
  const float* W3  = (const float*)d_in[7];
  const float* b3  = (const float*)d_in[8];
  const float* fc1 = (const float*)d_in[9];
  const float* a1s = (const float*)d_in[10];
  const float* a1d = (const float*)d_in[11];
  const float* fc2 = (const float*)d_in[12];
  const float* a2s = (const float*)d_in[13];
  const float* a2d = (const float*)d_in[14];
  const float* Wp  = (const float*)d_in[15];
  const float* bp  = (const float*)d_in[16];

  const int N = in_sizes[0] / 128;
  const int E = in_sizes[1];

  float* out_score = (float*)d_out;             // [E,2]
  float* gate      = out_score + (size_t)E*2;   // [E]

  char* w = (char*)d_ws;
  size_t off = 0;
  auto alloc = [&](size_t bytes) -> void* {
    off = (off + 255) & ~(size_t)255;
    void* p = w + off; off += bytes; return p;
  };
  float* u_s  = (float*)alloc((size_t)N*8*4);
  float* u_d  = (float*)alloc((size_t)N*8*4);
  unsigned int* z1b = (unsigned int*)alloc((size_t)N*256*2);  // bf16 [N,256]
  float* es1  = (float*)alloc((size_t)N*8*4);
  float* ed1  = (float*)alloc((size_t)N*8*4);
  float* sbuf = (float*)alloc((size_t)E*4);
  float* hA   = (float*)alloc((size_t)N*256*4);
  float* ap   = (float*)alloc((size_t)E*8*4);
  float* invden1 = (float*)alloc((size_t)N*8*4);
  float* es2  = (float*)alloc((size_t)N*4);
  float* ed2  = (float*)alloc((size_t)N*4);
  float* invden2 = (float*)alloc((size_t)N*4);
  float* minmax = (float*)alloc(2*4);
  int* counts = (int*)alloc((size_t)N*4);
  int* indptr = (int*)alloc(((size_t)N+1)*4);
  int* blockSums = (int*)alloc(1024*4);
  uint2* eg   = (uint2*)alloc((size_t)E*8);
  (void)ws_size; (void)n_in; (void)out_size;

  // reuse: z1b dead after gather1v -> z2b; hA dead after z2 -> hB;
  // ap dead after gather1v -> ap2; u_s/u_d dead after gate_edge -> ps/pd.
  unsigned int* z2b = z1b;          // bf16 [N,64]
  float* hB  = hA;                  // [N,64]
  float* ap2 = ap;                  // [E]
  float* ps  = u_s;                 // [N,2]
  float* pd  = u_d;                 // [N,2]

  const int SCAN_B = (N + 1023)/1024;

  k_init<<<(N + 255)/256, 256, 0, stream>>>(counts, minmax, N);
  k_h1u<<<(N + 15)/16, 256, 0, stream>>>(h, W1, b1, W2, u_s, u_d, N);
  k_z1<<<(N + 63)/64, 256, 0, stream>>>(h, fc1, a1s, a1d, z1b, es1, ed1, N);
  k_gate_edge<<<(E + 255)/256, 256, 0, stream>>>(u_s, u_d, src, dst, b2, W3, b3,
                                                 sbuf, counts, minmax, E);
  k_scan1<<<SCAN_B, 256, 0, stream>>>(counts, indptr, blockSums, N);
  k_scan2<<<1, 64, 0, stream>>>(blockSums, indptr, SCAN_B, N);
  k_scan3<<<(N + 255)/256, 256, 0, stream>>>(indptr, blockSums, counts, N);
  k_scatter<<<(E + 255)/256, 256, 0, stream>>>(src, dst, sbuf, minmax, gate,
                                               counts, eg, E);
  k_alpha1<<<(N*8 + 255)/256, 256, 0, stream>>>(indptr, eg, es1, ed1, ap, invden1, N);
  k_gather1v<<<(N + 3)/4, 256, 0, stream>>>(indptr, eg, ap, invden1, z1b, hA, N);
  k_z2<<<(N + 63)/64, 256, 0, stream>>>(hA, fc2, a2s, a2d, z2b, es2, ed2, N);
  k_alpha2<<<(N + 255)/256, 256, 0, stream>>>(indptr, eg, es2, ed2, ap2, invden2, N);
  k_gather2v<<<(N + 7)/8, 256, 0, stream>>>(indptr, eg, ap2, invden2, z2b, hB, N);
  k_ppred<<<(N + 255)/256, 256, 0, stream>>>(hB, Wp, ps, pd, N);
  k_edgepred<<<(E + 255)/256, 256, 0, stream>>>(src, dst, ps, pd, bp, out_score, E);
}

// Round 7
// 416.499 us; speedup vs baseline: 3.0816x; 1.1267x over previous
//
#include <hip/hip_runtime.h>
#include <math.h>

#define FINF __builtin_inff()

__device__ __forceinline__ float leaky(float x){ return x > 0.f ? x : 0.01f*x; }

// fp32 -> bf16 (RNE) and pack two into a u32
__device__ __forceinline__ unsigned int f2bf(float f){
  unsigned int x = __float_as_uint(f);
  x += 0x7FFFu + ((x >> 16) & 1u);
  return x >> 16;
}
__device__ __forceinline__ unsigned int pack2(float lo, float hi){
  return f2bf(lo) | (f2bf(hi) << 16);
}
__device__ __forceinline__ float bflo(unsigned int u){ return __uint_as_float(u << 16); }
__device__ __forceinline__ float bfhi(unsigned int u){ return __uint_as_float(u & 0xFFFF0000u); }

__global__ void k_init(int* counts, int N){
  int i = blockIdx.x*blockDim.x + threadIdx.x;
  if (i < N) counts[i] = 0;
}

// fused: h1 = h@W1+b1 (LDS only), then u_s = h1@W2[0:16], u_d = h1@W2[16:32]
__global__ __launch_bounds__(256) void k_h1u(const float* __restrict__ h,
        const float* __restrict__ W1, const float* __restrict__ b1,
        const float* __restrict__ W2,
        float* __restrict__ u_s, float* __restrict__ u_d, int N){
  __shared__ float lh[16][132];
  __shared__ float lw[128][16];
  __shared__ float lh1[16][17];
  int t = threadIdx.x;
  int n0 = blockIdx.x*16;
  const float4* w4 = (const float4*)W1;
  ((float4*)&lw[0][0])[t]       = w4[t];
  ((float4*)&lw[0][0])[t + 256] = w4[t + 256];
  const float4* h4 = (const float4*)(h + (size_t)n0*128);
  {
    int idx = t, row = idx >> 5, c4 = idx & 31;
    *(float4*)&lh[row][c4*4] = (n0+row < N) ? h4[idx] : make_float4(0,0,0,0);
    idx = t + 256; row = idx >> 5; c4 = idx & 31;
    *(float4*)&lh[row][c4*4] = (n0+row < N) ? h4[idx] : make_float4(0,0,0,0);
  }
  __syncthreads();
  int nl = t >> 4, j = t & 15;
  float s = b1[j];
  #pragma unroll 8
  for (int k = 0; k < 128; k++) s += lh[nl][k]*lw[k][j];
  lh1[nl][j] = s;
  __syncthreads();
  int n = n0 + nl;
  if (n < N){
    float acc = 0.f;
    if (j < 8){
      #pragma unroll
      for (int k = 0; k < 16; k++) acc += lh1[nl][k]*W2[k*8 + j];
      u_s[(size_t)n*8 + j] = acc;
    } else {
      int jj = j - 8;
      #pragma unroll
      for (int k = 0; k < 16; k++) acc += lh1[nl][k]*W2[(16 + k)*8 + jj];
      u_d[(size_t)n*8 + jj] = acc;
    }
  }
}

// z1 = h @ fc1 (reg-blocked 16x4), stored as bf16; es1/ed1 fused in epilogue
__global__ __launch_bounds__(256) void k_z1(const float* __restrict__ h,
        const float* __restrict__ fc1, const float* __restrict__ a1s,
        const float* __restrict__ a1d, unsigned int* __restrict__ z1b,
        float* __restrict__ es1, float* __restrict__ ed1, int N){
  __shared__ float hs[64][128];
  int t = threadIdx.x;
  int n0 = blockIdx.x * 64;
  const float4* h4 = (const float4*)(h + (size_t)n0*128);
  float4* hs4 = (float4*)&hs[0][0];
  #pragma unroll
  for (int i = 0; i < 8; i++){
    int idx = t + i*256;
    int row = idx >> 5;
    hs4[idx] = (n0 + row < N) ? h4[idx] : make_float4(0.f,0.f,0.f,0.f);
  }
  __syncthreads();
  int cg = t & 63, rg = t >> 6;
  int o0 = cg*4, m0 = rg*16;
  int hh = cg >> 3;
  const float* wb = fc1 + (size_t)hh*4096 + (o0 & 31);
  float acc[16][4];
  #pragma unroll
  for (int m = 0; m < 16; m++)
    acc[m][0] = acc[m][1] = acc[m][2] = acc[m][3] = 0.f;
  for (int k = 0; k < 128; k += 4){
    float4 w0 = *(const float4*)(wb + (size_t)(k+0)*32);
    float4 w1 = *(const float4*)(wb + (size_t)(k+1)*32);
    float4 w2 = *(const float4*)(wb + (size_t)(k+2)*32);
    float4 w3 = *(const float4*)(wb + (size_t)(k+3)*32);
    #pragma unroll
    for (int m = 0; m < 16; m++){
      float4 hv = *(const float4*)(&hs[m0 + m][k]);
      acc[m][0] += hv.x*w0.x + hv.y*w1.x + hv.z*w2.x + hv.w*w3.x;
      acc[m][1] += hv.x*w0.y + hv.y*w1.y + hv.z*w2.y + hv.w*w3.y;
      acc[m][2] += hv.x*w0.z + hv.y*w1.z + hv.z*w2.z + hv.w*w3.z;
      acc[m][3] += hv.x*w0.w + hv.y*w1.w + hv.z*w2.w + hv.w*w3.w;
    }
  }
  float4 as4 = *(const float4*)(a1s + hh*32 + (o0 & 31));
  float4 ad4 = *(const float4*)(a1d + hh*32 + (o0 & 31));
  #pragma unroll
  for (int m = 0; m < 16; m++){
    int node = n0 + m0 + m;
    if (node < N){
      uint2 pk;
      pk.x = pack2(acc[m][0], acc[m][1]);
      pk.y = pack2(acc[m][2], acc[m][3]);
      *(uint2*)(z1b + (size_t)node*128 + cg*2) = pk;
    }
    float s0 = acc[m][0]*as4.x + acc[m][1]*as4.y + acc[m][2]*as4.z + acc[m][3]*as4.w;
    float s1 = acc[m][0]*ad4.x + acc[m][1]*ad4.y + acc[m][2]*ad4.z + acc[m][3]*ad4.w;
    s0 += __shfl_xor(s0, 1); s1 += __shfl_xor(s1, 1);
    s0 += __shfl_xor(s0, 2); s1 += __shfl_xor(s1, 2);
    s0 += __shfl_xor(s0, 4); s1 += __shfl_xor(s1, 4);
    if ((cg & 7) == 0 && node < N){ es1[node*8 + hh] = s0; ed1[node*8 + hh] = s1; }
  }
}

// gate edge score; dst histogram; per-block (min,max) partials (NO global atomics)
__global__ __launch_bounds__(256) void k_gate_edge(const float* __restrict__ u_s,
        const float* __restrict__ u_d,
        const int* __restrict__ src, const int* __restrict__ dst,
        const float* __restrict__ b2, const float* __restrict__ W3,
        const float* __restrict__ b3,
        float* __restrict__ sbuf, int* __restrict__ counts,
        float2* __restrict__ pmm, int E){
  __shared__ float lb2[8], lw3[8];
  __shared__ float lb3;
  __shared__ float rmin[4], rmax[4];
  int t = threadIdx.x;
  if (t < 8){ lb2[t] = b2[t]; lw3[t] = W3[t]; }
  if (t == 8) lb3 = b3[0];
  __syncthreads();
  int e = blockIdx.x*blockDim.x + t;
  float s = 0.f;
  bool valid = (e < E);
  if (valid){
    int a = src[e], b = dst[e];
    float4 us0 = ((const float4*)(u_s + (size_t)a*8))[0];
    float4 us1 = ((const float4*)(u_s + (size_t)a*8))[1];
    float4 ud0 = ((const float4*)(u_d + (size_t)b*8))[0];
    float4 ud1 = ((const float4*)(u_d + (size_t)b*8))[1];
    float tv[8] = { us0.x+ud0.x, us0.y+ud0.y, us0.z+ud0.z, us0.w+ud0.w,
                    us1.x+ud1.x, us1.y+ud1.y, us1.z+ud1.z, us1.w+ud1.w };
    s = lb3;
    #pragma unroll
    for (int j = 0; j < 8; j++) s += fmaxf(tv[j] + lb2[j], 0.f)*lw3[j];
    sbuf[e] = s;
    atomicAdd(&counts[b], 1);
  }
  float vmin = valid ? s : FINF;
  float vmax = valid ? s : -FINF;
  #pragma unroll
  for (int o = 32; o > 0; o >>= 1){
    vmin = fminf(vmin, __shfl_xor(vmin, o));
    vmax = fmaxf(vmax, __shfl_xor(vmax, o));
  }
  if ((t & 63) == 0){ rmin[t >> 6] = vmin; rmax[t >> 6] = vmax; }
  __syncthreads();
  if (t == 0){
    float mn = fminf(fminf(rmin[0], rmin[1]), fminf(rmin[2], rmin[3]));
    float mx = fmaxf(fmaxf(rmax[0], rmax[1]), fmaxf(rmax[2], rmax[3]));
    pmm[blockIdx.x] = make_float2(mn, mx);
  }
}

// ---- device-wide exclusive scan (3 kernels) ----
__global__ __launch_bounds__(256) void k_scan1(const int* __restrict__ counts,
        int* __restrict__ indptr, int* __restrict__ blockSums, int N){
  __shared__ int wsum[4];
  int t = threadIdx.x;
  int base = blockIdx.x*1024 + t*4;
  int c[4];
  #pragma unroll
  for (int i = 0; i < 4; i++) c[i] = (base + i < N) ? counts[base + i] : 0;
  int s = c[0] + c[1] + c[2] + c[3];
  int lane = t & 63, wid = t >> 6;
  int inc = s;
  #pragma unroll
  for (int o = 1; o < 64; o <<= 1){
    int v = __shfl_up(inc, o);
    if (lane >= o) inc += v;
  }
  if (lane == 63) wsum[wid] = inc;
  __syncthreads();
  int woff = 0;
  #pragma unroll
  for (int i = 0; i < 4; i++) if (i < wid) woff += wsum[i];
  int run = woff + inc - s;
  #pragma unroll
  for (int i = 0; i < 4; i++){
    if (base + i < N) indptr[base + i] = run;
    run += c[i];
  }
  if (t == 255) blockSums[blockIdx.x] = woff + inc;
}

// pass2: single wave scans block sums; ALSO reduces per-block gate min/max partials
__global__ __launch_bounds__(64) void k_scan2(int* __restrict__ blockSums,
        int* __restrict__ indptr, int B, int N,
        const float2* __restrict__ pmm, int GB, float* __restrict__ minmax){
  int t = threadIdx.x;
  int carry = 0;
  for (int b0 = 0; b0 < B; b0 += 64){
    int idx = b0 + t;
    int v = (idx < B) ? blockSums[idx] : 0;
    int inc = v;
    #pragma unroll
    for (int o = 1; o < 64; o <<= 1){
      int u = __shfl_up(inc, o);
      if (t >= o) inc += u;
    }
    if (idx < B) blockSums[idx] = carry + inc - v;
    carry += __shfl(inc, 63);
  }
  if (t == 0) indptr[N] = carry;
  // gate min/max reduction
  float mn = FINF, mx = -FINF;
  for (int i = t; i < GB; i += 64){
    float2 v = pmm[i];
    mn = fminf(mn, v.x);
    mx = fmaxf(mx, v.y);
  }
  #pragma unroll
  for (int o = 32; o > 0; o >>= 1){
    mn = fminf(mn, __shfl_xor(mn, o));
    mx = fmaxf(mx, __shfl_xor(mx, o));
  }
  if (t == 0){ minmax[0] = mn; minmax[1] = mx; }
}

// pass3: add block offsets; materialize scatter cursor
__global__ __launch_bounds__(256) void k_scan3(int* __restrict__ indptr,
        const int* __restrict__ blockSums, int* __restrict__ cursor, int N){
  int i = blockIdx.x*blockDim.x + threadIdx.x;
  if (i >= N) return;
  int v = indptr[i] + blockSums[i >> 10];
  indptr[i] = v;
  cursor[i] = v;
}

// fused gate-normalize + CSR scatter; (src,gate) packed into one uint2
__global__ void k_scatter(const int* __restrict__ src, const int* __restrict__ dst,
                          const float* __restrict__ sbuf, const float* __restrict__ minmax,
                          float* __restrict__ gate_out, int* __restrict__ cursor,
                          uint2* __restrict__ eg, int E){
  int e = blockIdx.x*blockDim.x + threadIdx.x;
  if (e >= E) return;
  float mn = minmax[0], mx = minmax[1];
  float g = (sbuf[e] - mn) / (mx - mn);
  gate_out[e] = g;
  int pos = atomicAdd(&cursor[dst[e]], 1);
  uint2 v; v.x = (unsigned int)src[e]; v.y = __float_as_uint(g);
  eg[pos] = v;
}

// layer1 segment softmax, SINGLE PASS (no max-shift: logits bounded ~|4|,
// softmax is shift-invariant; exp<=e^4 is safe in fp32)
__global__ void k_alpha1(const int* __restrict__ indptr, const uint2* __restrict__ eg,
                         const float* __restrict__ es1, const float* __restrict__ ed1,
                         float* __restrict__ ap, float* __restrict__ invden, int N){
  int i = blockIdx.x*blockDim.x + threadIdx.x;
  if (i >= N*8) return;
  int n = i >> 3, hh = i & 7;
  int beg = indptr[n], end = indptr[n+1];
  float ed = ed1[i];
  float den = 0.f;
  for (int j = beg; j < end; j++){
    uint2 v = eg[j];
    float val = leaky(es1[(int)v.x*8 + hh] + ed) * __uint_as_float(v.y);
    float w = __expf(val);
    ap[(size_t)j*8 + hh] = w;
    den += w;
  }
  invden[i] = 1.f / fmaxf(den, 1e-12f);
}

// layer1 aggregation: one wave per dst node; bf16 z rows (512B, uint2/lane)
__global__ __launch_bounds__(256) void k_gather1v(const int* __restrict__ indptr,
        const uint2* __restrict__ eg, const float* __restrict__ ap,
        const float* __restrict__ invden, const unsigned int* __restrict__ z1b,
        float* __restrict__ hA, int N){
  __shared__ float lap[4][64][8];
  int t = threadIdx.x;
  int w = t >> 6, lane = t & 63;
  int n = blockIdx.x*4 + w;
  if (n >= N) return;
  int hh = lane >> 3;
  int beg = indptr[n], end = indptr[n+1];
  float4 acc = make_float4(0.f,0.f,0.f,0.f);
  for (int c = beg; c < end; c += 64){
    int len = min(64, end - c);
    int sv = 0;
    if (lane < len){
      sv = (int)eg[c + lane].x;
      float4 a0 = *(const float4*)(ap + (size_t)(c + lane)*8);
      float4 a1 = *(const float4*)(ap + (size_t)(c + lane)*8 + 4);
      *(float4*)&lap[w][lane][0] = a0;
      *(float4*)&lap[w][lane][4] = a1;
    }
    __builtin_amdgcn_wave_barrier();
    for (int jj = 0; jj < len; jj++){
      int a = __shfl(sv, jj);
      float wgt = lap[w][jj][hh];
      uint2 zv = *(const uint2*)(z1b + (size_t)a*128 + lane*2);
      acc.x += wgt*bflo(zv.x); acc.y += wgt*bfhi(zv.x);
      acc.z += wgt*bflo(zv.y); acc.w += wgt*bfhi(zv.y);
    }
    __builtin_amdgcn_wave_barrier();
  }
  float iv = invden[n*8 + hh];
  float4 o;
  o.x = leaky(acc.x*iv); o.y = leaky(acc.y*iv);
  o.z = leaky(acc.z*iv); o.w = leaky(acc.w*iv);
  ((float4*)(hA + (size_t)n*256))[lane] = o;
}

// z2 = hA @ fc2 (reg-blocked 8x2), stored as bf16; es2/ed2 fused via 32-lane reduce
__global__ __launch_bounds__(256) void k_z2(const float* __restrict__ hA,
        const float* __restrict__ fc2, const float* __restrict__ a2s,
        const float* __restrict__ a2d, unsigned int* __restrict__ z2b,
        float* __restrict__ es2, float* __restrict__ ed2, int N){
  __shared__ float hs[64][128];
  int t = threadIdx.x;
  int n0 = blockIdx.x * 64;
  int cg = t & 31, rg = t >> 5;
  int o0 = cg*2, m0 = rg*8;
  float acc[8][2];
  #pragma unroll
  for (int m = 0; m < 8; m++) acc[m][0] = acc[m][1] = 0.f;
  for (int kc = 0; kc < 2; kc++){
    const float* base = hA + (size_t)n0*256 + kc*128;
    #pragma unroll
    for (int i = 0; i < 8; i++){
      int idx = t + i*256;
      int row = idx >> 5, c4 = idx & 31;
      float4 v = (n0 + row < N) ? *(const float4*)(base + (size_t)row*256 + c4*4)
                                : make_float4(0.f,0.f,0.f,0.f);
      *(float4*)(&hs[row][c4*4]) = v;
    }
    __syncthreads();
    const float* wp = fc2 + (size_t)(kc*128)*64 + o0;
    for (int k = 0; k < 128; k += 4){
      float2 w0 = *(const float2*)(wp + (size_t)(k+0)*64);
      float2 w1 = *(const float2*)(wp + (size_t)(k+1)*64);
      float2 w2 = *(const float2*)(wp + (size_t)(k+2)*64);
      float2 w3 = *(const float2*)(wp + (size_t)(k+3)*64);
      #pragma unroll
      for (int m = 0; m < 8; m++){
        float4 hv = *(const float4*)(&hs[m0 + m][k]);
        acc[m][0] += hv.x*w0.x + hv.y*w1.x + hv.z*w2.x + hv.w*w3.x;
        acc[m][1] += hv.x*w0.y + hv.y*w1.y + hv.z*w2.y + hv.w*w3.y;
      }
    }
    __syncthreads();
  }
  float a2s0 = a2s[o0], a2s1 = a2s[o0+1];
  float a2d0 = a2d[o0], a2d1 = a2d[o0+1];
  #pragma unroll
  for (int m = 0; m < 8; m++){
    int node = n0 + m0 + m;
    if (node < N)
      z2b[(size_t)node*32 + cg] = pack2(acc[m][0], acc[m][1]);
    float s0 = acc[m][0]*a2s0 + acc[m][1]*a2s1;
    float s1 = acc[m][0]*a2d0 + acc[m][1]*a2d1;
    #pragma unroll
    for (int o = 1; o < 32; o <<= 1){
      s0 += __shfl_xor(s0, o);
      s1 += __shfl_xor(s1, o);
    }
    if (cg == 0 && node < N){ es2[node] = s0; ed2[node] = s1; }
  }
}

// layer2 segment softmax, single pass (no max-shift)
__global__ void k_alpha2(const int* __restrict__ indptr, const uint2* __restrict__ eg,
                         const float* __restrict__ es2, const float* __restrict__ ed2,
                         float* __restrict__ ap2, float* __restrict__ invden2, int N){
  int n = blockIdx.x*blockDim.x + threadIdx.x;
  if (n >= N) return;
  int beg = indptr[n], end = indptr[n+1];
  float ed = ed2[n];
  float den = 0.f;
  for (int j = beg; j < end; j++){
    uint2 v = eg[j];
    float val = leaky(es2[(int)v.x] + ed) * __uint_as_float(v.y);
    float w = __expf(val);
    ap2[j] = w;
    den += w;
  }
  invden2[n] = 1.f / fmaxf(den, 1e-12f);
}

// layer2 aggregation: half-wave (32 lanes) per dst node, bf16 rows (128B, u32/lane)
__global__ __launch_bounds__(256) void k_gather2v(const int* __restrict__ indptr,
        const uint2* __restrict__ eg, const float* __restrict__ ap2,
        const float* __restrict__ invden2, const unsigned int* __restrict__ z2b,
        float* __restrict__ hB, int N){
  int t = threadIdx.x;
  int n = blockIdx.x*8 + (t >> 5);
  if (n >= N) return;
  int l = t & 31;
  int beg = indptr[n], end = indptr[n+1];
  float a0 = 0.f, a1 = 0.f;
  for (int j = beg; j < end; j++){
    int a = (int)eg[j].x;
    float wgt = ap2[j];
    unsigned int u = z2b[(size_t)a*32 + l];
    a0 += wgt*bflo(u);
    a1 += wgt*bfhi(u);
  }
  float iv = invden2[n];
  *(float2*)(hB + (size_t)n*64 + l*2) = make_float2(a0*iv, a1*iv);
}

// per-node split of edge predictor: ps = hB@Wp[0:64], pd = hB@Wp[64:128]
__global__ __launch_bounds__(256) void k_ppred(const float* __restrict__ hB,
        const float* __restrict__ Wp, float* __restrict__ ps,
        float* __restrict__ pd, int N){
  __shared__ float lwp[256];
  int t = threadIdx.x;
  lwp[t] = Wp[t];
  __syncthreads();
  int n = blockIdx.x*256 + t;
  if (n >= N) return;
  const float4* r = (const float4*)(hB + (size_t)n*64);
  float s0 = 0.f, s1 = 0.f, d0 = 0.f, d1 = 0.f;
  #pragma unroll
  for (int q = 0; q < 16; q++){
    float4 v = r[q];
    int k = q*4;
    s0 += v.x*lwp[(k+0)*2]   + v.y*lwp[(k+1)*2]   + v.z*lwp[(k+2)*2]   + v.w*lwp[(k+3)*2];
    s1 += v.x*lwp[(k+0)*2+1] + v.y*lwp[(k+1)*2+1] + v.z*lwp[(k+2)*2+1] + v.w*lwp[(k+3)*2+1];
    d0 += v.x*lwp[128+(k+0)*2]   + v.y*lwp[128+(k+1)*2]   + v.z*lwp[128+(k+2)*2]   + v.w*lwp[128+(k+3)*2];
    d1 += v.x*lwp[128+(k+0)*2+1] + v.y*lwp[128+(k+1)*2+1] + v.z*lwp[128+(k+2)*2+1] + v.w*lwp[128+(k+3)*2+1];
  }
  ps[(size_t)n*2]   = s0; ps[(size_t)n*2+1] = s1;
  pd[(size_t)n*2]   = d0; pd[(size_t)n*2+1] = d1;
}

__global__ void k_edgepred(const int* __restrict__ src, const int* __restrict__ dst,
                           const float* __restrict__ ps, const float* __restrict__ pd,
                           const float* __restrict__ bp, float* __restrict__ out, int E){
  int e = blockIdx.x*blockDim.x + threadIdx.x;
  if (e >= E) return;
  int a = src[e], b = dst[e];
  float2 vs = ((const float2*)ps)[a];
  float2 vd = ((const float2*)pd)[b];
  float2 o;
  o.x = vs.x + vd.x + bp[0];
  o.y = vs.y + vd.y + bp[1];
  ((float2*)out)[e] = o;
}

extern "C" void kernel_launch(void* const* d_in, const int* in_sizes, int n_in,
                              void* d_out, int out_size, void* d_ws, size_t ws_size,
                              hipStream_t stream) {
  const float* h   = (const float*)d_in[0];
  const int*   src = (const int*)d_in[1];
  const int*   dst = (const int*)d_in[2];
  const float* W1  = (const float*)d_in[3];
  const float* b1  = (const float*)d_in[4];
  const float* W2  = (const float*)d_in[5];
  const float* b2  = (const float*)d_in[6];
  const float* W3  = (const float*)d_in[7];
  const float* b3  = (const float*)d_in[8];
  const float* fc1 = (const float*)d_in[9];
  const float* a1s = (const float*)d_in[10];
  const float* a1d = (const float*)d_in[11];
  const float* fc2 = (const float*)d_in[12];
  const float* a2s = (const float*)d_in[13];
  const float* a2d = (const float*)d_in[14];
  const float* Wp  = (const float*)d_in[15];
  const float* bp  = (const float*)d_in[16];

  const int N = in_sizes[0] / 128;
  const int E = in_sizes[1];

  float* out_score = (float*)d_out;             // [E,2]
  float* gate      = out_score + (size_t)E*2;   // [E]

  char* w = (char*)d_ws;
  size_t off = 0;
  auto alloc = [&](size_t bytes) -> void* {
    off = (off + 255) & ~(size_t)255;
    void* p = w + off; off += bytes; return p;
  };
  float* u_s  = (float*)alloc((size_t)N*8*4);
  float* u_d  = (float*)alloc((size_t)N*8*4);
  unsigned int* z1b = (unsigned int*)alloc((size_t)N*256*2);  // bf16 [N,256]
  float* es1  = (float*)alloc((size_t)N*8*4);
  float* ed1  = (float*)alloc((size_t)N*8*4);
  float* sbuf = (float*)alloc((size_t)E*4);
  float* hA   = (float*)alloc((size_t)N*256*4);
  float* ap   = (float*)alloc((size_t)E*8*4);
  float* invden1 = (float*)alloc((size_t)N*8*4);
  float* es2  = (float*)alloc((size_t)N*4);
  float* ed2  = (float*)alloc((size_t)N*4);
  float* invden2 = (float*)alloc((size_t)N*4);
  float* minmax = (float*)alloc(2*4);
  int* counts = (int*)alloc((size_t)N*4);
  int* indptr = (int*)alloc(((size_t)N+1)*4);
  int* blockSums = (int*)alloc(1024*4);
  const int GATE_B = (E + 255)/256;
  float2* pmm = (float2*)alloc((size_t)GATE_B*8);
  uint2* eg   = (uint2*)alloc((size_t)E*8);
  (void)ws_size; (void)n_in; (void)out_size;

  unsigned int* z2b = z1b;          // bf16 [N,64]
  float* hB  = hA;                  // [N,64]
  float* ap2 = ap;                  // [E]
  float* ps  = u_s;                 // [N,2]
  float* pd  = u_d;                 // [N,2]

  const int SCAN_B = (N + 1023)/1024;

  k_init<<<(N + 255)/256, 256, 0, stream>>>(counts, N);
  k_h1u<<<(N + 15)/16, 256, 0, stream>>>(h, W1, b1, W2, u_s, u_d, N);
  k_z1<<<(N + 63)/64, 256, 0, stream>>>(h, fc1, a1s, a1d, z1b, es1, ed1, N);
  k_gate_edge<<<GATE_B, 256, 0, stream>>>(u_s, u_d, src, dst, b2, W3, b3,
                                          sbuf, counts, pmm, E);
  k_scan1<<<SCAN_B, 256, 0, stream>>>(counts, indptr, blockSums, N);
  k_scan2<<<1, 64, 0, stream>>>(blockSums, indptr, SCAN_B, N, pmm, GATE_B, minmax);
  k_scan3<<<(N + 255)/256, 256, 0, stream>>>(indptr, blockSums, counts, N);
  k_scatter<<<(E + 255)/256, 256, 0, stream>>>(src, dst, sbuf, minmax, gate,
                                               counts, eg, E);
  k_alpha1<<<(N*8 + 255)/256, 256, 0, stream>>>(indptr, eg, es1, ed1, ap, invden1, N);
  k_gather1v<<<(N + 3)/4, 256, 0, stream>>>(indptr, eg, ap, invden1, z1b, hA, N);
  k_z2<<<(N + 63)/64, 256, 0, stream>>>(hA, fc2, a2s, a2d, z2b, es2, ed2, N);
  k_alpha2<<<(N + 255)/256, 256, 0, stream>>>(indptr, eg, es2, ed2, ap2, invden2, N);
  k_gather2v<<<(N + 7)/8, 256, 0, stream>>>(indptr, eg, ap2, invden2, z2b, hB, N);
  k_ppred<<<(N + 255)/256, 256, 0, stream>>>(hB, Wp, ps, pd, N);
  k_edgepred<<<(E + 255)/256, 256, 0, stream>>>(src, dst, ps, pd, bp, out_score, E);
}

// Round 8
// 354.398 us; speedup vs baseline: 3.6216x; 1.1752x over previous
//
#include <hip/hip_runtime.h>
#include <math.h>

#define FINF __builtin_inff()

using short8  = __attribute__((ext_vector_type(8))) short;
using floatx4 = __attribute__((ext_vector_type(4))) float;
union U4 { uint4 u; short8 s; };

__device__ __forceinline__ float leaky(float x){ return x > 0.f ? x : 0.01f*x; }

// fp32 -> bf16 (RNE) and pack two into a u32
__device__ __forceinline__ unsigned int f2bf(float f){
  unsigned int x = __float_as_uint(f);
  x += 0x7FFFu + ((x >> 16) & 1u);
  return x >> 16;
}
__device__ __forceinline__ unsigned int pack2(float lo, float hi){
  return f2bf(lo) | (f2bf(hi) << 16);
}
__device__ __forceinline__ float bflo(unsigned int u){ return __uint_as_float(u << 16); }
__device__ __forceinline__ float bfhi(unsigned int u){ return __uint_as_float(u & 0xFFFF0000u); }

__global__ void k_init(int* counts, int N){
  int i = blockIdx.x*blockDim.x + threadIdx.x;
  if (i < N) counts[i] = 0;
}

// fused: h1 = h@W1+b1 (LDS only), then u_s = h1@W2[0:16], u_d = h1@W2[16:32]
__global__ __launch_bounds__(256) void k_h1u(const float* __restrict__ h,
        const float* __restrict__ W1, const float* __restrict__ b1,
        const float* __restrict__ W2,
        float* __restrict__ u_s, float* __restrict__ u_d, int N){
  __shared__ float lh[16][132];
  __shared__ float lw[128][16];
  __shared__ float lh1[16][17];
  int t = threadIdx.x;
  int n0 = blockIdx.x*16;
  const float4* w4 = (const float4*)W1;
  ((float4*)&lw[0][0])[t]       = w4[t];
  ((float4*)&lw[0][0])[t + 256] = w4[t + 256];
  const float4* h4 = (const float4*)(h + (size_t)n0*128);
  {
    int idx = t, row = idx >> 5, c4 = idx & 31;
    *(float4*)&lh[row][c4*4] = (n0+row < N) ? h4[idx] : make_float4(0,0,0,0);
    idx = t + 256; row = idx >> 5; c4 = idx & 31;
    *(float4*)&lh[row][c4*4] = (n0+row < N) ? h4[idx] : make_float4(0,0,0,0);
  }
  __syncthreads();
  int nl = t >> 4, j = t & 15;
  float s = b1[j];
  #pragma unroll 8
  for (int k = 0; k < 128; k++) s += lh[nl][k]*lw[k][j];
  lh1[nl][j] = s;
  __syncthreads();
  int n = n0 + nl;
  if (n < N){
    float acc = 0.f;
    if (j < 8){
      #pragma unroll
      for (int k = 0; k < 16; k++) acc += lh1[nl][k]*W2[k*8 + j];
      u_s[(size_t)n*8 + j] = acc;
    } else {
      int jj = j - 8;
      #pragma unroll
      for (int k = 0; k < 16; k++) acc += lh1[nl][k]*W2[(16 + k)*8 + jj];
      u_d[(size_t)n*8 + jj] = acc;
    }
  }
}

// repack fc1 [8][128][32] -> bf16 B-fragment order: wp1[nt][kk][lane][i],
// nt=0..15 (16-col tiles of N=256), kk=0..3 (K-steps of 32),
// element = B[k = kk*32+(lane>>4)*8+i][n = nt*16+(lane&15)]
__global__ void k_wpack1(const float* __restrict__ fc1, unsigned short* __restrict__ wp1){
  int idx = blockIdx.x*256 + threadIdx.x;
  if (idx >= 32768) return;
  int i  = idx & 7;
  int l  = (idx >> 3) & 63;
  int kk = (idx >> 9) & 3;
  int nt = idx >> 11;
  int n = nt*16 + (l & 15);
  int k = kk*32 + ((l >> 4) << 3) + i;
  wp1[idx] = (unsigned short)f2bf(fc1[(size_t)(n >> 5)*4096 + k*32 + (n & 31)]);
}

// repack fc2 [256][64] similarly: nt=0..3, kk=0..7
__global__ void k_wpack2(const float* __restrict__ fc2, unsigned short* __restrict__ wp2){
  int idx = blockIdx.x*256 + threadIdx.x;
  if (idx >= 16384) return;
  int i  = idx & 7;
  int l  = (idx >> 3) & 63;
  int kk = (idx >> 9) & 7;
  int nt = idx >> 12;
  int n = nt*16 + (l & 15);
  int k = kk*32 + ((l >> 4) << 3) + i;
  wp2[idx] = (unsigned short)f2bf(fc2[(size_t)k*64 + n]);
}

// z1 = h @ fc1 via MFMA bf16: 64-row tile, 4 waves x 16 rows, N=256, K=128
__global__ __launch_bounds__(256) void k_z1m(const float* __restrict__ h,
        const unsigned short* __restrict__ wp1, unsigned short* __restrict__ z1u,
        int N){
  __shared__ uint4 lw[4096];   // 64KB staged weights
  int t = threadIdx.x;
  const uint4* wp4 = (const uint4*)wp1;
  #pragma unroll
  for (int i = 0; i < 16; i++) lw[t + i*256] = wp4[t + i*256];
  __syncthreads();
  int l = t & 63, wv = t >> 6;
  int n0 = blockIdx.x*64, m0 = wv*16;
  int rowA = min(n0 + m0 + (l & 15), N-1);
  const float* hr = h + (size_t)rowA*128 + ((l >> 4) << 3);
  U4 a[4];
  #pragma unroll
  for (int kk = 0; kk < 4; kk++){
    float4 f0 = *(const float4*)(hr + kk*32);
    float4 f1 = *(const float4*)(hr + kk*32 + 4);
    a[kk].u.x = pack2(f0.x, f0.y); a[kk].u.y = pack2(f0.z, f0.w);
    a[kk].u.z = pack2(f1.x, f1.y); a[kk].u.w = pack2(f1.z, f1.w);
  }
  int node0 = n0 + m0 + ((l >> 4) << 2);
  #pragma unroll
  for (int nt = 0; nt < 16; nt++){
    floatx4 acc = {0.f, 0.f, 0.f, 0.f};
    #pragma unroll
    for (int kk = 0; kk < 4; kk++){
      U4 b; b.u = lw[(nt*4 + kk)*64 + l];
      acc = __builtin_amdgcn_mfma_f32_16x16x32_bf16(a[kk].s, b.s, acc, 0, 0, 0);
    }
    int col = nt*16 + (l & 15);
    #pragma unroll
    for (int i2 = 0; i2 < 4; i2++){
      int node = node0 + i2;
      if (node < N) z1u[(size_t)node*256 + col] = (unsigned short)f2bf(acc[i2]);
    }
  }
}

// es1/ed1 from bf16 z1
__global__ void k_es_ed1(const unsigned short* __restrict__ z1u,
                         const float* __restrict__ a1s, const float* __restrict__ a1d,
                         float* __restrict__ es1, float* __restrict__ ed1, int N){
  int i = blockIdx.x*blockDim.x + threadIdx.x;
  if (i >= N*8) return;
  int n = i >> 3, hh = i & 7;
  const uint4* zr = (const uint4*)(z1u + (size_t)n*256 + hh*32);
  const float* as = a1s + hh*32;
  const float* ad = a1d + hh*32;
  float s0 = 0.f, s1 = 0.f;
  #pragma unroll
  for (int q = 0; q < 4; q++){
    uint4 v = zr[q];
    int o = q*8;
    s0 += bflo(v.x)*as[o+0] + bfhi(v.x)*as[o+1] + bflo(v.y)*as[o+2] + bfhi(v.y)*as[o+3]
        + bflo(v.z)*as[o+4] + bfhi(v.z)*as[o+5] + bflo(v.w)*as[o+6] + bfhi(v.w)*as[o+7];
    s1 += bflo(v.x)*ad[o+0] + bfhi(v.x)*ad[o+1] + bflo(v.y)*ad[o+2] + bfhi(v.y)*ad[o+3]
        + bflo(v.z)*ad[o+4] + bfhi(v.z)*ad[o+5] + bflo(v.w)*ad[o+6] + bfhi(v.w)*ad[o+7];
  }
  es1[i] = s0; ed1[i] = s1;
}

// gate edge score; dst histogram; per-block (min,max) partials (no global atomics)
__global__ __launch_bounds__(256) void k_gate_edge(const float* __restrict__ u_s,
        const float* __restrict__ u_d,
        const int* __restrict__ src, const int* __restrict__ dst,
        const float* __restrict__ b2, const float* __restrict__ W3,
        const float* __restrict__ b3,
        float* __restrict__ sbuf, int* __restrict__ counts,
        float2* __restrict__ pmm, int E){
  __shared__ float lb2[8], lw3[8];
  __shared__ float lb3;
  __shared__ float rmin[4], rmax[4];
  int t = threadIdx.x;
  if (t < 8){ lb2[t] = b2[t]; lw3[t] = W3[t]; }
  if (t == 8) lb3 = b3[0];
  __syncthreads();
  int e = blockIdx.x*blockDim.x + t;
  float s = 0.f;
  bool valid = (e < E);
  if (valid){
    int a = src[e], b = dst[e];
    float4 us0 = ((const float4*)(u_s + (size_t)a*8))[0];
    float4 us1 = ((const float4*)(u_s + (size_t)a*8))[1];
    float4 ud0 = ((const float4*)(u_d + (size_t)b*8))[0];
    float4 ud1 = ((const float4*)(u_d + (size_t)b*8))[1];
    float tv[8] = { us0.x+ud0.x, us0.y+ud0.y, us0.z+ud0.z, us0.w+ud0.w,
                    us1.x+ud1.x, us1.y+ud1.y, us1.z+ud1.z, us1.w+ud1.w };
    s = lb3;
    #pragma unroll
    for (int j = 0; j < 8; j++) s += fmaxf(tv[j] + lb2[j], 0.f)*lw3[j];
    sbuf[e] = s;
    atomicAdd(&counts[b], 1);
  }
  float vmin = valid ? s : FINF;
  float vmax = valid ? s : -FINF;
  #pragma unroll
  for (int o = 32; o > 0; o >>= 1){
    vmin = fminf(vmin, __shfl_xor(vmin, o));
    vmax = fmaxf(vmax, __shfl_xor(vmax, o));
  }
  if ((t & 63) == 0){ rmin[t >> 6] = vmin; rmax[t >> 6] = vmax; }
  __syncthreads();
  if (t == 0){
    float mn = fminf(fminf(rmin[0], rmin[1]), fminf(rmin[2], rmin[3]));
    float mx = fmaxf(fmaxf(rmax[0], rmax[1]), fmaxf(rmax[2], rmax[3]));
    pmm[blockIdx.x] = make_float2(mn, mx);
  }
}

// ---- device-wide exclusive scan (3 kernels) ----
__global__ __launch_bounds__(256) void k_scan1(const int* __restrict__ counts,
        int* __restrict__ indptr, int* __restrict__ blockSums, int N){
  __shared__ int wsum[4];
  int t = threadIdx.x;
  int base = blockIdx.x*1024 + t*4;
  int c[4];
  #pragma unroll
  for (int i = 0; i < 4; i++) c[i] = (base + i < N) ? counts[base + i] : 0;
  int s = c[0] + c[1] + c[2] + c[3];
  int lane = t & 63, wid = t >> 6;
  int inc = s;
  #pragma unroll
  for (int o = 1; o < 64; o <<= 1){
    int v = __shfl_up(inc, o);
    if (lane >= o) inc += v;
  }
  if (lane == 63) wsum[wid] = inc;
  __syncthreads();
  int woff = 0;
  #pragma unroll
  for (int i = 0; i < 4; i++) if (i < wid) woff += wsum[i];
  int run = woff + inc - s;
  #pragma unroll
  for (int i = 0; i < 4; i++){
    if (base + i < N) indptr[base + i] = run;
    run += c[i];
  }
  if (t == 255) blockSums[blockIdx.x] = woff + inc;
}

__global__ __launch_bounds__(64) void k_scan2(int* __restrict__ blockSums,
        int* __restrict__ indptr, int B, int N,
        const float2* __restrict__ pmm, int GB, float* __restrict__ minmax){
  int t = threadIdx.x;
  int carry = 0;
  for (int b0 = 0; b0 < B; b0 += 64){
    int idx = b0 + t;
    int v = (idx < B) ? blockSums[idx] : 0;
    int inc = v;
    #pragma unroll
    for (int o = 1; o < 64; o <<= 1){
      int u = __shfl_up(inc, o);
      if (t >= o) inc += u;
    }
    if (idx < B) blockSums[idx] = carry + inc - v;
    carry += __shfl(inc, 63);
  }
  if (t == 0) indptr[N] = carry;
  float mn = FINF, mx = -FINF;
  for (int i = t; i < GB; i += 64){
    float2 v = pmm[i];
    mn = fminf(mn, v.x);
    mx = fmaxf(mx, v.y);
  }
  #pragma unroll
  for (int o = 32; o > 0; o >>= 1){
    mn = fminf(mn, __shfl_xor(mn, o));
    mx = fmaxf(mx, __shfl_xor(mx, o));
  }
  if (t == 0){ minmax[0] = mn; minmax[1] = mx; }
}

__global__ __launch_bounds__(256) void k_scan3(int* __restrict__ indptr,
        const int* __restrict__ blockSums, int* __restrict__ cursor, int N){
  int i = blockIdx.x*blockDim.x + threadIdx.x;
  if (i >= N) return;
  int v = indptr[i] + blockSums[i >> 10];
  indptr[i] = v;
  cursor[i] = v;
}

// fused gate-normalize + CSR scatter; (src,gate) packed into one uint2
__global__ void k_scatter(const int* __restrict__ src, const int* __restrict__ dst,
                          const float* __restrict__ sbuf, const float* __restrict__ minmax,
                          float* __restrict__ gate_out, int* __restrict__ cursor,
                          uint2* __restrict__ eg, int E){
  int e = blockIdx.x*blockDim.x + threadIdx.x;
  if (e >= E) return;
  float mn = minmax[0], mx = minmax[1];
  float g = (sbuf[e] - mn) / (mx - mn);
  gate_out[e] = g;
  int pos = atomicAdd(&cursor[dst[e]], 1);
  uint2 v; v.x = (unsigned int)src[e]; v.y = __float_as_uint(g);
  eg[pos] = v;
}

// layer1 segment softmax, single pass (logits bounded; softmax shift-invariant)
__global__ void k_alpha1(const int* __restrict__ indptr, const uint2* __restrict__ eg,
                         const float* __restrict__ es1, const float* __restrict__ ed1,
                         float* __restrict__ ap, float* __restrict__ invden, int N){
  int i = blockIdx.x*blockDim.x + threadIdx.x;
  if (i >= N*8) return;
  int n = i >> 3, hh = i & 7;
  int beg = indptr[n], end = indptr[n+1];
  float ed = ed1[i];
  float den = 0.f;
  for (int j = beg; j < end; j++){
    uint2 v = eg[j];
    float val = leaky(es1[(int)v.x*8 + hh] + ed) * __uint_as_float(v.y);
    float w = __expf(val);
    ap[(size_t)j*8 + hh] = w;
    den += w;
  }
  invden[i] = 1.f / fmaxf(den, 1e-12f);
}

// layer1 aggregation: one wave per dst node; bf16 z rows; writes hA as bf16
__global__ __launch_bounds__(256) void k_gather1v(const int* __restrict__ indptr,
        const uint2* __restrict__ eg, const float* __restrict__ ap,
        const float* __restrict__ invden, const unsigned int* __restrict__ z1b,
        unsigned int* __restrict__ hAb, int N){
  __shared__ float lap[4][64][8];
  int t = threadIdx.x;
  int w = t >> 6, lane = t & 63;
  int n = blockIdx.x*4 + w;
  if (n >= N) return;
  int hh = lane >> 3;
  int beg = indptr[n], end = indptr[n+1];
  float4 acc = make_float4(0.f,0.f,0.f,0.f);
  for (int c = beg; c < end; c += 64){
    int len = min(64, end - c);
    int sv = 0;
    if (lane < len){
      sv = (int)eg[c + lane].x;
      float4 a0 = *(const float4*)(ap + (size_t)(c + lane)*8);
      float4 a1 = *(const float4*)(ap + (size_t)(c + lane)*8 + 4);
      *(float4*)&lap[w][lane][0] = a0;
      *(float4*)&lap[w][lane][4] = a1;
    }
    __builtin_amdgcn_wave_barrier();
    for (int jj = 0; jj < len; jj++){
      int a = __shfl(sv, jj);
      float wgt = lap[w][jj][hh];
      uint2 zv = *(const uint2*)(z1b + (size_t)a*128 + lane*2);
      acc.x += wgt*bflo(zv.x); acc.y += wgt*bfhi(zv.x);
      acc.z += wgt*bflo(zv.y); acc.w += wgt*bfhi(zv.y);
    }
    __builtin_amdgcn_wave_barrier();
  }
  float iv = invden[n*8 + hh];
  uint2 o;
  o.x = pack2(leaky(acc.x*iv), leaky(acc.y*iv));
  o.y = pack2(leaky(acc.z*iv), leaky(acc.w*iv));
  *(uint2*)(hAb + (size_t)n*128 + lane*2) = o;
}

// z2 = hA @ fc2 via MFMA bf16: 64-row tile, N=64, K=256
__global__ __launch_bounds__(256) void k_z2m(const unsigned short* __restrict__ hAu,
        const unsigned short* __restrict__ wp2, unsigned short* __restrict__ z2u,
        int N){
  __shared__ uint4 lw[2048];   // 32KB
  int t = threadIdx.x;
  const uint4* wp4 = (const uint4*)wp2;
  #pragma unroll
  for (int i = 0; i < 8; i++) lw[t + i*256] = wp4[t + i*256];
  __syncthreads();
  int l = t & 63, wv = t >> 6;
  int n0 = blockIdx.x*64, m0 = wv*16;
  int rowA = min(n0 + m0 + (l & 15), N-1);
  const unsigned short* ar = hAu + (size_t)rowA*256 + ((l >> 4) << 3);
  U4 a[8];
  #pragma unroll
  for (int kk = 0; kk < 8; kk++)
    a[kk].u = *(const uint4*)(ar + kk*32);
  int node0 = n0 + m0 + ((l >> 4) << 2);
  #pragma unroll
  for (int nt = 0; nt < 4; nt++){
    floatx4 acc = {0.f, 0.f, 0.f, 0.f};
    #pragma unroll
    for (int kk = 0; kk < 8; kk++){
      U4 b; b.u = lw[(nt*8 + kk)*64 + l];
      acc = __builtin_amdgcn_mfma_f32_16x16x32_bf16(a[kk].s, b.s, acc, 0, 0, 0);
    }
    int col = nt*16 + (l & 15);
    #pragma unroll
    for (int i2 = 0; i2 < 4; i2++){
      int node = node0 + i2;
      if (node < N) z2u[(size_t)node*64 + col] = (unsigned short)f2bf(acc[i2]);
    }
  }
}

// es2/ed2 from bf16 z2
__global__ void k_es_ed2(const unsigned short* __restrict__ z2u,
                         const float* __restrict__ a2s, const float* __restrict__ a2d,
                         float* __restrict__ es2, float* __restrict__ ed2, int N){
  int n = blockIdx.x*blockDim.x + threadIdx.x;
  if (n >= N) return;
  const uint4* zr = (const uint4*)(z2u + (size_t)n*64);
  float s0 = 0.f, s1 = 0.f;
  #pragma unroll
  for (int q = 0; q < 8; q++){
    uint4 v = zr[q];
    int o = q*8;
    s0 += bflo(v.x)*a2s[o+0] + bfhi(v.x)*a2s[o+1] + bflo(v.y)*a2s[o+2] + bfhi(v.y)*a2s[o+3]
        + bflo(v.z)*a2s[o+4] + bfhi(v.z)*a2s[o+5] + bflo(v.w)*a2s[o+6] + bfhi(v.w)*a2s[o+7];
    s1 += bflo(v.x)*a2d[o+0] + bfhi(v.x)*a2d[o+1] + bflo(v.y)*a2d[o+2] + bfhi(v.y)*a2d[o+3]
        + bflo(v.z)*a2d[o+4] + bfhi(v.z)*a2d[o+5] + bflo(v.w)*a2d[o+6] + bfhi(v.w)*a2d[o+7];
  }
  es2[n] = s0; ed2[n] = s1;
}

// layer2 segment softmax, single pass
__global__ void k_alpha2(const int* __restrict__ indptr, const uint2* __restrict__ eg,
                         const float* __restrict__ es2, const float* __restrict__ ed2,
                         float* __restrict__ ap2, float* __restrict__ invden2, int N){
  int n = blockIdx.x*blockDim.x + threadIdx.x;
  if (n >= N) return;
  int beg = indptr[n], end = indptr[n+1];
  float ed = ed2[n];
  float den = 0.f;
  for (int j = beg; j < end; j++){
    uint2 v = eg[j];
    float val = leaky(es2[(int)v.x] + ed) * __uint_as_float(v.y);
    float w = __expf(val);
    ap2[j] = w;
    den += w;
  }
  invden2[n] = 1.f / fmaxf(den, 1e-12f);
}

// layer2 aggregation: half-wave per dst node, bf16 rows
__global__ __launch_bounds__(256) void k_gather2v(const int* __restrict__ indptr,
        const uint2* __restrict__ eg, const float* __restrict__ ap2,
        const float* __restrict__ invden2, const unsigned int* __restrict__ z2b,
        float* __restrict__ hB, int N){
  int t = threadIdx.x;
  int n = blockIdx.x*8 + (t >> 5);
  if (n >= N) return;
  int l = t & 31;
  int beg = indptr[n], end = indptr[n+1];
  float a0 = 0.f, a1 = 0.f;
  for (int j = beg; j < end; j++){
    int a = (int)eg[j].x;
    float wgt = ap2[j];
    unsigned int u = z2b[(size_t)a*32 + l];
    a0 += wgt*bflo(u);
    a1 += wgt*bfhi(u);
  }
  float iv = invden2[n];
  *(float2*)(hB + (size_t)n*64 + l*2) = make_float2(a0*iv, a1*iv);
}

// per-node split of edge predictor: ps = hB@Wp[0:64], pd = hB@Wp[64:128]
__global__ __launch_bounds__(256) void k_ppred(const float* __restrict__ hB,
        const float* __restrict__ Wp, float* __restrict__ ps,
        float* __restrict__ pd, int N){
  __shared__ float lwp[256];
  int t = threadIdx.x;
  lwp[t] = Wp[t];
  __syncthreads();
  int n = blockIdx.x*256 + t;
  if (n >= N) return;
  const float4* r = (const float4*)(hB + (size_t)n*64);
  float s0 = 0.f, s1 = 0.f, d0 = 0.f, d1 = 0.f;
  #pragma unroll
  for (int q = 0; q < 16; q++){
    float4 v = r[q];
    int k = q*4;
    s0 += v.x*lwp[(k+0)*2]   + v.y*lwp[(k+1)*2]   + v.z*lwp[(k+2)*2]   + v.w*lwp[(k+3)*2];
    s1 += v.x*lwp[(k+0)*2+1] + v.y*lwp[(k+1)*2+1] + v.z*lwp[(k+2)*2+1] + v.w*lwp[(k+3)*2+1];
    d0 += v.x*lwp[128+(k+0)*2]   + v.y*lwp[128+(k+1)*2]   + v.z*lwp[128+(k+2)*2]   + v.w*lwp[128+(k+3)*2];
    d1 += v.x*lwp[128+(k+0)*2+1] + v.y*lwp[128+(k+1)*2+1] + v.z*lwp[128+(k+2)*2+1] + v.w*lwp[128+(k+3)*2+1];
  }
  ps[(size_t)n*2]   = s0; ps[(size_t)n*2+1] = s1;
  pd[(size_t)n*2]   = d0; pd[(size_t)n*2+1] = d1;
}

__global__ void k_edgepred(const int* __restrict__ src, const int* __restrict__ dst,
                           const float* __restrict__ ps, const float* __restrict__ pd,
                           const float* __restrict__ bp, float* __restrict__ out, int E){
  int e = blockIdx.x*blockDim.x + threadIdx.x;
  if (e >= E) return;
  int a = src[e], b = dst[e];
  float2 vs = ((const float2*)ps)[a];
  float2 vd = ((const float2*)pd)[b];
  float2 o;
  o.x = vs.x + vd.x + bp[0];
  o.y = vs.y + vd.y + bp[1];
  ((float2*)out)[e] = o;
}

extern "C" void kernel_launch(void* const* d_in, const int* in_sizes, int n_in,
                              void* d_out, int out_size, void* d_ws, size_t ws_size,
                              hipStream_t stream) {
  const float* h   = (const float*)d_in[0];
  const int*   src = (const int*)d_in[1];
  const int*   dst = (const int*)d_in[2];
  const float* W1  = (const float*)d_in[3];
  const float* b1  = (const float*)d_in[4];
  const float* W2  = (const float*)d_in[5];
  const float* b2  = (const float*)d_in[6];
  const float* W3  = (const float*)d_in[7];
  const float* b3  = (const float*)d_in[8];
  const float* fc1 = (const float*)d_in[9];
  const float* a1s = (const float*)d_in[10];
  const float* a1d = (const float*)d_in[11];
  const float* fc2 = (const float*)d_in[12];
  const float* a2s = (const float*)d_in[13];
  const float* a2d = (const float*)d_in[14];
  const float* Wp  = (const float*)d_in[15];
  const float* bp  = (const float*)d_in[16];

  const int N = in_sizes[0] / 128;
  const int E = in_sizes[1];

  float* out_score = (float*)d_out;             // [E,2]
  float* gate      = out_score + (size_t)E*2;   // [E]

  char* w = (char*)d_ws;
  size_t off = 0;
  auto alloc = [&](size_t bytes) -> void* {
    off = (off + 255) & ~(size_t)255;
    void* p = w + off; off += bytes; return p;
  };
  float* u_s  = (float*)alloc((size_t)N*8*4);
  float* u_d  = (float*)alloc((size_t)N*8*4);
  unsigned short* z1u = (unsigned short*)alloc((size_t)N*256*2);  // bf16 [N,256]
  float* es1  = (float*)alloc((size_t)N*8*4);
  float* ed1  = (float*)alloc((size_t)N*8*4);
  float* sbuf = (float*)alloc((size_t)E*4);
  unsigned short* hAu = (unsigned short*)alloc((size_t)N*256*2);  // bf16 [N,256]
  float* ap   = (float*)alloc((size_t)E*8*4);
  float* invden1 = (float*)alloc((size_t)N*8*4);
  float* es2  = (float*)alloc((size_t)N*4);
  float* ed2  = (float*)alloc((size_t)N*4);
  float* invden2 = (float*)alloc((size_t)N*4);
  float* minmax = (float*)alloc(2*4);
  int* counts = (int*)alloc((size_t)N*4);
  int* indptr = (int*)alloc(((size_t)N+1)*4);
  int* blockSums = (int*)alloc(1024*4);
  const int GATE_B = (E + 255)/256;
  float2* pmm = (float2*)alloc((size_t)GATE_B*8);
  uint2* eg   = (uint2*)alloc((size_t)E*8);
  unsigned short* wp1 = (unsigned short*)alloc(32768*2);
  unsigned short* wp2 = (unsigned short*)alloc(16384*2);
  (void)ws_size; (void)n_in; (void)out_size;

  // reuse: z1u dead after gather1v -> z2u (N*64 bf16 = first 6.4MB) and
  // hB fp32 [N,64] right after it (12.8MB; total 19.2MB <= 25.6MB region).
  unsigned short* z2u = z1u;
  float* hB = (float*)(z1u + (size_t)N*64);
  float* ap2 = ap;
  float* ps  = u_s;
  float* pd  = u_d;

  const int SCAN_B = (N + 1023)/1024;

  k_init<<<(N + 255)/256, 256, 0, stream>>>(counts, N);
  k_h1u<<<(N + 15)/16, 256, 0, stream>>>(h, W1, b1, W2, u_s, u_d, N);
  k_wpack1<<<128, 256, 0, stream>>>(fc1, wp1);
  k_wpack2<<<64, 256, 0, stream>>>(fc2, wp2);
  k_z1m<<<(N + 63)/64, 256, 0, stream>>>(h, wp1, z1u, N);
  k_es_ed1<<<(N*8 + 255)/256, 256, 0, stream>>>(z1u, a1s, a1d, es1, ed1, N);
  k_gate_edge<<<GATE_B, 256, 0, stream>>>(u_s, u_d, src, dst, b2, W3, b3,
                                          sbuf, counts, pmm, E);
  k_scan1<<<SCAN_B, 256, 0, stream>>>(counts, indptr, blockSums, N);
  k_scan2<<<1, 64, 0, stream>>>(blockSums, indptr, SCAN_B, N, pmm, GATE_B, minmax);
  k_scan3<<<(N + 255)/256, 256, 0, stream>>>(indptr, blockSums, counts, N);
  k_scatter<<<(E + 255)/256, 256, 0, stream>>>(src, dst, sbuf, minmax, gate,
                                               counts, eg, E);
  k_alpha1<<<(N*8 + 255)/256, 256, 0, stream>>>(indptr, eg, es1, ed1, ap, invden1, N);
  k_gather1v<<<(N + 3)/4, 256, 0, stream>>>(indptr, eg, ap, invden1,
                                            (const unsigned int*)z1u,
                                            (unsigned int*)hAu, N);
  k_z2m<<<(N + 63)/64, 256, 0, stream>>>(hAu, wp2, z2u, N);
  k_es_ed2<<<(N + 255)/256, 256, 0, stream>>>(z2u, a2s, a2d, es2, ed2, N);
  k_alpha2<<<(N + 255)/256, 256, 0, stream>>>(indptr, eg, es2, ed2, ap2, invden2, N);
  k_gather2v<<<(N + 7)/8, 256, 0, stream>>>(indptr, eg, ap2, invden2,
                                            (const unsigned int*)z2u, hB, N);
  k_ppred<<<(N + 255)/256, 256, 0, stream>>>(hB, Wp, ps, pd, N);
  k_edgepred<<<(E + 255)/256, 256, 0, stream>>>(src, dst, ps, pd, bp, out_score, E);
}

// Round 9
// 325.497 us; speedup vs baseline: 3.9432x; 1.0888x over previous
//
#include <hip/hip_runtime.h>
#include <math.h>

#define FINF __builtin_inff()

using short8  = __attribute__((ext_vector_type(8))) short;
using floatx4 = __attribute__((ext_vector_type(4))) float;
union U4 { uint4 u; short8 s; };

__device__ __forceinline__ float leaky(float x){ return x > 0.f ? x : 0.01f*x; }

// fp32 -> bf16 (RNE) and pack two into a u32
__device__ __forceinline__ unsigned int f2bf(float f){
  unsigned int x = __float_as_uint(f);
  x += 0x7FFFu + ((x >> 16) & 1u);
  return x >> 16;
}
__device__ __forceinline__ unsigned int pack2(float lo, float hi){
  return f2bf(lo) | (f2bf(hi) << 16);
}
__device__ __forceinline__ float bflo(unsigned int u){ return __uint_as_float(u << 16); }
__device__ __forceinline__ float bfhi(unsigned int u){ return __uint_as_float(u & 0xFFFF0000u); }

__global__ void k_init(int* counts, int N){
  int i = blockIdx.x*blockDim.x + threadIdx.x;
  if (i < N) counts[i] = 0;
}

// fused: h1 = h@W1+b1 (LDS only), then u_s = h1@W2[0:16], u_d = h1@W2[16:32]
__global__ __launch_bounds__(256) void k_h1u(const float* __restrict__ h,
        const float* __restrict__ W1, const float* __restrict__ b1,
        const float* __restrict__ W2,
        float* __restrict__ u_s, float* __restrict__ u_d, int N){
  __shared__ float lh[16][132];
  __shared__ float lw[128][16];
  __shared__ float lh1[16][17];
  int t = threadIdx.x;
  int n0 = blockIdx.x*16;
  const float4* w4 = (const float4*)W1;
  ((float4*)&lw[0][0])[t]       = w4[t];
  ((float4*)&lw[0][0])[t + 256] = w4[t + 256];
  const float4* h4 = (const float4*)(h + (size_t)n0*128);
  {
    int idx = t, row = idx >> 5, c4 = idx & 31;
    *(float4*)&lh[row][c4*4] = (n0+row < N) ? h4[idx] : make_float4(0,0,0,0);
    idx = t + 256; row = idx >> 5; c4 = idx & 31;
    *(float4*)&lh[row][c4*4] = (n0+row < N) ? h4[idx] : make_float4(0,0,0,0);
  }
  __syncthreads();
  int nl = t >> 4, j = t & 15;
  float s = b1[j];
  #pragma unroll 8
  for (int k = 0; k < 128; k++) s += lh[nl][k]*lw[k][j];
  lh1[nl][j] = s;
  __syncthreads();
  int n = n0 + nl;
  if (n < N){
    float acc = 0.f;
    if (j < 8){
      #pragma unroll
      for (int k = 0; k < 16; k++) acc += lh1[nl][k]*W2[k*8 + j];
      u_s[(size_t)n*8 + j] = acc;
    } else {
      int jj = j - 8;
      #pragma unroll
      for (int k = 0; k < 16; k++) acc += lh1[nl][k]*W2[(16 + k)*8 + jj];
      u_d[(size_t)n*8 + jj] = acc;
    }
  }
}

// repack fc1 [8][128][32] -> bf16 B-fragment order
__global__ void k_wpack1(const float* __restrict__ fc1, unsigned short* __restrict__ wp1){
  int idx = blockIdx.x*256 + threadIdx.x;
  if (idx >= 32768) return;
  int i  = idx & 7;
  int l  = (idx >> 3) & 63;
  int kk = (idx >> 9) & 3;
  int nt = idx >> 11;
  int n = nt*16 + (l & 15);
  int k = kk*32 + ((l >> 4) << 3) + i;
  wp1[idx] = (unsigned short)f2bf(fc1[(size_t)(n >> 5)*4096 + k*32 + (n & 31)]);
}

// repack fc2 [256][64] similarly
__global__ void k_wpack2(const float* __restrict__ fc2, unsigned short* __restrict__ wp2){
  int idx = blockIdx.x*256 + threadIdx.x;
  if (idx >= 16384) return;
  int i  = idx & 7;
  int l  = (idx >> 3) & 63;
  int kk = (idx >> 9) & 7;
  int nt = idx >> 12;
  int n = nt*16 + (l & 15);
  int k = kk*32 + ((l >> 4) << 3) + i;
  wp2[idx] = (unsigned short)f2bf(fc2[(size_t)k*64 + n]);
}

// z1 = h @ fc1 via MFMA bf16: 64-row tile, 4 waves x 16 rows, N=256, K=128
__global__ __launch_bounds__(256) void k_z1m(const float* __restrict__ h,
        const unsigned short* __restrict__ wp1, unsigned short* __restrict__ z1u,
        int N){
  __shared__ uint4 lw[4096];   // 64KB staged weights
  int t = threadIdx.x;
  const uint4* wp4 = (const uint4*)wp1;
  #pragma unroll
  for (int i = 0; i < 16; i++) lw[t + i*256] = wp4[t + i*256];
  __syncthreads();
  int l = t & 63, wv = t >> 6;
  int n0 = blockIdx.x*64, m0 = wv*16;
  int rowA = min(n0 + m0 + (l & 15), N-1);
  const float* hr = h + (size_t)rowA*128 + ((l >> 4) << 3);
  U4 a[4];
  #pragma unroll
  for (int kk = 0; kk < 4; kk++){
    float4 f0 = *(const float4*)(hr + kk*32);
    float4 f1 = *(const float4*)(hr + kk*32 + 4);
    a[kk].u.x = pack2(f0.x, f0.y); a[kk].u.y = pack2(f0.z, f0.w);
    a[kk].u.z = pack2(f1.x, f1.y); a[kk].u.w = pack2(f1.z, f1.w);
  }
  int node0 = n0 + m0 + ((l >> 4) << 2);
  #pragma unroll
  for (int nt = 0; nt < 16; nt++){
    floatx4 acc = {0.f, 0.f, 0.f, 0.f};
    #pragma unroll
    for (int kk = 0; kk < 4; kk++){
      U4 b; b.u = lw[(nt*4 + kk)*64 + l];
      acc = __builtin_amdgcn_mfma_f32_16x16x32_bf16(a[kk].s, b.s, acc, 0, 0, 0);
    }
    int col = nt*16 + (l & 15);
    #pragma unroll
    for (int i2 = 0; i2 < 4; i2++){
      int node = node0 + i2;
      if (node < N) z1u[(size_t)node*256 + col] = (unsigned short)f2bf(acc[i2]);
    }
  }
}

// es1/ed1 from bf16 z1
__global__ void k_es_ed1(const unsigned short* __restrict__ z1u,
                         const float* __restrict__ a1s, const float* __restrict__ a1d,
                         float* __restrict__ es1, float* __restrict__ ed1, int N){
  int i = blockIdx.x*blockDim.x + threadIdx.x;
  if (i >= N*8) return;
  int n = i >> 3, hh = i & 7;
  const uint4* zr = (const uint4*)(z1u + (size_t)n*256 + hh*32);
  const float* as = a1s + hh*32;
  const float* ad = a1d + hh*32;
  float s0 = 0.f, s1 = 0.f;
  #pragma unroll
  for (int q = 0; q < 4; q++){
    uint4 v = zr[q];
    int o = q*8;
    s0 += bflo(v.x)*as[o+0] + bfhi(v.x)*as[o+1] + bflo(v.y)*as[o+2] + bfhi(v.y)*as[o+3]
        + bflo(v.z)*as[o+4] + bfhi(v.z)*as[o+5] + bflo(v.w)*as[o+6] + bfhi(v.w)*as[o+7];
    s1 += bflo(v.x)*ad[o+0] + bfhi(v.x)*ad[o+1] + bflo(v.y)*ad[o+2] + bfhi(v.y)*ad[o+3]
        + bflo(v.z)*ad[o+4] + bfhi(v.z)*ad[o+5] + bflo(v.w)*ad[o+6] + bfhi(v.w)*ad[o+7];
  }
  es1[i] = s0; ed1[i] = s1;
}

// gate edge score; dst histogram; per-block (min,max) partials (no global atomics)
__global__ __launch_bounds__(256) void k_gate_edge(const float* __restrict__ u_s,
        const float* __restrict__ u_d,
        const int* __restrict__ src, const int* __restrict__ dst,
        const float* __restrict__ b2, const float* __restrict__ W3,
        const float* __restrict__ b3,
        float* __restrict__ sbuf, int* __restrict__ counts,
        float2* __restrict__ pmm, int E){
  __shared__ float lb2[8], lw3[8];
  __shared__ float lb3;
  __shared__ float rmin[4], rmax[4];
  int t = threadIdx.x;
  if (t < 8){ lb2[t] = b2[t]; lw3[t] = W3[t]; }
  if (t == 8) lb3 = b3[0];
  __syncthreads();
  int e = blockIdx.x*blockDim.x + t;
  float s = 0.f;
  bool valid = (e < E);
  if (valid){
    int a = src[e], b = dst[e];
    float4 us0 = ((const float4*)(u_s + (size_t)a*8))[0];
    float4 us1 = ((const float4*)(u_s + (size_t)a*8))[1];
    float4 ud0 = ((const float4*)(u_d + (size_t)b*8))[0];
    float4 ud1 = ((const float4*)(u_d + (size_t)b*8))[1];
    float tv[8] = { us0.x+ud0.x, us0.y+ud0.y, us0.z+ud0.z, us0.w+ud0.w,
                    us1.x+ud1.x, us1.y+ud1.y, us1.z+ud1.z, us1.w+ud1.w };
    s = lb3;
    #pragma unroll
    for (int j = 0; j < 8; j++) s += fmaxf(tv[j] + lb2[j], 0.f)*lw3[j];
    sbuf[e] = s;
    atomicAdd(&counts[b], 1);
  }
  float vmin = valid ? s : FINF;
  float vmax = valid ? s : -FINF;
  #pragma unroll
  for (int o = 32; o > 0; o >>= 1){
    vmin = fminf(vmin, __shfl_xor(vmin, o));
    vmax = fmaxf(vmax, __shfl_xor(vmax, o));
  }
  if ((t & 63) == 0){ rmin[t >> 6] = vmin; rmax[t >> 6] = vmax; }
  __syncthreads();
  if (t == 0){
    float mn = fminf(fminf(rmin[0], rmin[1]), fminf(rmin[2], rmin[3]));
    float mx = fmaxf(fmaxf(rmax[0], rmax[1]), fmaxf(rmax[2], rmax[3]));
    pmm[blockIdx.x] = make_float2(mn, mx);
  }
}

// ---- device-wide exclusive scan (3 kernels) ----
__global__ __launch_bounds__(256) void k_scan1(const int* __restrict__ counts,
        int* __restrict__ indptr, int* __restrict__ blockSums, int N){
  __shared__ int wsum[4];
  int t = threadIdx.x;
  int base = blockIdx.x*1024 + t*4;
  int c[4];
  #pragma unroll
  for (int i = 0; i < 4; i++) c[i] = (base + i < N) ? counts[base + i] : 0;
  int s = c[0] + c[1] + c[2] + c[3];
  int lane = t & 63, wid = t >> 6;
  int inc = s;
  #pragma unroll
  for (int o = 1; o < 64; o <<= 1){
    int v = __shfl_up(inc, o);
    if (lane >= o) inc += v;
  }
  if (lane == 63) wsum[wid] = inc;
  __syncthreads();
  int woff = 0;
  #pragma unroll
  for (int i = 0; i < 4; i++) if (i < wid) woff += wsum[i];
  int run = woff + inc - s;
  #pragma unroll
  for (int i = 0; i < 4; i++){
    if (base + i < N) indptr[base + i] = run;
    run += c[i];
  }
  if (t == 255) blockSums[blockIdx.x] = woff + inc;
}

__global__ __launch_bounds__(64) void k_scan2(int* __restrict__ blockSums,
        int* __restrict__ indptr, int B, int N,
        const float2* __restrict__ pmm, int GB, float* __restrict__ minmax){
  int t = threadIdx.x;
  int carry = 0;
  for (int b0 = 0; b0 < B; b0 += 64){
    int idx = b0 + t;
    int v = (idx < B) ? blockSums[idx] : 0;
    int inc = v;
    #pragma unroll
    for (int o = 1; o < 64; o <<= 1){
      int u = __shfl_up(inc, o);
      if (t >= o) inc += u;
    }
    if (idx < B) blockSums[idx] = carry + inc - v;
    carry += __shfl(inc, 63);
  }
  if (t == 0) indptr[N] = carry;
  float mn = FINF, mx = -FINF;
  for (int i = t; i < GB; i += 64){
    float2 v = pmm[i];
    mn = fminf(mn, v.x);
    mx = fmaxf(mx, v.y);
  }
  #pragma unroll
  for (int o = 32; o > 0; o >>= 1){
    mn = fminf(mn, __shfl_xor(mn, o));
    mx = fmaxf(mx, __shfl_xor(mx, o));
  }
  if (t == 0){ minmax[0] = mn; minmax[1] = mx; }
}

__global__ __launch_bounds__(256) void k_scan3(int* __restrict__ indptr,
        const int* __restrict__ blockSums, int* __restrict__ cursor, int N){
  int i = blockIdx.x*blockDim.x + threadIdx.x;
  if (i >= N) return;
  int v = indptr[i] + blockSums[i >> 10];
  indptr[i] = v;
  cursor[i] = v;
}

// fused gate-normalize + CSR scatter; (src,gate) packed into one uint2
__global__ void k_scatter(const int* __restrict__ src, const int* __restrict__ dst,
                          const float* __restrict__ sbuf, const float* __restrict__ minmax,
                          float* __restrict__ gate_out, int* __restrict__ cursor,
                          uint2* __restrict__ eg, int E){
  int e = blockIdx.x*blockDim.x + threadIdx.x;
  if (e >= E) return;
  float mn = minmax[0], mx = minmax[1];
  float g = (sbuf[e] - mn) / (mx - mn);
  gate_out[e] = g;
  int pos = atomicAdd(&cursor[dst[e]], 1);
  uint2 v; v.x = (unsigned int)src[e]; v.y = __float_as_uint(g);
  eg[pos] = v;
}

// fused layer1 softmax+aggregation: one wave per dst node. Staging lane computes
// all 8 heads' exp-weights inline (single-pass, bounded logits); inner loop
// accumulates den online. Writes hA as bf16.
__global__ __launch_bounds__(256) void k_gather1f(const int* __restrict__ indptr,
        const uint2* __restrict__ eg, const float* __restrict__ es1,
        const float* __restrict__ ed1, const unsigned int* __restrict__ z1b,
        unsigned int* __restrict__ hAb, int N){
  __shared__ float lap[4][64][8];
  int t = threadIdx.x;
  int w = t >> 6, lane = t & 63;
  int n = blockIdx.x*4 + w;
  if (n >= N) return;
  int hh = lane >> 3;
  float4 ev0 = *(const float4*)(ed1 + (size_t)n*8);
  float4 ev1 = *(const float4*)(ed1 + (size_t)n*8 + 4);
  int beg = indptr[n], end = indptr[n+1];
  float4 acc = make_float4(0.f,0.f,0.f,0.f);
  float den = 0.f;
  for (int c = beg; c < end; c += 64){
    int len = min(64, end - c);
    int sv = 0;
    if (lane < len){
      uint2 v = eg[c + lane];
      sv = (int)v.x;
      float g = __uint_as_float(v.y);
      float4 e0 = *(const float4*)(es1 + (size_t)sv*8);
      float4 e1 = *(const float4*)(es1 + (size_t)sv*8 + 4);
      float4 w0, w1;
      w0.x = __expf(leaky(e0.x + ev0.x)*g);
      w0.y = __expf(leaky(e0.y + ev0.y)*g);
      w0.z = __expf(leaky(e0.z + ev0.z)*g);
      w0.w = __expf(leaky(e0.w + ev0.w)*g);
      w1.x = __expf(leaky(e1.x + ev1.x)*g);
      w1.y = __expf(leaky(e1.y + ev1.y)*g);
      w1.z = __expf(leaky(e1.z + ev1.z)*g);
      w1.w = __expf(leaky(e1.w + ev1.w)*g);
      *(float4*)&lap[w][lane][0] = w0;
      *(float4*)&lap[w][lane][4] = w1;
    }
    __builtin_amdgcn_wave_barrier();
    for (int jj = 0; jj < len; jj++){
      int a = __shfl(sv, jj);
      float wgt = lap[w][jj][hh];
      uint2 zv = *(const uint2*)(z1b + (size_t)a*128 + lane*2);
      den += wgt;
      acc.x += wgt*bflo(zv.x); acc.y += wgt*bfhi(zv.x);
      acc.z += wgt*bflo(zv.y); acc.w += wgt*bfhi(zv.y);
    }
    __builtin_amdgcn_wave_barrier();
  }
  float iv = 1.f / fmaxf(den, 1e-12f);
  uint2 o;
  o.x = pack2(leaky(acc.x*iv), leaky(acc.y*iv));
  o.y = pack2(leaky(acc.z*iv), leaky(acc.w*iv));
  *(uint2*)(hAb + (size_t)n*128 + lane*2) = o;
}

// z2 = hA @ fc2 via MFMA bf16: 64-row tile, N=64, K=256
__global__ __launch_bounds__(256) void k_z2m(const unsigned short* __restrict__ hAu,
        const unsigned short* __restrict__ wp2, unsigned short* __restrict__ z2u,
        int N){
  __shared__ uint4 lw[2048];   // 32KB
  int t = threadIdx.x;
  const uint4* wp4 = (const uint4*)wp2;
  #pragma unroll
  for (int i = 0; i < 8; i++) lw[t + i*256] = wp4[t + i*256];
  __syncthreads();
  int l = t & 63, wv = t >> 6;
  int n0 = blockIdx.x*64, m0 = wv*16;
  int rowA = min(n0 + m0 + (l & 15), N-1);
  const unsigned short* ar = hAu + (size_t)rowA*256 + ((l >> 4) << 3);
  U4 a[8];
  #pragma unroll
  for (int kk = 0; kk < 8; kk++)
    a[kk].u = *(const uint4*)(ar + kk*32);
  int node0 = n0 + m0 + ((l >> 4) << 2);
  #pragma unroll
  for (int nt = 0; nt < 4; nt++){
    floatx4 acc = {0.f, 0.f, 0.f, 0.f};
    #pragma unroll
    for (int kk = 0; kk < 8; kk++){
      U4 b; b.u = lw[(nt*8 + kk)*64 + l];
      acc = __builtin_amdgcn_mfma_f32_16x16x32_bf16(a[kk].s, b.s, acc, 0, 0, 0);
    }
    int col = nt*16 + (l & 15);
    #pragma unroll
    for (int i2 = 0; i2 < 4; i2++){
      int node = node0 + i2;
      if (node < N) z2u[(size_t)node*64 + col] = (unsigned short)f2bf(acc[i2]);
    }
  }
}

// es2/ed2 from bf16 z2
__global__ void k_es_ed2(const unsigned short* __restrict__ z2u,
                         const float* __restrict__ a2s, const float* __restrict__ a2d,
                         float* __restrict__ es2, float* __restrict__ ed2, int N){
  int n = blockIdx.x*blockDim.x + threadIdx.x;
  if (n >= N) return;
  const uint4* zr = (const uint4*)(z2u + (size_t)n*64);
  float s0 = 0.f, s1 = 0.f;
  #pragma unroll
  for (int q = 0; q < 8; q++){
    uint4 v = zr[q];
    int o = q*8;
    s0 += bflo(v.x)*a2s[o+0] + bfhi(v.x)*a2s[o+1] + bflo(v.y)*a2s[o+2] + bfhi(v.y)*a2s[o+3]
        + bflo(v.z)*a2s[o+4] + bfhi(v.z)*a2s[o+5] + bflo(v.w)*a2s[o+6] + bfhi(v.w)*a2s[o+7];
    s1 += bflo(v.x)*a2d[o+0] + bfhi(v.x)*a2d[o+1] + bflo(v.y)*a2d[o+2] + bfhi(v.y)*a2d[o+3]
        + bflo(v.z)*a2d[o+4] + bfhi(v.z)*a2d[o+5] + bflo(v.w)*a2d[o+6] + bfhi(v.w)*a2d[o+7];
  }
  es2[n] = s0; ed2[n] = s1;
}

// fused layer2 softmax+aggregation: half-wave per dst node; weight computed
// in-register per edge (uniform within the 32-lane group)
__global__ __launch_bounds__(256) void k_gather2f(const int* __restrict__ indptr,
        const uint2* __restrict__ eg, const float* __restrict__ es2,
        const float* __restrict__ ed2, const unsigned int* __restrict__ z2b,
        float* __restrict__ hB, int N){
  int t = threadIdx.x;
  int n = blockIdx.x*8 + (t >> 5);
  if (n >= N) return;
  int l = t & 31;
  float ed = ed2[n];
  int beg = indptr[n], end = indptr[n+1];
  float a0 = 0.f, a1 = 0.f, den = 0.f;
  for (int j = beg; j < end; j++){
    uint2 v = eg[j];
    int a = (int)v.x;
    float wgt = __expf(leaky(es2[a] + ed) * __uint_as_float(v.y));
    unsigned int u = z2b[(size_t)a*32 + l];
    den += wgt;
    a0 += wgt*bflo(u);
    a1 += wgt*bfhi(u);
  }
  float iv = 1.f / fmaxf(den, 1e-12f);
  *(float2*)(hB + (size_t)n*64 + l*2) = make_float2(a0*iv, a1*iv);
}

// per-node split of edge predictor: ps = hB@Wp[0:64], pd = hB@Wp[64:128]
__global__ __launch_bounds__(256) void k_ppred(const float* __restrict__ hB,
        const float* __restrict__ Wp, float* __restrict__ ps,
        float* __restrict__ pd, int N){
  __shared__ float lwp[256];
  int t = threadIdx.x;
  lwp[t] = Wp[t];
  __syncthreads();
  int n = blockIdx.x*256 + t;
  if (n >= N) return;
  const float4* r = (const float4*)(hB + (size_t)n*64);
  float s0 = 0.f, s1 = 0.f, d0 = 0.f, d1 = 0.f;
  #pragma unroll
  for (int q = 0; q < 16; q++){
    float4 v = r[q];
    int k = q*4;
    s0 += v.x*lwp[(k+0)*2]   + v.y*lwp[(k+1)*2]   + v.z*lwp[(k+2)*2]   + v.w*lwp[(k+3)*2];
    s1 += v.x*lwp[(k+0)*2+1] + v.y*lwp[(k+1)*2+1] + v.z*lwp[(k+2)*2+1] + v.w*lwp[(k+3)*2+1];
    d0 += v.x*lwp[128+(k+0)*2]   + v.y*lwp[128+(k+1)*2]   + v.z*lwp[128+(k+2)*2]   + v.w*lwp[128+(k+3)*2];
    d1 += v.x*lwp[128+(k+0)*2+1] + v.y*lwp[128+(k+1)*2+1] + v.z*lwp[128+(k+2)*2+1] + v.w*lwp[128+(k+3)*2+1];
  }
  ps[(size_t)n*2]   = s0; ps[(size_t)n*2+1] = s1;
  pd[(size_t)n*2]   = d0; pd[(size_t)n*2+1] = d1;
}

__global__ void k_edgepred(const int* __restrict__ src, const int* __restrict__ dst,
                           const float* __restrict__ ps, const float* __restrict__ pd,
                           const float* __restrict__ bp, float* __restrict__ out, int E){
  int e = blockIdx.x*blockDim.x + threadIdx.x;
  if (e >= E) return;
  int a = src[e], b = dst[e];
  float2 vs = ((const float2*)ps)[a];
  float2 vd = ((const float2*)pd)[b];
  float2 o;
  o.x = vs.x + vd.x + bp[0];
  o.y = vs.y + vd.y + bp[1];
  ((float2*)out)[e] = o;
}

extern "C" void kernel_launch(void* const* d_in, const int* in_sizes, int n_in,
                              void* d_out, int out_size, void* d_ws, size_t ws_size,
                              hipStream_t stream) {
  const float* h   = (const float*)d_in[0];
  const int*   src = (const int*)d_in[1];
  const int*   dst = (const int*)d_in[2];
  const float* W1  = (const float*)d_in[3];
  const float* b1  = (const float*)d_in[4];
  const float* W2  = (const float*)d_in[5];
  const float* b2  = (const float*)d_in[6];
  const float* W3  = (const float*)d_in[7];
  const float* b3  = (const float*)d_in[8];
  const float* fc1 = (const float*)d_in[9];
  const float* a1s = (const float*)d_in[10];
  const float* a1d = (const float*)d_in[11];
  const float* fc2 = (const float*)d_in[12];
  const float* a2s = (const float*)d_in[13];
  const float* a2d = (const float*)d_in[14];
  const float* Wp  = (const float*)d_in[15];
  const float* bp  = (const float*)d_in[16];

  const int N = in_sizes[0] / 128;
  const int E = in_sizes[1];

  float* out_score = (float*)d_out;             // [E,2]
  float* gate      = out_score + (size_t)E*2;   // [E]

  char* w = (char*)d_ws;
  size_t off = 0;
  auto alloc = [&](size_t bytes) -> void* {
    off = (off + 255) & ~(size_t)255;
    void* p = w + off; off += bytes; return p;
  };
  float* u_s  = (float*)alloc((size_t)N*8*4);
  float* u_d  = (float*)alloc((size_t)N*8*4);
  unsigned short* z1u = (unsigned short*)alloc((size_t)N*256*2);  // bf16 [N,256]
  float* es1  = (float*)alloc((size_t)N*8*4);
  float* ed1  = (float*)alloc((size_t)N*8*4);
  float* sbuf = (float*)alloc((size_t)E*4);
  unsigned short* hAu = (unsigned short*)alloc((size_t)N*256*2);  // bf16 [N,256]
  float* es2  = (float*)alloc((size_t)N*4);
  float* ed2  = (float*)alloc((size_t)N*4);
  float* minmax = (float*)alloc(2*4);
  int* counts = (int*)alloc((size_t)N*4);
  int* indptr = (int*)alloc(((size_t)N+1)*4);
  int* blockSums = (int*)alloc(1024*4);
  const int GATE_B = (E + 255)/256;
  float2* pmm = (float2*)alloc((size_t)GATE_B*8);
  uint2* eg   = (uint2*)alloc((size_t)E*8);
  unsigned short* wp1 = (unsigned short*)alloc(32768*2);
  unsigned short* wp2 = (unsigned short*)alloc(16384*2);
  (void)ws_size; (void)n_in; (void)out_size;

  // reuse: z1u dead after gather1f -> z2u (bf16 [N,64]) + hB fp32 [N,64] after it
  unsigned short* z2u = z1u;
  float* hB = (float*)(z1u + (size_t)N*64);
  float* ps  = u_s;
  float* pd  = u_d;

  const int SCAN_B = (N + 1023)/1024;

  k_init<<<(N + 255)/256, 256, 0, stream>>>(counts, N);
  k_h1u<<<(N + 15)/16, 256, 0, stream>>>(h, W1, b1, W2, u_s, u_d, N);
  k_wpack1<<<128, 256, 0, stream>>>(fc1, wp1);
  k_wpack2<<<64, 256, 0, stream>>>(fc2, wp2);
  k_z1m<<<(N + 63)/64, 256, 0, stream>>>(h, wp1, z1u, N);
  k_es_ed1<<<(N*8 + 255)/256, 256, 0, stream>>>(z1u, a1s, a1d, es1, ed1, N);
  k_gate_edge<<<GATE_B, 256, 0, stream>>>(u_s, u_d, src, dst, b2, W3, b3,
                                          sbuf, counts, pmm, E);
  k_scan1<<<SCAN_B, 256, 0, stream>>>(counts, indptr, blockSums, N);
  k_scan2<<<1, 64, 0, stream>>>(blockSums, indptr, SCAN_B, N, pmm, GATE_B, minmax);
  k_scan3<<<(N + 255)/256, 256, 0, stream>>>(indptr, blockSums, counts, N);
  k_scatter<<<(E + 255)/256, 256, 0, stream>>>(src, dst, sbuf, minmax, gate,
                                               counts, eg, E);
  k_gather1f<<<(N + 3)/4, 256, 0, stream>>>(indptr, eg, es1, ed1,
                                            (const unsigned int*)z1u,
                                            (unsigned int*)hAu, N);
  k_z2m<<<(N + 63)/64, 256, 0, stream>>>(hAu, wp2, z2u, N);
  k_es_ed2<<<(N + 255)/256, 256, 0, stream>>>(z2u, a2s, a2d, es2, ed2, N);
  k_gather2f<<<(N + 7)/8, 256, 0, stream>>>(indptr, eg, es2, ed2,
                                            (const unsigned int*)z2u, hB, N);
  k_ppred<<<(N + 255)/256, 256, 0, stream>>>(hB, Wp, ps, pd, N);
  k_edgepred<<<(E + 255)/256, 256, 0, stream>>>(src, dst, ps, pd, bp, out_score, E);
}

// Round 10
// 261.265 us; speedup vs baseline: 4.9126x; 1.2458x over previous
//
#include <hip/hip_runtime.h>
#include <math.h>

#define FINF __builtin_inff()

using short8  = __attribute__((ext_vector_type(8))) short;
using floatx4 = __attribute__((ext_vector_type(4))) float;
union U4 { uint4 u; short8 s; };

__device__ __forceinline__ float leaky(float x){ return x > 0.f ? x : 0.01f*x; }

// fp32 -> bf16 (RNE) and pack two into a u32
__device__ __forceinline__ unsigned int f2bf(float f){
  unsigned int x = __float_as_uint(f);
  x += 0x7FFFu + ((x >> 16) & 1u);
  return x >> 16;
}
__device__ __forceinline__ unsigned int pack2(float lo, float hi){
  return f2bf(lo) | (f2bf(hi) << 16);
}
__device__ __forceinline__ float bflo(unsigned int u){ return __uint_as_float(u << 16); }
__device__ __forceinline__ float bfhi(unsigned int u){ return __uint_as_float(u & 0xFFFF0000u); }

__global__ void k_init(int* counts8, int M){
  int i = blockIdx.x*blockDim.x + threadIdx.x;
  if (i < M) counts8[i] = 0;
}

// fused: h1 = h@W1+b1 (LDS only), then u_s = h1@W2[0:16], u_d = h1@W2[16:32]
__global__ __launch_bounds__(256) void k_h1u(const float* __restrict__ h,
        const float* __restrict__ W1, const float* __restrict__ b1,
        const float* __restrict__ W2,
        float* __restrict__ u_s, float* __restrict__ u_d, int N){
  __shared__ float lh[16][132];
  __shared__ float lw[128][16];
  __shared__ float lh1[16][17];
  int t = threadIdx.x;
  int n0 = blockIdx.x*16;
  const float4* w4 = (const float4*)W1;
  ((float4*)&lw[0][0])[t]       = w4[t];
  ((float4*)&lw[0][0])[t + 256] = w4[t + 256];
  const float4* h4 = (const float4*)(h + (size_t)n0*128);
  {
    int idx = t, row = idx >> 5, c4 = idx & 31;
    *(float4*)&lh[row][c4*4] = (n0+row < N) ? h4[idx] : make_float4(0,0,0,0);
    idx = t + 256; row = idx >> 5; c4 = idx & 31;
    *(float4*)&lh[row][c4*4] = (n0+row < N) ? h4[idx] : make_float4(0,0,0,0);
  }
  __syncthreads();
  int nl = t >> 4, j = t & 15;
  float s = b1[j];
  #pragma unroll 8
  for (int k = 0; k < 128; k++) s += lh[nl][k]*lw[k][j];
  lh1[nl][j] = s;
  __syncthreads();
  int n = n0 + nl;
  if (n < N){
    float acc = 0.f;
    if (j < 8){
      #pragma unroll
      for (int k = 0; k < 16; k++) acc += lh1[nl][k]*W2[k*8 + j];
      u_s[(size_t)n*8 + j] = acc;
    } else {
      int jj = j - 8;
      #pragma unroll
      for (int k = 0; k < 16; k++) acc += lh1[nl][k]*W2[(16 + k)*8 + jj];
      u_d[(size_t)n*8 + jj] = acc;
    }
  }
}

// repack fc1+fc2 -> bf16 B-fragment order (one kernel)
__global__ void k_wpack(const float* __restrict__ fc1, const float* __restrict__ fc2,
                        unsigned short* __restrict__ wp1, unsigned short* __restrict__ wp2){
  int idx = blockIdx.x*256 + threadIdx.x;
  if (idx < 32768){
    int i  = idx & 7;
    int l  = (idx >> 3) & 63;
    int kk = (idx >> 9) & 3;
    int nt = idx >> 11;
    int n = nt*16 + (l & 15);
    int k = kk*32 + ((l >> 4) << 3) + i;
    wp1[idx] = (unsigned short)f2bf(fc1[(size_t)(n >> 5)*4096 + k*32 + (n & 31)]);
  } else if (idx < 49152){
    int j = idx - 32768;
    int i  = j & 7;
    int l  = (j >> 3) & 63;
    int kk = (j >> 9) & 7;
    int nt = j >> 12;
    int n = nt*16 + (l & 15);
    int k = kk*32 + ((l >> 4) << 3) + i;
    wp2[j] = (unsigned short)f2bf(fc2[(size_t)k*64 + n]);
  }
}

// z1 = h @ fc1 via MFMA bf16: 64-row tile, 4 waves x 16 rows, N=256, K=128
__global__ __launch_bounds__(256) void k_z1m(const float* __restrict__ h,
        const unsigned short* __restrict__ wp1, unsigned short* __restrict__ z1u,
        int N){
  __shared__ uint4 lw[4096];   // 64KB staged weights
  int t = threadIdx.x;
  const uint4* wp4 = (const uint4*)wp1;
  #pragma unroll
  for (int i = 0; i < 16; i++) lw[t + i*256] = wp4[t + i*256];
  __syncthreads();
  int l = t & 63, wv = t >> 6;
  int n0 = blockIdx.x*64, m0 = wv*16;
  int rowA = min(n0 + m0 + (l & 15), N-1);
  const float* hr = h + (size_t)rowA*128 + ((l >> 4) << 3);
  U4 a[4];
  #pragma unroll
  for (int kk = 0; kk < 4; kk++){
    float4 f0 = *(const float4*)(hr + kk*32);
    float4 f1 = *(const float4*)(hr + kk*32 + 4);
    a[kk].u.x = pack2(f0.x, f0.y); a[kk].u.y = pack2(f0.z, f0.w);
    a[kk].u.z = pack2(f1.x, f1.y); a[kk].u.w = pack2(f1.z, f1.w);
  }
  int node0 = n0 + m0 + ((l >> 4) << 2);
  #pragma unroll
  for (int nt = 0; nt < 16; nt++){
    floatx4 acc = {0.f, 0.f, 0.f, 0.f};
    #pragma unroll
    for (int kk = 0; kk < 4; kk++){
      U4 b; b.u = lw[(nt*4 + kk)*64 + l];
      acc = __builtin_amdgcn_mfma_f32_16x16x32_bf16(a[kk].s, b.s, acc, 0, 0, 0);
    }
    int col = nt*16 + (l & 15);
    #pragma unroll
    for (int i2 = 0; i2 < 4; i2++){
      int node = node0 + i2;
      if (node < N) z1u[(size_t)node*256 + col] = (unsigned short)f2bf(acc[i2]);
    }
  }
}

// es1/ed1 from bf16 z1
__global__ void k_es_ed1(const unsigned short* __restrict__ z1u,
                         const float* __restrict__ a1s, const float* __restrict__ a1d,
                         float* __restrict__ es1, float* __restrict__ ed1, int N){
  int i = blockIdx.x*blockDim.x + threadIdx.x;
  if (i >= N*8) return;
  int n = i >> 3, hh = i & 7;
  const uint4* zr = (const uint4*)(z1u + (size_t)n*256 + hh*32);
  const float* as = a1s + hh*32;
  const float* ad = a1d + hh*32;
  float s0 = 0.f, s1 = 0.f;
  #pragma unroll
  for (int q = 0; q < 4; q++){
    uint4 v = zr[q];
    int o = q*8;
    s0 += bflo(v.x)*as[o+0] + bfhi(v.x)*as[o+1] + bflo(v.y)*as[o+2] + bfhi(v.y)*as[o+3]
        + bflo(v.z)*as[o+4] + bfhi(v.z)*as[o+5] + bflo(v.w)*as[o+6] + bfhi(v.w)*as[o+7];
    s1 += bflo(v.x)*ad[o+0] + bfhi(v.x)*ad[o+1] + bflo(v.y)*ad[o+2] + bfhi(v.y)*ad[o+3]
        + bflo(v.z)*ad[o+4] + bfhi(v.z)*ad[o+5] + bflo(v.w)*ad[o+6] + bfhi(v.w)*ad[o+7];
  }
  es1[i] = s0; ed1[i] = s1;
}

// gate edge score; XCD-replicated dst histogram + per-edge rank; block (min,max)
__global__ __launch_bounds__(256) void k_gate_edge(const float* __restrict__ u_s,
        const float* __restrict__ u_d,
        const int* __restrict__ src, const int* __restrict__ dst,
        const float* __restrict__ b2, const float* __restrict__ W3,
        const float* __restrict__ b3,
        float* __restrict__ sbuf, int* __restrict__ counts8,
        int* __restrict__ rank, float2* __restrict__ pmm, int E, int N){
  __shared__ float lb2[8], lw3[8];
  __shared__ float lb3;
  __shared__ float rmin[4], rmax[4];
  int t = threadIdx.x;
  if (t < 8){ lb2[t] = b2[t]; lw3[t] = W3[t]; }
  if (t == 8) lb3 = b3[0];
  __syncthreads();
  int e = blockIdx.x*blockDim.x + t;
  float s = 0.f;
  bool valid = (e < E);
  if (valid){
    int a = src[e], b = dst[e];
    float4 us0 = ((const float4*)(u_s + (size_t)a*8))[0];
    float4 us1 = ((const float4*)(u_s + (size_t)a*8))[1];
    float4 ud0 = ((const float4*)(u_d + (size_t)b*8))[0];
    float4 ud1 = ((const float4*)(u_d + (size_t)b*8))[1];
    float tv[8] = { us0.x+ud0.x, us0.y+ud0.y, us0.z+ud0.z, us0.w+ud0.w,
                    us1.x+ud1.x, us1.y+ud1.y, us1.z+ud1.z, us1.w+ud1.w };
    s = lb3;
    #pragma unroll
    for (int j = 0; j < 8; j++) s += fmaxf(tv[j] + lb2[j], 0.f)*lw3[j];
    sbuf[e] = s;
    rank[e] = atomicAdd(&counts8[(size_t)(blockIdx.x & 7)*N + b], 1);
  }
  float vmin = valid ? s : FINF;
  float vmax = valid ? s : -FINF;
  #pragma unroll
  for (int o = 32; o > 0; o >>= 1){
    vmin = fminf(vmin, __shfl_xor(vmin, o));
    vmax = fmaxf(vmax, __shfl_xor(vmax, o));
  }
  if ((t & 63) == 0){ rmin[t >> 6] = vmin; rmax[t >> 6] = vmax; }
  __syncthreads();
  if (t == 0){
    float mn = fminf(fminf(rmin[0], rmin[1]), fminf(rmin[2], rmin[3]));
    float mx = fmaxf(fmaxf(rmax[0], rmax[1]), fmaxf(rmax[2], rmax[3]));
    pmm[blockIdx.x] = make_float2(mn, mx);
  }
}

// ---- device-wide exclusive scan over node totals (3 kernels) ----
__global__ __launch_bounds__(256) void k_scan1(const int* __restrict__ counts8,
        int* __restrict__ indptr, int* __restrict__ blockSums, int N){
  __shared__ int wsum[4];
  int t = threadIdx.x;
  int base = blockIdx.x*1024 + t*4;
  int c[4];
  #pragma unroll
  for (int i = 0; i < 4; i++) c[i] = 0;
  for (int r = 0; r < 8; r++){
    const int* cr = counts8 + (size_t)r*N;
    #pragma unroll
    for (int i = 0; i < 4; i++) if (base + i < N) c[i] += cr[base + i];
  }
  int s = c[0] + c[1] + c[2] + c[3];
  int lane = t & 63, wid = t >> 6;
  int inc = s;
  #pragma unroll
  for (int o = 1; o < 64; o <<= 1){
    int v = __shfl_up(inc, o);
    if (lane >= o) inc += v;
  }
  if (lane == 63) wsum[wid] = inc;
  __syncthreads();
  int woff = 0;
  #pragma unroll
  for (int i = 0; i < 4; i++) if (i < wid) woff += wsum[i];
  int run = woff + inc - s;
  #pragma unroll
  for (int i = 0; i < 4; i++){
    if (base + i < N) indptr[base + i] = run;
    run += c[i];
  }
  if (t == 255) blockSums[blockIdx.x] = woff + inc;
}

__global__ __launch_bounds__(64) void k_scan2(int* __restrict__ blockSums,
        int* __restrict__ indptr, int B, int N,
        const float2* __restrict__ pmm, int GB, float* __restrict__ minmax){
  int t = threadIdx.x;
  int carry = 0;
  for (int b0 = 0; b0 < B; b0 += 64){
    int idx = b0 + t;
    int v = (idx < B) ? blockSums[idx] : 0;
    int inc = v;
    #pragma unroll
    for (int o = 1; o < 64; o <<= 1){
      int u = __shfl_up(inc, o);
      if (t >= o) inc += u;
    }
    if (idx < B) blockSums[idx] = carry + inc - v;
    carry += __shfl(inc, 63);
  }
  if (t == 0) indptr[N] = carry;
  float mn = FINF, mx = -FINF;
  for (int i = t; i < GB; i += 64){
    float2 v = pmm[i];
    mn = fminf(mn, v.x);
    mx = fmaxf(mx, v.y);
  }
  #pragma unroll
  for (int o = 32; o > 0; o >>= 1){
    mn = fminf(mn, __shfl_xor(mn, o));
    mx = fmaxf(mx, __shfl_xor(mx, o));
  }
  if (t == 0){ minmax[0] = mn; minmax[1] = mx; }
}

// pass3: finalize indptr; per-(node,replica) scatter offsets
__global__ __launch_bounds__(256) void k_scan3(int* __restrict__ indptr,
        const int* __restrict__ blockSums, const int* __restrict__ counts8,
        int* __restrict__ repoff, int N){
  int i = blockIdx.x*blockDim.x + threadIdx.x;
  if (i >= N) return;
  int v = indptr[i] + blockSums[i >> 10];
  indptr[i] = v;
  int run = v;
  for (int r = 0; r < 8; r++){
    repoff[(size_t)r*N + i] = run;
    run += counts8[(size_t)r*N + i];
  }
}

// atomic-free CSR scatter (rank precomputed); fused gate-normalize
__global__ void k_scatter(const int* __restrict__ src, const int* __restrict__ dst,
                          const float* __restrict__ sbuf, const float* __restrict__ minmax,
                          const int* __restrict__ rank, const int* __restrict__ repoff,
                          float* __restrict__ gate_out, uint2* __restrict__ eg,
                          int E, int N){
  int e = blockIdx.x*blockDim.x + threadIdx.x;
  if (e >= E) return;
  float mn = minmax[0], mx = minmax[1];
  float g = (sbuf[e] - mn) / (mx - mn);
  gate_out[e] = g;
  int r = blockIdx.x & 7;   // must match k_gate_edge's blocking
  int pos = repoff[(size_t)r*N + dst[e]] + rank[e];
  uint2 v; v.x = (unsigned int)src[e]; v.y = __float_as_uint(g);
  eg[pos] = v;
}

// fused layer1 softmax+aggregation: one wave per dst node; staging lane computes
// 8 head-weights inline; den accumulated online. Writes hA as bf16.
__global__ __launch_bounds__(256) void k_gather1f(const int* __restrict__ indptr,
        const uint2* __restrict__ eg, const float* __restrict__ es1,
        const float* __restrict__ ed1, const unsigned int* __restrict__ z1b,
        unsigned int* __restrict__ hAb, int N){
  __shared__ float lap[4][64][8];
  int t = threadIdx.x;
  int w = t >> 6, lane = t & 63;
  int n = blockIdx.x*4 + w;
  if (n >= N) return;
  int hh = lane >> 3;
  float4 ev0 = *(const float4*)(ed1 + (size_t)n*8);
  float4 ev1 = *(const float4*)(ed1 + (size_t)n*8 + 4);
  int beg = indptr[n], end = indptr[n+1];
  float4 acc = make_float4(0.f,0.f,0.f,0.f);
  float den = 0.f;
  for (int c = beg; c < end; c += 64){
    int len = min(64, end - c);
    int sv = 0;
    if (lane < len){
      uint2 v = eg[c + lane];
      sv = (int)v.x;
      float g = __uint_as_float(v.y);
      float4 e0 = *(const float4*)(es1 + (size_t)sv*8);
      float4 e1 = *(const float4*)(es1 + (size_t)sv*8 + 4);
      float4 w0, w1;
      w0.x = __expf(leaky(e0.x + ev0.x)*g);
      w0.y = __expf(leaky(e0.y + ev0.y)*g);
      w0.z = __expf(leaky(e0.z + ev0.z)*g);
      w0.w = __expf(leaky(e0.w + ev0.w)*g);
      w1.x = __expf(leaky(e1.x + ev1.x)*g);
      w1.y = __expf(leaky(e1.y + ev1.y)*g);
      w1.z = __expf(leaky(e1.z + ev1.z)*g);
      w1.w = __expf(leaky(e1.w + ev1.w)*g);
      *(float4*)&lap[w][lane][0] = w0;
      *(float4*)&lap[w][lane][4] = w1;
    }
    __builtin_amdgcn_wave_barrier();
    for (int jj = 0; jj < len; jj++){
      int a = __shfl(sv, jj);
      float wgt = lap[w][jj][hh];
      uint2 zv = *(const uint2*)(z1b + (size_t)a*128 + lane*2);
      den += wgt;
      acc.x += wgt*bflo(zv.x); acc.y += wgt*bfhi(zv.x);
      acc.z += wgt*bflo(zv.y); acc.w += wgt*bfhi(zv.y);
    }
    __builtin_amdgcn_wave_barrier();
  }
  float iv = 1.f / fmaxf(den, 1e-12f);
  uint2 o;
  o.x = pack2(leaky(acc.x*iv), leaky(acc.y*iv));
  o.y = pack2(leaky(acc.z*iv), leaky(acc.w*iv));
  *(uint2*)(hAb + (size_t)n*128 + lane*2) = o;
}

// z2 = hA @ fc2 via MFMA bf16: 64-row tile, N=64, K=256
__global__ __launch_bounds__(256) void k_z2m(const unsigned short* __restrict__ hAu,
        const unsigned short* __restrict__ wp2, unsigned short* __restrict__ z2u,
        int N){
  __shared__ uint4 lw[2048];   // 32KB
  int t = threadIdx.x;
  const uint4* wp4 = (const uint4*)wp2;
  #pragma unroll
  for (int i = 0; i < 8; i++) lw[t + i*256] = wp4[t + i*256];
  __syncthreads();
  int l = t & 63, wv = t >> 6;
  int n0 = blockIdx.x*64, m0 = wv*16;
  int rowA = min(n0 + m0 + (l & 15), N-1);
  const unsigned short* ar = hAu + (size_t)rowA*256 + ((l >> 4) << 3);
  U4 a[8];
  #pragma unroll
  for (int kk = 0; kk < 8; kk++)
    a[kk].u = *(const uint4*)(ar + kk*32);
  int node0 = n0 + m0 + ((l >> 4) << 2);
  #pragma unroll
  for (int nt = 0; nt < 4; nt++){
    floatx4 acc = {0.f, 0.f, 0.f, 0.f};
    #pragma unroll
    for (int kk = 0; kk < 8; kk++){
      U4 b; b.u = lw[(nt*8 + kk)*64 + l];
      acc = __builtin_amdgcn_mfma_f32_16x16x32_bf16(a[kk].s, b.s, acc, 0, 0, 0);
    }
    int col = nt*16 + (l & 15);
    #pragma unroll
    for (int i2 = 0; i2 < 4; i2++){
      int node = node0 + i2;
      if (node < N) z2u[(size_t)node*64 + col] = (unsigned short)f2bf(acc[i2]);
    }
  }
}

// es2/ed2 from bf16 z2
__global__ void k_es_ed2(const unsigned short* __restrict__ z2u,
                         const float* __restrict__ a2s, const float* __restrict__ a2d,
                         float* __restrict__ es2, float* __restrict__ ed2, int N){
  int n = blockIdx.x*blockDim.x + threadIdx.x;
  if (n >= N) return;
  const uint4* zr = (const uint4*)(z2u + (size_t)n*64);
  float s0 = 0.f, s1 = 0.f;
  #pragma unroll
  for (int q = 0; q < 8; q++){
    uint4 v = zr[q];
    int o = q*8;
    s0 += bflo(v.x)*a2s[o+0] + bfhi(v.x)*a2s[o+1] + bflo(v.y)*a2s[o+2] + bfhi(v.y)*a2s[o+3]
        + bflo(v.z)*a2s[o+4] + bfhi(v.z)*a2s[o+5] + bflo(v.w)*a2s[o+6] + bfhi(v.w)*a2s[o+7];
    s1 += bflo(v.x)*a2d[o+0] + bfhi(v.x)*a2d[o+1] + bflo(v.y)*a2d[o+2] + bfhi(v.y)*a2d[o+3]
        + bflo(v.z)*a2d[o+4] + bfhi(v.z)*a2d[o+5] + bflo(v.w)*a2d[o+6] + bfhi(v.w)*a2d[o+7];
  }
  es2[n] = s0; ed2[n] = s1;
}

// fused layer2 softmax+aggregation+edge-predictor-projection:
// half-wave per dst node; lane-parallel weight staging (1 exp/edge);
// hB row kept in registers; ps/pd computed via shfl-reduce (no hB buffer).
__global__ __launch_bounds__(256) void k_gather2f(const int* __restrict__ indptr,
        const uint2* __restrict__ eg, const float* __restrict__ es2,
        const float* __restrict__ ed2, const unsigned int* __restrict__ z2b,
        const float* __restrict__ Wp, float* __restrict__ ps, float* __restrict__ pd,
        int N){
  __shared__ float lwp[256];
  int t = threadIdx.x;
  lwp[t] = Wp[t];
  __syncthreads();
  int n = blockIdx.x*8 + (t >> 5);
  if (n >= N) return;
  int l = t & 31;
  int sb = t & 32;   // shfl base within the wave (half 0 or half 1)
  float ed = ed2[n];
  int beg = indptr[n], end = indptr[n+1];
  float a0 = 0.f, a1 = 0.f, den = 0.f;
  for (int c = beg; c < end; c += 32){
    int len = min(32, end - c);
    int sv = 0; float wr = 0.f;
    if (l < len){
      uint2 v = eg[c + l];
      sv = (int)v.x;
      wr = __expf(leaky(es2[sv] + ed) * __uint_as_float(v.y));
    }
    for (int jj = 0; jj < len; jj++){
      int a = __shfl(sv, sb + jj);
      float wgt = __shfl(wr, sb + jj);
      unsigned int u = z2b[(size_t)a*32 + l];
      den += wgt;
      a0 += wgt*bflo(u);
      a1 += wgt*bfhi(u);
    }
  }
  float iv = 1.f / fmaxf(den, 1e-12f);
  float h0 = a0*iv, h1 = a1*iv;   // hB cols 2l, 2l+1
  float s0 = h0*lwp[4*l+0] + h1*lwp[4*l+2];
  float s1 = h0*lwp[4*l+1] + h1*lwp[4*l+3];
  float d0 = h0*lwp[128+4*l+0] + h1*lwp[128+4*l+2];
  float d1 = h0*lwp[128+4*l+1] + h1*lwp[128+4*l+3];
  #pragma unroll
  for (int o = 1; o < 32; o <<= 1){
    s0 += __shfl_xor(s0, o); s1 += __shfl_xor(s1, o);
    d0 += __shfl_xor(d0, o); d1 += __shfl_xor(d1, o);
  }
  if (l == 0){
    ps[(size_t)n*2]   = s0; ps[(size_t)n*2+1] = s1;
    pd[(size_t)n*2]   = d0; pd[(size_t)n*2+1] = d1;
  }
}

__global__ void k_edgepred(const int* __restrict__ src, const int* __restrict__ dst,
                           const float* __restrict__ ps, const float* __restrict__ pd,
                           const float* __restrict__ bp, float* __restrict__ out, int E){
  int e = blockIdx.x*blockDim.x + threadIdx.x;
  if (e >= E) return;
  int a = src[e], b = dst[e];
  float2 vs = ((const float2*)ps)[a];
  float2 vd = ((const float2*)pd)[b];
  float2 o;
  o.x = vs.x + vd.x + bp[0];
  o.y = vs.y + vd.y + bp[1];
  ((float2*)out)[e] = o;
}

extern "C" void kernel_launch(void* const* d_in, const int* in_sizes, int n_in,
                              void* d_out, int out_size, void* d_ws, size_t ws_size,
                              hipStream_t stream) {
  const float* h   = (const float*)d_in[0];
  const int*   src = (const int*)d_in[1];
  const int*   dst = (const int*)d_in[2];
  const float* W1  = (const float*)d_in[3];
  const float* b1  = (const float*)d_in[4];
  const float* W2  = (const float*)d_in[5];
  const float* b2  = (const float*)d_in[6];
  const float* W3  = (const float*)d_in[7];
  const float* b3  = (const float*)d_in[8];
  const float* fc1 = (const float*)d_in[9];
  const float* a1s = (const float*)d_in[10];
  const float* a1d = (const float*)d_in[11];
  const float* fc2 = (const float*)d_in[12];
  const float* a2s = (const float*)d_in[13];
  const float* a2d = (const float*)d_in[14];
  const float* Wp  = (const float*)d_in[15];
  const float* bp  = (const float*)d_in[16];

  const int N = in_sizes[0] / 128;
  const int E = in_sizes[1];

  float* out_score = (float*)d_out;             // [E,2]
  float* gate      = out_score + (size_t)E*2;   // [E]

  char* w = (char*)d_ws;
  size_t off = 0;
  auto alloc = [&](size_t bytes) -> void* {
    off = (off + 255) & ~(size_t)255;
    void* p = w + off; off += bytes; return p;
  };
  float* u_s  = (float*)alloc((size_t)N*8*4);
  float* u_d  = (float*)alloc((size_t)N*8*4);
  unsigned short* z1u = (unsigned short*)alloc((size_t)N*256*2);  // bf16 [N,256]
  float* es1  = (float*)alloc((size_t)N*8*4);
  float* ed1  = (float*)alloc((size_t)N*8*4);
  float* sbuf = (float*)alloc((size_t)E*4);
  unsigned short* hAu = (unsigned short*)alloc((size_t)N*256*2);  // bf16 [N,256]
  float* es2  = (float*)alloc((size_t)N*4);
  float* ed2  = (float*)alloc((size_t)N*4);
  float* minmax = (float*)alloc(2*4);
  int* counts8 = (int*)alloc((size_t)N*8*4);
  int* repoff  = (int*)alloc((size_t)N*8*4);
  int* rank    = (int*)alloc((size_t)E*4);
  int* indptr = (int*)alloc(((size_t)N+1)*4);
  int* blockSums = (int*)alloc(1024*4);
  const int GATE_B = (E + 255)/256;
  float2* pmm = (float2*)alloc((size_t)GATE_B*8);
  uint2* eg   = (uint2*)alloc((size_t)E*8);
  unsigned short* wp1 = (unsigned short*)alloc(32768*2);
  unsigned short* wp2 = (unsigned short*)alloc(16384*2);
  (void)ws_size; (void)n_in; (void)out_size;

  // reuse: z1u dead after gather1f -> z2u; u_s/u_d dead after gate_edge -> ps/pd
  unsigned short* z2u = z1u;
  float* ps  = u_s;
  float* pd  = u_d;

  const int SCAN_B = (N + 1023)/1024;

  k_init<<<(N*8 + 255)/256, 256, 0, stream>>>(counts8, N*8);
  k_h1u<<<(N + 15)/16, 256, 0, stream>>>(h, W1, b1, W2, u_s, u_d, N);
  k_wpack<<<192, 256, 0, stream>>>(fc1, fc2, wp1, wp2);
  k_z1m<<<(N + 63)/64, 256, 0, stream>>>(h, wp1, z1u, N);
  k_es_ed1<<<(N*8 + 255)/256, 256, 0, stream>>>(z1u, a1s, a1d, es1, ed1, N);
  k_gate_edge<<<GATE_B, 256, 0, stream>>>(u_s, u_d, src, dst, b2, W3, b3,
                                          sbuf, counts8, rank, pmm, E, N);
  k_scan1<<<SCAN_B, 256, 0, stream>>>(counts8, indptr, blockSums, N);
  k_scan2<<<1, 64, 0, stream>>>(blockSums, indptr, SCAN_B, N, pmm, GATE_B, minmax);
  k_scan3<<<(N + 255)/256, 256, 0, stream>>>(indptr, blockSums, counts8, repoff, N);
  k_scatter<<<GATE_B, 256, 0, stream>>>(src, dst, sbuf, minmax, rank, repoff,
                                        gate, eg, E, N);
  k_gather1f<<<(N + 3)/4, 256, 0, stream>>>(indptr, eg, es1, ed1,
                                            (const unsigned int*)z1u,
                                            (unsigned int*)hAu, N);
  k_z2m<<<(N + 63)/64, 256, 0, stream>>>(hAu, wp2, z2u, N);
  k_es_ed2<<<(N + 255)/256, 256, 0, stream>>>(z2u, a2s, a2d, es2, ed2, N);
  k_gather2f<<<(N + 7)/8, 256, 0, stream>>>(indptr, eg, es2, ed2,
                                            (const unsigned int*)z2u,
                                            Wp, ps, pd, N);
  k_edgepred<<<(E + 255)/256, 256, 0, stream>>>(src, dst, ps, pd, bp, out_score, E);
}

// Round 11
// 228.690 us; speedup vs baseline: 5.6124x; 1.1424x over previous
//
#include <hip/hip_runtime.h>
#include <math.h>

#define FINF __builtin_inff()

using short8  = __attribute__((ext_vector_type(8))) short;
using floatx4 = __attribute__((ext_vector_type(4))) float;
union U4 { uint4 u; short8 s; };

__device__ __forceinline__ float leaky(float x){ return x > 0.f ? x : 0.01f*x; }

// fp32 -> bf16 (RNE) and pack two into a u32
__device__ __forceinline__ unsigned int f2bf(float f){
  unsigned int x = __float_as_uint(f);
  x += 0x7FFFu + ((x >> 16) & 1u);
  return x >> 16;
}
__device__ __forceinline__ unsigned int pack2(float lo, float hi){
  return f2bf(lo) | (f2bf(hi) << 16);
}
__device__ __forceinline__ float bflo(unsigned int u){ return __uint_as_float(u << 16); }
__device__ __forceinline__ float bfhi(unsigned int u){ return __uint_as_float(u & 0xFFFF0000u); }

// ---- k_prep: weight repack (incl. algebraic folds) + ubias + counts8 init ----
// wp1 layout: 18 tiles x [kk 0..3][lane 0..63][i 0..7], tile nt covers cols nt*16..+15
//   tiles 0..15 : fc1 (z1 GEMM B)
//   tile 16     : cols = interleaved [es h, ed h] folds = fc1[h]@a1s/d[h]
//   tile 17     : cols = [u_s 0..7, u_d 0..7] folds = W1@W2top/bot
// wp2 layout: 5 tiles x [kk 0..7][lane][i]
//   tiles 0..3 : fc2 ; tile 4: col0 = fc2@a2s, col1 = fc2@a2d
__global__ __launch_bounds__(256) void k_prep(const float* __restrict__ fc1,
        const float* __restrict__ fc2, const float* __restrict__ W1,
        const float* __restrict__ W2, const float* __restrict__ b1,
        const float* __restrict__ a1s, const float* __restrict__ a1d,
        const float* __restrict__ a2s, const float* __restrict__ a2d,
        unsigned short* __restrict__ wp1, unsigned short* __restrict__ wp2,
        float* __restrict__ ubias, int* __restrict__ counts8, int N){
  int b = blockIdx.x, t = threadIdx.x;
  if (b < 224){
    int idx = b*256 + t;
    if (idx < 32768){
      int i  = idx & 7;
      int l  = (idx >> 3) & 63;
      int kk = (idx >> 9) & 3;
      int nt = idx >> 11;
      int n = nt*16 + (l & 15);
      int k = kk*32 + ((l >> 4) << 3) + i;
      wp1[idx] = (unsigned short)f2bf(fc1[(size_t)(n >> 5)*4096 + k*32 + (n & 31)]);
    } else if (idx < 34816){
      int j = idx - 32768;
      int i = j & 7, l = (j >> 3) & 63, kk = j >> 9;
      int k = kk*32 + ((l >> 4) << 3) + i;
      int c = l & 15, hh = c >> 1;
      const float* f = fc1 + (size_t)hh*4096 + (size_t)k*32;
      const float* av = (c & 1) ? (a1d + hh*32) : (a1s + hh*32);
      float s = 0.f;
      #pragma unroll
      for (int o = 0; o < 32; o++) s += f[o]*av[o];
      wp1[idx] = (unsigned short)f2bf(s);
    } else if (idx < 36864){
      int j = idx - 34816;
      int i = j & 7, l = (j >> 3) & 63, kk = j >> 9;
      int k = kk*32 + ((l >> 4) << 3) + i;
      int c = l & 15;
      float s = 0.f;
      if (c < 8){
        #pragma unroll
        for (int o = 0; o < 16; o++) s += W1[k*16 + o]*W2[o*8 + c];
      } else {
        #pragma unroll
        for (int o = 0; o < 16; o++) s += W1[k*16 + o]*W2[(16 + o)*8 + (c - 8)];
      }
      wp1[idx] = (unsigned short)f2bf(s);
    } else {
      int j = idx - 36864;
      if (j < 16384){
        int i  = j & 7, l = (j >> 3) & 63, kk = (j >> 9) & 7, nt = j >> 12;
        int n = nt*16 + (l & 15);
        int k = kk*32 + ((l >> 4) << 3) + i;
        wp2[j] = (unsigned short)f2bf(fc2[(size_t)k*64 + n]);
      } else {
        int q = j - 16384;
        int i = q & 7, l = (q >> 3) & 63, kk = q >> 9;
        int k = kk*32 + ((l >> 4) << 3) + i;
        int c = l & 15;
        float s = 0.f;
        if (c == 0){
          for (int o = 0; o < 64; o++) s += fc2[(size_t)k*64 + o]*a2s[o];
        } else if (c == 1){
          for (int o = 0; o < 64; o++) s += fc2[(size_t)k*64 + o]*a2d[o];
        }
        wp2[j] = (unsigned short)f2bf(s);
      }
    }
  } else if (b == 224){
    if (t < 16){
      float s = 0.f;
      if (t < 8){
        #pragma unroll
        for (int o = 0; o < 16; o++) s += b1[o]*W2[o*8 + t];
      } else {
        #pragma unroll
        for (int o = 0; o < 16; o++) s += b1[o]*W2[(16 + o)*8 + (t - 8)];
      }
      ubias[t] = s;
    }
  } else {
    int i = (b - 225)*256 + t;
    if (i < N*8) counts8[i] = 0;
  }
}

// z1 GEMM via MFMA bf16 + fused es1/ed1 + u_s/u_d epilogue columns.
// 64-row tile, 4 waves x 16 rows. Tiles 0..15 B from LDS; 16..17 from L2.
__global__ __launch_bounds__(256) void k_z1m(const float* __restrict__ h,
        const unsigned short* __restrict__ wp1, const float* __restrict__ ubias,
        unsigned short* __restrict__ z1u, float* __restrict__ es1,
        float* __restrict__ ed1, float* __restrict__ u_s, float* __restrict__ u_d,
        int N){
  __shared__ uint4 lw[4096];   // 64KB: tiles 0..15
  int t = threadIdx.x;
  const uint4* wp4 = (const uint4*)wp1;
  #pragma unroll
  for (int i = 0; i < 16; i++) lw[t + i*256] = wp4[t + i*256];
  __syncthreads();
  int l = t & 63, wv = t >> 6;
  int n0 = blockIdx.x*64, m0 = wv*16;
  int rowA = min(n0 + m0 + (l & 15), N-1);
  const float* hr = h + (size_t)rowA*128 + ((l >> 4) << 3);
  U4 a[4];
  #pragma unroll
  for (int kk = 0; kk < 4; kk++){
    float4 f0 = *(const float4*)(hr + kk*32);
    float4 f1 = *(const float4*)(hr + kk*32 + 4);
    a[kk].u.x = pack2(f0.x, f0.y); a[kk].u.y = pack2(f0.z, f0.w);
    a[kk].u.z = pack2(f1.x, f1.y); a[kk].u.w = pack2(f1.z, f1.w);
  }
  int node0 = n0 + m0 + ((l >> 4) << 2);
  int c = l & 15;
  float ub = ubias[c];
  #pragma unroll
  for (int nt = 0; nt < 18; nt++){
    floatx4 acc;
    float b0 = (nt == 17) ? ub : 0.f;
    acc[0] = b0; acc[1] = b0; acc[2] = b0; acc[3] = b0;
    #pragma unroll
    for (int kk = 0; kk < 4; kk++){
      U4 bfr;
      bfr.u = (nt < 16) ? lw[(nt*4 + kk)*64 + l] : wp4[(nt*4 + kk)*64 + l];
      acc = __builtin_amdgcn_mfma_f32_16x16x32_bf16(a[kk].s, bfr.s, acc, 0, 0, 0);
    }
    if (nt < 16){
      int col = nt*16 + c;
      #pragma unroll
      for (int i2 = 0; i2 < 4; i2++){
        int node = node0 + i2;
        if (node < N) z1u[(size_t)node*256 + col] = (unsigned short)f2bf(acc[i2]);
      }
    } else if (nt == 16){
      int hh = c >> 1;
      #pragma unroll
      for (int i2 = 0; i2 < 4; i2++){
        int node = node0 + i2;
        if (node < N){
          if (c & 1) ed1[node*8 + hh] = acc[i2];
          else       es1[node*8 + hh] = acc[i2];
        }
      }
    } else {
      #pragma unroll
      for (int i2 = 0; i2 < 4; i2++){
        int node = node0 + i2;
        if (node < N){
          if (c < 8) u_s[(size_t)node*8 + c] = acc[i2];
          else       u_d[(size_t)node*8 + (c - 8)] = acc[i2];
        }
      }
    }
  }
}

// gate edge score; XCD-replicated dst histogram + per-edge rank; block (min,max)
__global__ __launch_bounds__(256) void k_gate_edge(const float* __restrict__ u_s,
        const float* __restrict__ u_d,
        const int* __restrict__ src, const int* __restrict__ dst,
        const float* __restrict__ b2, const float* __restrict__ W3,
        const float* __restrict__ b3,
        float* __restrict__ sbuf, int* __restrict__ counts8,
        int* __restrict__ rank, float2* __restrict__ pmm, int E, int N){
  __shared__ float lb2[8], lw3[8];
  __shared__ float lb3;
  __shared__ float rmin[4], rmax[4];
  int t = threadIdx.x;
  if (t < 8){ lb2[t] = b2[t]; lw3[t] = W3[t]; }
  if (t == 8) lb3 = b3[0];
  __syncthreads();
  int e = blockIdx.x*blockDim.x + t;
  float s = 0.f;
  bool valid = (e < E);
  if (valid){
    int a = src[e], b = dst[e];
    float4 us0 = ((const float4*)(u_s + (size_t)a*8))[0];
    float4 us1 = ((const float4*)(u_s + (size_t)a*8))[1];
    float4 ud0 = ((const float4*)(u_d + (size_t)b*8))[0];
    float4 ud1 = ((const float4*)(u_d + (size_t)b*8))[1];
    float tv[8] = { us0.x+ud0.x, us0.y+ud0.y, us0.z+ud0.z, us0.w+ud0.w,
                    us1.x+ud1.x, us1.y+ud1.y, us1.z+ud1.z, us1.w+ud1.w };
    s = lb3;
    #pragma unroll
    for (int j = 0; j < 8; j++) s += fmaxf(tv[j] + lb2[j], 0.f)*lw3[j];
    sbuf[e] = s;
    rank[e] = atomicAdd(&counts8[(size_t)(blockIdx.x & 7)*N + b], 1);
  }
  float vmin = valid ? s : FINF;
  float vmax = valid ? s : -FINF;
  #pragma unroll
  for (int o = 32; o > 0; o >>= 1){
    vmin = fminf(vmin, __shfl_xor(vmin, o));
    vmax = fmaxf(vmax, __shfl_xor(vmax, o));
  }
  if ((t & 63) == 0){ rmin[t >> 6] = vmin; rmax[t >> 6] = vmax; }
  __syncthreads();
  if (t == 0){
    float mn = fminf(fminf(rmin[0], rmin[1]), fminf(rmin[2], rmin[3]));
    float mx = fmaxf(fmaxf(rmax[0], rmax[1]), fmaxf(rmax[2], rmax[3]));
    pmm[blockIdx.x] = make_float2(mn, mx);
  }
}

// ---- device-wide exclusive scan over node totals (3 kernels) ----
__global__ __launch_bounds__(256) void k_scan1(const int* __restrict__ counts8,
        int* __restrict__ indptr, int* __restrict__ blockSums, int N){
  __shared__ int wsum[4];
  int t = threadIdx.x;
  int base = blockIdx.x*1024 + t*4;
  int c[4];
  #pragma unroll
  for (int i = 0; i < 4; i++) c[i] = 0;
  for (int r = 0; r < 8; r++){
    const int* cr = counts8 + (size_t)r*N;
    #pragma unroll
    for (int i = 0; i < 4; i++) if (base + i < N) c[i] += cr[base + i];
  }
  int s = c[0] + c[1] + c[2] + c[3];
  int lane = t & 63, wid = t >> 6;
  int inc = s;
  #pragma unroll
  for (int o = 1; o < 64; o <<= 1){
    int v = __shfl_up(inc, o);
    if (lane >= o) inc += v;
  }
  if (lane == 63) wsum[wid] = inc;
  __syncthreads();
  int woff = 0;
  #pragma unroll
  for (int i = 0; i < 4; i++) if (i < wid) woff += wsum[i];
  int run = woff + inc - s;
  #pragma unroll
  for (int i = 0; i < 4; i++){
    if (base + i < N) indptr[base + i] = run;
    run += c[i];
  }
  if (t == 255) blockSums[blockIdx.x] = woff + inc;
}

__global__ __launch_bounds__(64) void k_scan2(int* __restrict__ blockSums,
        int* __restrict__ indptr, int B, int N,
        const float2* __restrict__ pmm, int GB, float* __restrict__ minmax){
  int t = threadIdx.x;
  int carry = 0;
  for (int b0 = 0; b0 < B; b0 += 64){
    int idx = b0 + t;
    int v = (idx < B) ? blockSums[idx] : 0;
    int inc = v;
    #pragma unroll
    for (int o = 1; o < 64; o <<= 1){
      int u = __shfl_up(inc, o);
      if (t >= o) inc += u;
    }
    if (idx < B) blockSums[idx] = carry + inc - v;
    carry += __shfl(inc, 63);
  }
  if (t == 0) indptr[N] = carry;
  float mn = FINF, mx = -FINF;
  for (int i = t; i < GB; i += 64){
    float2 v = pmm[i];
    mn = fminf(mn, v.x);
    mx = fmaxf(mx, v.y);
  }
  #pragma unroll
  for (int o = 32; o > 0; o >>= 1){
    mn = fminf(mn, __shfl_xor(mn, o));
    mx = fmaxf(mx, __shfl_xor(mx, o));
  }
  if (t == 0){ minmax[0] = mn; minmax[1] = mx; }
}

// pass3: finalize indptr; per-(node,replica) scatter offsets
__global__ __launch_bounds__(256) void k_scan3(int* __restrict__ indptr,
        const int* __restrict__ blockSums, const int* __restrict__ counts8,
        int* __restrict__ repoff, int N){
  int i = blockIdx.x*blockDim.x + threadIdx.x;
  if (i >= N) return;
  int v = indptr[i] + blockSums[i >> 10];
  indptr[i] = v;
  int run = v;
  for (int r = 0; r < 8; r++){
    repoff[(size_t)r*N + i] = run;
    run += counts8[(size_t)r*N + i];
  }
}

// atomic-free CSR scatter (rank precomputed); fused gate-normalize
__global__ void k_scatter(const int* __restrict__ src, const int* __restrict__ dst,
                          const float* __restrict__ sbuf, const float* __restrict__ minmax,
                          const int* __restrict__ rank, const int* __restrict__ repoff,
                          float* __restrict__ gate_out, uint2* __restrict__ eg,
                          int E, int N){
  int e = blockIdx.x*blockDim.x + threadIdx.x;
  if (e >= E) return;
  float mn = minmax[0], mx = minmax[1];
  float g = (sbuf[e] - mn) / (mx - mn);
  gate_out[e] = g;
  int r = blockIdx.x & 7;   // must match k_gate_edge's blocking
  int pos = repoff[(size_t)r*N + dst[e]] + rank[e];
  uint2 v; v.x = (unsigned int)src[e]; v.y = __float_as_uint(g);
  eg[pos] = v;
}

// fused layer1 softmax+aggregation: one wave per dst node; staging lane computes
// 8 head-weights inline; den accumulated online. Writes hA as bf16.
__global__ __launch_bounds__(256) void k_gather1f(const int* __restrict__ indptr,
        const uint2* __restrict__ eg, const float* __restrict__ es1,
        const float* __restrict__ ed1, const unsigned int* __restrict__ z1b,
        unsigned int* __restrict__ hAb, int N){
  __shared__ float lap[4][64][8];
  int t = threadIdx.x;
  int w = t >> 6, lane = t & 63;
  int n = blockIdx.x*4 + w;
  if (n >= N) return;
  int hh = lane >> 3;
  float4 ev0 = *(const float4*)(ed1 + (size_t)n*8);
  float4 ev1 = *(const float4*)(ed1 + (size_t)n*8 + 4);
  int beg = indptr[n], end = indptr[n+1];
  float4 acc = make_float4(0.f,0.f,0.f,0.f);
  float den = 0.f;
  for (int c = beg; c < end; c += 64){
    int len = min(64, end - c);
    int sv = 0;
    if (lane < len){
      uint2 v = eg[c + lane];
      sv = (int)v.x;
      float g = __uint_as_float(v.y);
      float4 e0 = *(const float4*)(es1 + (size_t)sv*8);
      float4 e1 = *(const float4*)(es1 + (size_t)sv*8 + 4);
      float4 w0, w1;
      w0.x = __expf(leaky(e0.x + ev0.x)*g);
      w0.y = __expf(leaky(e0.y + ev0.y)*g);
      w0.z = __expf(leaky(e0.z + ev0.z)*g);
      w0.w = __expf(leaky(e0.w + ev0.w)*g);
      w1.x = __expf(leaky(e1.x + ev1.x)*g);
      w1.y = __expf(leaky(e1.y + ev1.y)*g);
      w1.z = __expf(leaky(e1.z + ev1.z)*g);
      w1.w = __expf(leaky(e1.w + ev1.w)*g);
      *(float4*)&lap[w][lane][0] = w0;
      *(float4*)&lap[w][lane][4] = w1;
    }
    __builtin_amdgcn_wave_barrier();
    for (int jj = 0; jj < len; jj++){
      int a = __shfl(sv, jj);
      float wgt = lap[w][jj][hh];
      uint2 zv = *(const uint2*)(z1b + (size_t)a*128 + lane*2);
      den += wgt;
      acc.x += wgt*bflo(zv.x); acc.y += wgt*bfhi(zv.x);
      acc.z += wgt*bflo(zv.y); acc.w += wgt*bfhi(zv.y);
    }
    __builtin_amdgcn_wave_barrier();
  }
  float iv = 1.f / fmaxf(den, 1e-12f);
  uint2 o;
  o.x = pack2(leaky(acc.x*iv), leaky(acc.y*iv));
  o.y = pack2(leaky(acc.z*iv), leaky(acc.w*iv));
  *(uint2*)(hAb + (size_t)n*128 + lane*2) = o;
}

// z2 GEMM via MFMA bf16 + fused es2/ed2 epilogue columns. Tiles 0..3 LDS, 4 L2.
__global__ __launch_bounds__(256) void k_z2m(const unsigned short* __restrict__ hAu,
        const unsigned short* __restrict__ wp2, unsigned short* __restrict__ z2u,
        float* __restrict__ es2, float* __restrict__ ed2, int N){
  __shared__ uint4 lw[2048];   // 32KB: tiles 0..3
  int t = threadIdx.x;
  const uint4* wp4 = (const uint4*)wp2;
  #pragma unroll
  for (int i = 0; i < 8; i++) lw[t + i*256] = wp4[t + i*256];
  __syncthreads();
  int l = t & 63, wv = t >> 6;
  int n0 = blockIdx.x*64, m0 = wv*16;
  int rowA = min(n0 + m0 + (l & 15), N-1);
  const unsigned short* ar = hAu + (size_t)rowA*256 + ((l >> 4) << 3);
  U4 a[8];
  #pragma unroll
  for (int kk = 0; kk < 8; kk++)
    a[kk].u = *(const uint4*)(ar + kk*32);
  int node0 = n0 + m0 + ((l >> 4) << 2);
  int c = l & 15;
  #pragma unroll
  for (int nt = 0; nt < 5; nt++){
    floatx4 acc = {0.f, 0.f, 0.f, 0.f};
    #pragma unroll
    for (int kk = 0; kk < 8; kk++){
      U4 bfr;
      bfr.u = (nt < 4) ? lw[(nt*8 + kk)*64 + l] : wp4[(nt*8 + kk)*64 + l];
      acc = __builtin_amdgcn_mfma_f32_16x16x32_bf16(a[kk].s, bfr.s, acc, 0, 0, 0);
    }
    if (nt < 4){
      int col = nt*16 + c;
      #pragma unroll
      for (int i2 = 0; i2 < 4; i2++){
        int node = node0 + i2;
        if (node < N) z2u[(size_t)node*64 + col] = (unsigned short)f2bf(acc[i2]);
      }
    } else {
      #pragma unroll
      for (int i2 = 0; i2 < 4; i2++){
        int node = node0 + i2;
        if (node < N){
          if (c == 0) es2[node] = acc[i2];
          else if (c == 1) ed2[node] = acc[i2];
        }
      }
    }
  }
}

// fused layer2 softmax+aggregation+edge-predictor-projection
__global__ __launch_bounds__(256) void k_gather2f(const int* __restrict__ indptr,
        const uint2* __restrict__ eg, const float* __restrict__ es2,
        const float* __restrict__ ed2, const unsigned int* __restrict__ z2b,
        const float* __restrict__ Wp, float* __restrict__ ps, float* __restrict__ pd,
        int N){
  __shared__ float lwp[256];
  int t = threadIdx.x;
  lwp[t] = Wp[t];
  __syncthreads();
  int n = blockIdx.x*8 + (t >> 5);
  if (n >= N) return;
  int l = t & 31;
  int sb = t & 32;   // shfl base within the wave (half 0 or half 1)
  float ed = ed2[n];
  int beg = indptr[n], end = indptr[n+1];
  float a0 = 0.f, a1 = 0.f, den = 0.f;
  for (int c = beg; c < end; c += 32){
    int len = min(32, end - c);
    int sv = 0; float wr = 0.f;
    if (l < len){
      uint2 v = eg[c + l];
      sv = (int)v.x;
      wr = __expf(leaky(es2[sv] + ed) * __uint_as_float(v.y));
    }
    for (int jj = 0; jj < len; jj++){
      int a = __shfl(sv, sb + jj);
      float wgt = __shfl(wr, sb + jj);
      unsigned int u = z2b[(size_t)a*32 + l];
      den += wgt;
      a0 += wgt*bflo(u);
      a1 += wgt*bfhi(u);
    }
  }
  float iv = 1.f / fmaxf(den, 1e-12f);
  float h0 = a0*iv, h1 = a1*iv;   // hB cols 2l, 2l+1
  float s0 = h0*lwp[4*l+0] + h1*lwp[4*l+2];
  float s1 = h0*lwp[4*l+1] + h1*lwp[4*l+3];
  float d0 = h0*lwp[128+4*l+0] + h1*lwp[128+4*l+2];
  float d1 = h0*lwp[128+4*l+1] + h1*lwp[128+4*l+3];
  #pragma unroll
  for (int o = 1; o < 32; o <<= 1){
    s0 += __shfl_xor(s0, o); s1 += __shfl_xor(s1, o);
    d0 += __shfl_xor(d0, o); d1 += __shfl_xor(d1, o);
  }
  if (l == 0){
    ps[(size_t)n*2]   = s0; ps[(size_t)n*2+1] = s1;
    pd[(size_t)n*2]   = d0; pd[(size_t)n*2+1] = d1;
  }
}

__global__ void k_edgepred(const int* __restrict__ src, const int* __restrict__ dst,
                           const float* __restrict__ ps, const float* __restrict__ pd,
                           const float* __restrict__ bp, float* __restrict__ out, int E){
  int e = blockIdx.x*blockDim.x + threadIdx.x;
  if (e >= E) return;
  int a = src[e], b = dst[e];
  float2 vs = ((const float2*)ps)[a];
  float2 vd = ((const float2*)pd)[b];
  float2 o;
  o.x = vs.x + vd.x + bp[0];
  o.y = vs.y + vd.y + bp[1];
  ((float2*)out)[e] = o;
}

extern "C" void kernel_launch(void* const* d_in, const int* in_sizes, int n_in,
                              void* d_out, int out_size, void* d_ws, size_t ws_size,
                              hipStream_t stream) {
  const float* h   = (const float*)d_in[0];
  const int*   src = (const int*)d_in[1];
  const int*   dst = (const int*)d_in[2];
  const float* W1  = (const float*)d_in[3];
  const float* b1  = (const float*)d_in[4];
  const float* W2  = (const float*)d_in[5];
  const float* b2  = (const float*)d_in[6];
  const float* W3  = (const float*)d_in[7];
  const float* b3  = (const float*)d_in[8];
  const float* fc1 = (const float*)d_in[9];
  const float* a1s = (const float*)d_in[10];
  const float* a1d = (const float*)d_in[11];
  const float* fc2 = (const float*)d_in[12];
  const float* a2s = (const float*)d_in[13];
  const float* a2d = (const float*)d_in[14];
  const float* Wp  = (const float*)d_in[15];
  const float* bp  = (const float*)d_in[16];

  const int N = in_sizes[0] / 128;
  const int E = in_sizes[1];

  float* out_score = (float*)d_out;             // [E,2]
  float* gate      = out_score + (size_t)E*2;   // [E]

  char* w = (char*)d_ws;
  size_t off = 0;
  auto alloc = [&](size_t bytes) -> void* {
    off = (off + 255) & ~(size_t)255;
    void* p = w + off; off += bytes; return p;
  };
  float* u_s  = (float*)alloc((size_t)N*8*4);
  float* u_d  = (float*)alloc((size_t)N*8*4);
  unsigned short* z1u = (unsigned short*)alloc((size_t)N*256*2);  // bf16 [N,256]
  float* es1  = (float*)alloc((size_t)N*8*4);
  float* ed1  = (float*)alloc((size_t)N*8*4);
  float* sbuf = (float*)alloc((size_t)E*4);
  unsigned short* hAu = (unsigned short*)alloc((size_t)N*256*2);  // bf16 [N,256]
  float* es2  = (float*)alloc((size_t)N*4);
  float* ed2  = (float*)alloc((size_t)N*4);
  float* minmax = (float*)alloc(2*4);
  float* ubias  = (float*)alloc(16*4);
  int* counts8 = (int*)alloc((size_t)N*8*4);
  int* repoff  = (int*)alloc((size_t)N*8*4);
  int* rank    = (int*)alloc((size_t)E*4);
  int* indptr = (int*)alloc(((size_t)N+1)*4);
  int* blockSums = (int*)alloc(1024*4);
  const int GATE_B = (E + 255)/256;
  float2* pmm = (float2*)alloc((size_t)GATE_B*8);
  uint2* eg   = (uint2*)alloc((size_t)E*8);
  unsigned short* wp1 = (unsigned short*)alloc(36864*2);  // 18 tiles
  unsigned short* wp2 = (unsigned short*)alloc(20480*2);  // 5 tiles
  (void)ws_size; (void)n_in; (void)out_size;

  // reuse: z1u dead after gather1f -> z2u; u_s/u_d dead after gate_edge -> ps/pd
  unsigned short* z2u = z1u;
  float* ps  = u_s;
  float* pd  = u_d;

  const int SCAN_B = (N + 1023)/1024;
  const int INIT_B = (N*8 + 255)/256;

  k_prep<<<225 + INIT_B, 256, 0, stream>>>(fc1, fc2, W1, W2, b1, a1s, a1d,
                                           a2s, a2d, wp1, wp2, ubias, counts8, N);
  k_z1m<<<(N + 63)/64, 256, 0, stream>>>(h, wp1, ubias, z1u, es1, ed1, u_s, u_d, N);
  k_gate_edge<<<GATE_B, 256, 0, stream>>>(u_s, u_d, src, dst, b2, W3, b3,
                                          sbuf, counts8, rank, pmm, E, N);
  k_scan1<<<SCAN_B, 256, 0, stream>>>(counts8, indptr, blockSums, N);
  k_scan2<<<1, 64, 0, stream>>>(blockSums, indptr, SCAN_B, N, pmm, GATE_B, minmax);
  k_scan3<<<(N + 255)/256, 256, 0, stream>>>(indptr, blockSums, counts8, repoff, N);
  k_scatter<<<GATE_B, 256, 0, stream>>>(src, dst, sbuf, minmax, rank, repoff,
                                        gate, eg, E, N);
  k_gather1f<<<(N + 3)/4, 256, 0, stream>>>(indptr, eg, es1, ed1,
                                            (const unsigned int*)z1u,
                                            (unsigned int*)hAu, N);
  k_z2m<<<(N + 63)/64, 256, 0, stream>>>(hAu, wp2, z2u, es2, ed2, N);
  k_gather2f<<<(N + 7)/8, 256, 0, stream>>>(indptr, eg, es2, ed2,
                                            (const unsigned int*)z2u,
                                            Wp, ps, pd, N);
  k_edgepred<<<(E + 255)/256, 256, 0, stream>>>(src, dst, ps, pd, bp, out_score, E);
}